// Round 1
// baseline (18252.908 us; speedup 1.0000x reference)
//
#include <hip/hip_runtime.h>
#include <hip/hip_bf16.h>
#include <cstdint>

// ---------------------------------------------------------------------------
// FullHeteroGCN: 2-layer hetero GraphSAGE (mean aggr), f32.
// Pipeline per call:
//   1. build CSR per relation (hist -> scan -> fill)     [reused across layers]
//   2. prep combined/scaled weights for the 3-pair transforms
//   3. layer1: agg x3, transform p1 (3-pair), transform a1 (2-pair)
//   4. layer2: agg x2 (from p1/a1), transform p2 (3-pair)
//   5. final 128->8 linear head
// ---------------------------------------------------------------------------

__global__ __launch_bounds__(256)
void hist_kernel(const int* __restrict__ dst, int E, int* __restrict__ cnt) {
    int i = blockIdx.x * 256 + threadIdx.x;
    if (i < E) atomicAdd(&cnt[dst[i]], 1);
}

// One block per relation: sequential-chunk exclusive scan (256-wide Hillis-Steele).
__global__ __launch_bounds__(256)
void scan3_kernel(const int* c0, int* o0, int n0,
                  const int* c1, int* o1, int n1,
                  const int* c2, int* o2, int n2) {
    const int* cnt; int* off; int n;
    if (blockIdx.x == 0)      { cnt = c0; off = o0; n = n0; }
    else if (blockIdx.x == 1) { cnt = c1; off = o1; n = n1; }
    else                      { cnt = c2; off = o2; n = n2; }
    __shared__ int s[256];
    __shared__ int carry;
    const int tid = threadIdx.x;
    if (tid == 0) carry = 0;
    __syncthreads();
    for (int base = 0; base < n; base += 256) {
        int i = base + tid;
        int v = (i < n) ? cnt[i] : 0;
        s[tid] = v;
        __syncthreads();
        for (int d = 1; d < 256; d <<= 1) {
            int t = (tid >= d) ? s[tid - d] : 0;
            __syncthreads();
            s[tid] += t;
            __syncthreads();
        }
        int inc = s[tid];
        if (i < n) off[i] = carry + inc - v;   // exclusive prefix
        int tot = s[255];
        __syncthreads();
        if (tid == 0) carry += tot;
        __syncthreads();
    }
    if (tid == 0) off[n] = carry;
}

__global__ __launch_bounds__(256)
void fill_kernel(const int* __restrict__ src, const int* __restrict__ dst, int E,
                 const int* __restrict__ off, int* __restrict__ cur, int* __restrict__ col) {
    int i = blockIdx.x * 256 + threadIdx.x;
    if (i < E) {
        int d = dst[i];
        int p = off[d] + atomicAdd(&cur[d], 1);
        col[p] = src[i];
    }
}

// One wave per destination row; each lane owns 2 columns (float2).
__global__ __launch_bounds__(256)
void agg_mean_kernel(const float* __restrict__ X,
                     const int* __restrict__ off, const int* __restrict__ col,
                     float* __restrict__ Y, int n) {
    int gw   = (blockIdx.x * 256 + threadIdx.x) >> 6;
    int lane = threadIdx.x & 63;
    if (gw >= n) return;
    int e0 = off[gw], e1 = off[gw + 1];
    float ax = 0.f, ay = 0.f;
    for (int e = e0; e < e1; ++e) {
        int s = col[e];
        const float2 v = *(const float2*)&X[(size_t)s * 128 + (lane << 1)];
        ax += v.x; ay += v.y;
    }
    int deg = e1 - e0;
    float inv = 1.0f / (float)(deg > 0 ? deg : 1);
    float2 o; o.x = ax * inv; o.y = ay * inv;
    *(float2*)&Y[(size_t)gw * 128 + (lane << 1)] = o;
}

// W[0]=0.5*cWl, W[1]=0.5*aWl, W[2]=0.5*(cWr+aWr); b=0.5*(cbl+abl)
__global__ __launch_bounds__(256)
void prep_weights_kernel(const float* __restrict__ cWl, const float* __restrict__ cbl,
                         const float* __restrict__ cWr,
                         const float* __restrict__ aWl, const float* __restrict__ abl,
                         const float* __restrict__ aWr,
                         float* __restrict__ W, float* __restrict__ b) {
    int i = blockIdx.x * 256 + threadIdx.x;
    if (i < 16384) {
        W[i]         = 0.5f * cWl[i];
        W[16384 + i] = 0.5f * aWl[i];
        W[32768 + i] = 0.5f * (cWr[i] + aWr[i]);
    }
    if (i < 128) b[i] = 0.5f * (cbl[i] + abl[i]);
}

// Y[i,:] = act( sum_p A_p[i,:] @ W_p^T + bias ), W_p row-major [128 out][128 in].
// Tile: 64 rows x 128 cols per block (256 thr). Thread: 8 rows x 4 cols.
template <int PAIRS, bool RELU>
__global__ __launch_bounds__(256)
void transform_kernel(const float* __restrict__ A0, const float* __restrict__ A1,
                      const float* __restrict__ A2,
                      const float* __restrict__ W0, const float* __restrict__ W1p,
                      const float* __restrict__ W2p,
                      const float* __restrict__ bias, float* __restrict__ Y, int N) {
    __shared__ float As[64][36];     // +4 pad: conflict-free staging stores
    __shared__ float Ws[128 * 32];   // XOR-swizzled rows
    const int tid = threadIdx.x;
    const int jg  = tid & 31;        // col group: cols jg*4 .. +3
    const int rg  = tid >> 5;        // row group: rows rg*8 .. +7
    const int r0  = blockIdx.x * 64;

    float acc[8][4];
#pragma unroll
    for (int r = 0; r < 8; ++r)
#pragma unroll
        for (int c = 0; c < 4; ++c) acc[r][c] = 0.f;

    const float* Ap[3] = {A0, A1, A2};
    const float* Wp[3] = {W0, W1p, W2p};
#pragma unroll
    for (int p = 0; p < PAIRS; ++p) {
        const float* __restrict__ A  = Ap[p];
        const float* __restrict__ Wm = Wp[p];
#pragma unroll
        for (int kc = 0; kc < 4; ++kc) {
            // stage A tile: 64x32 f32 (512 float4, 2 per thread)
#pragma unroll
            for (int q = 0; q < 2; ++q) {
                int f4 = tid + q * 256;
                int rr = f4 >> 3;
                int kk = (f4 & 7) << 2;
                int row = r0 + rr;
                float4 v = make_float4(0.f, 0.f, 0.f, 0.f);
                if (row < N) v = *(const float4*)&A[(size_t)row * 128 + kc * 32 + kk];
                *(float4*)&As[rr][kk] = v;
            }
            // stage W tile: 128x32 f32, slot-XOR-swizzled within each row
#pragma unroll
            for (int q = 0; q < 4; ++q) {
                int f4 = tid + q * 256;
                int jj = f4 >> 3;
                int k4 = f4 & 7;
                float4 v = *(const float4*)&Wm[(size_t)jj * 128 + kc * 32 + (k4 << 2)];
                int slot = k4 ^ ((jj >> 2) & 7);
                *(float4*)&Ws[(jj << 5) + (slot << 2)] = v;
            }
            __syncthreads();
#pragma unroll
            for (int k4 = 0; k4 < 8; ++k4) {
                float4 a[8];
#pragma unroll
                for (int r = 0; r < 8; ++r)
                    a[r] = *(const float4*)&As[(rg << 3) + r][k4 << 2];
#pragma unroll
                for (int c = 0; c < 4; ++c) {
                    const int j = (jg << 2) + c;
                    const int slot = k4 ^ (jg & 7);  // (j>>2)&7 == jg&7
                    float4 w = *(const float4*)&Ws[(j << 5) + (slot << 2)];
#pragma unroll
                    for (int r = 0; r < 8; ++r)
                        acc[r][c] += a[r].x * w.x + a[r].y * w.y + a[r].z * w.z + a[r].w * w.w;
                }
            }
            __syncthreads();
        }
    }
    float4 bv = *(const float4*)&bias[jg << 2];
#pragma unroll
    for (int r = 0; r < 8; ++r) {
        int row = r0 + (rg << 3) + r;
        if (row < N) {
            float4 o;
            o.x = acc[r][0] + bv.x; o.y = acc[r][1] + bv.y;
            o.z = acc[r][2] + bv.z; o.w = acc[r][3] + bv.w;
            if (RELU) {
                o.x = fmaxf(o.x, 0.f); o.y = fmaxf(o.y, 0.f);
                o.z = fmaxf(o.z, 0.f); o.w = fmaxf(o.w, 0.f);
            }
            *(float4*)&Y[(size_t)row * 128 + (jg << 2)] = o;
        }
    }
}

__global__ __launch_bounds__(256)
void final_linear_kernel(const float* __restrict__ P, const float* __restrict__ Wt,
                         const float* __restrict__ bb, float* __restrict__ out, int N) {
    __shared__ float lw[1024];
    __shared__ float lb[8];
    for (int i = threadIdx.x; i < 1024; i += 256) lw[i] = Wt[i];
    if (threadIdx.x < 8) lb[threadIdx.x] = bb[threadIdx.x];
    __syncthreads();
    int idx = blockIdx.x * 256 + threadIdx.x;
    if (idx >= N * 8) return;
    int row = idx >> 3, c = idx & 7;
    const float* pr = &P[(size_t)row * 128];
    const float* wr = &lw[c << 7];
    float s = 0.f;
#pragma unroll
    for (int k = 0; k < 128; k += 4) {
        float4 pv = *(const float4*)&pr[k];
        float4 wv = *(const float4*)&wr[k];
        s += pv.x * wv.x + pv.y * wv.y + pv.z * wv.z + pv.w * wv.w;
    }
    out[idx] = s + lb[c];
}

extern "C" void kernel_launch(void* const* d_in, const int* in_sizes, int n_in,
                              void* d_out, int out_size, void* d_ws, size_t ws_size,
                              hipStream_t stream) {
    const float* x_p = (const float*)d_in[0];
    const float* x_a = (const float*)d_in[1];
    const int* c_src = (const int*)d_in[2];
    const int* c_dst = (const int*)d_in[3];
    const int* a_src = (const int*)d_in[4];
    const int* a_dst = (const int*)d_in[5];
    const int* h_src = (const int*)d_in[6];
    const int* h_dst = (const int*)d_in[7];
    const float* l1c_Wl = (const float*)d_in[8];
    const float* l1c_bl = (const float*)d_in[9];
    const float* l1c_Wr = (const float*)d_in[10];
    const float* l1a_Wl = (const float*)d_in[11];
    const float* l1a_bl = (const float*)d_in[12];
    const float* l1a_Wr = (const float*)d_in[13];
    const float* l1h_Wl = (const float*)d_in[14];
    const float* l1h_bl = (const float*)d_in[15];
    const float* l1h_Wr = (const float*)d_in[16];
    const float* l2c_Wl = (const float*)d_in[17];
    const float* l2c_bl = (const float*)d_in[18];
    const float* l2c_Wr = (const float*)d_in[19];
    const float* l2a_Wl = (const float*)d_in[20];
    const float* l2a_bl = (const float*)d_in[21];
    const float* l2a_Wr = (const float*)d_in[22];
    const float* linW   = (const float*)d_in[26];
    const float* linb   = (const float*)d_in[27];

    const int NP = in_sizes[0] / 128;
    const int NA = in_sizes[1] / 128;
    const int Ec = in_sizes[2];
    const int Ea = in_sizes[4];
    const int Eh = in_sizes[6];

    // ---- carve workspace ----
    char* base = (char*)d_ws;
    size_t cur = 0;
    auto carve = [&](size_t bytes) -> char* {
        char* p = base + cur;
        cur = (cur + bytes + 255) & ~(size_t)255;
        return p;
    };
    float* S1 = (float*)carve((size_t)NP * 128 * 4);   // agg_c1 -> p1 (in place)
    float* S2 = (float*)carve((size_t)NP * 128 * 4);   // agg_a1 -> agg_c2 -> p2 (in place)
    float* S3 = (float*)carve((size_t)NP * 128 * 4);   // agg_a2
    float* SH = (float*)carve((size_t)NA * 128 * 4);   // agg_h1 -> a1 (in place)
    float* W1 = (float*)carve(3 * 16384 * 4);
    float* b1 = (float*)carve(512);
    float* W2 = (float*)carve(3 * 16384 * 4);
    float* b2 = (float*)carve(512);
    int* off_c = (int*)carve((size_t)(NP + 1) * 4);
    int* off_a = (int*)carve((size_t)(NP + 1) * 4);
    int* off_h = (int*)carve((size_t)(NA + 1) * 4);
    int* col_c = (int*)carve((size_t)Ec * 4);
    int* col_a = (int*)carve((size_t)Ea * 4);
    int* col_h = (int*)carve((size_t)Eh * 4);
    char* cntBase = base + cur;
    int* cnt_c = (int*)carve((size_t)NP * 4);
    int* cnt_a = (int*)carve((size_t)NP * 4);
    int* cnt_h = (int*)carve((size_t)NA * 4);
    size_t cntBytes = (size_t)((base + cur) - cntBase);
    if (cur > ws_size) return;  // insufficient workspace -> loud failure

    // ---- CSR build (reused by both layers) ----
    hipMemsetAsync(cntBase, 0, cntBytes, stream);
    hist_kernel<<<(Ec + 255) / 256, 256, 0, stream>>>(c_dst, Ec, cnt_c);
    hist_kernel<<<(Ea + 255) / 256, 256, 0, stream>>>(a_dst, Ea, cnt_a);
    hist_kernel<<<(Eh + 255) / 256, 256, 0, stream>>>(h_dst, Eh, cnt_h);
    scan3_kernel<<<3, 256, 0, stream>>>(cnt_c, off_c, NP, cnt_a, off_a, NP, cnt_h, off_h, NA);
    hipMemsetAsync(cntBase, 0, cntBytes, stream);
    fill_kernel<<<(Ec + 255) / 256, 256, 0, stream>>>(c_src, c_dst, Ec, off_c, cnt_c, col_c);
    fill_kernel<<<(Ea + 255) / 256, 256, 0, stream>>>(a_src, a_dst, Ea, off_a, cnt_a, col_a);
    fill_kernel<<<(Eh + 255) / 256, 256, 0, stream>>>(h_src, h_dst, Eh, off_h, cnt_h, col_h);

    // ---- combined weights for the fused 0.5*(c + a) transforms ----
    prep_weights_kernel<<<64, 256, 0, stream>>>(l1c_Wl, l1c_bl, l1c_Wr,
                                                l1a_Wl, l1a_bl, l1a_Wr, W1, b1);
    prep_weights_kernel<<<64, 256, 0, stream>>>(l2c_Wl, l2c_bl, l2c_Wr,
                                                l2a_Wl, l2a_bl, l2a_Wr, W2, b2);

    // ---- layer 1 ----
    agg_mean_kernel<<<(NP + 3) / 4, 256, 0, stream>>>(x_p, off_c, col_c, S1, NP);
    agg_mean_kernel<<<(NP + 3) / 4, 256, 0, stream>>>(x_a, off_a, col_a, S2, NP);
    agg_mean_kernel<<<(NA + 3) / 4, 256, 0, stream>>>(x_p, off_h, col_h, SH, NA);
    transform_kernel<3, true><<<(NP + 63) / 64, 256, 0, stream>>>(
        S1, S2, x_p, W1, W1 + 16384, W1 + 32768, b1, S1, NP);            // p1 (in place)
    transform_kernel<2, true><<<(NA + 63) / 64, 256, 0, stream>>>(
        SH, x_a, nullptr, l1h_Wl, l1h_Wr, nullptr, l1h_bl, SH, NA);      // a1 (in place)

    // ---- layer 2 ----
    agg_mean_kernel<<<(NP + 3) / 4, 256, 0, stream>>>(S1, off_c, col_c, S2, NP);
    agg_mean_kernel<<<(NP + 3) / 4, 256, 0, stream>>>(SH, off_a, col_a, S3, NP);
    transform_kernel<3, true><<<(NP + 63) / 64, 256, 0, stream>>>(
        S2, S3, S1, W2, W2 + 16384, W2 + 32768, b2, S2, NP);             // p2 (in place)

    // ---- head ----
    final_linear_kernel<<<((NP * 8) + 255) / 256, 256, 0, stream>>>(
        S2, linW, linb, (float*)d_out, NP);
}

// Round 2
// 1512.330 us; speedup vs baseline: 12.0694x; 12.0694x over previous
//
#include <hip/hip_runtime.h>
#include <hip/hip_bf16.h>
#include <cstdint>

// ---------------------------------------------------------------------------
// FullHeteroGCN: 2-layer hetero GraphSAGE (mean aggr), f32.
//   1. build CSR per relation (hist -> scan -> fill)     [reused across layers]
//   2. prep combined/scaled weights for the 3-pair transforms
//   3. layer1: agg x3, transform p1 (3-pair), transform a1 (2-pair)
//   4. layer2: agg x2 (from p1/a1), transform p2 (3-pair)
//   5. final 128->8 linear head
// Round 2: transform staging via global_load_lds (no staging VGPRs -> no
// spill; R1 spilled: VGPR=256, 5.4 GB scratch FETCH per dispatch), aligned
// LDS tiles, W swizzled via pre-swizzled global source addresses.
// ---------------------------------------------------------------------------

__device__ __forceinline__ void gload_lds16(const void* g, void* l) {
    __builtin_amdgcn_global_load_lds(
        (const __attribute__((address_space(1))) unsigned int*)g,
        (__attribute__((address_space(3))) unsigned int*)l,
        16, 0, 0);
}

__global__ __launch_bounds__(256)
void hist_kernel(const int* __restrict__ dst, int E, int* __restrict__ cnt) {
    int i = blockIdx.x * 256 + threadIdx.x;
    if (i < E) atomicAdd(&cnt[dst[i]], 1);
}

// One block per relation: sequential-chunk exclusive scan (256-wide Hillis-Steele).
__global__ __launch_bounds__(256)
void scan3_kernel(const int* c0, int* o0, int n0,
                  const int* c1, int* o1, int n1,
                  const int* c2, int* o2, int n2) {
    const int* cnt; int* off; int n;
    if (blockIdx.x == 0)      { cnt = c0; off = o0; n = n0; }
    else if (blockIdx.x == 1) { cnt = c1; off = o1; n = n1; }
    else                      { cnt = c2; off = o2; n = n2; }
    __shared__ int s[256];
    __shared__ int carry;
    const int tid = threadIdx.x;
    if (tid == 0) carry = 0;
    __syncthreads();
    for (int base = 0; base < n; base += 256) {
        int i = base + tid;
        int v = (i < n) ? cnt[i] : 0;
        s[tid] = v;
        __syncthreads();
        for (int d = 1; d < 256; d <<= 1) {
            int t = (tid >= d) ? s[tid - d] : 0;
            __syncthreads();
            s[tid] += t;
            __syncthreads();
        }
        int inc = s[tid];
        if (i < n) off[i] = carry + inc - v;   // exclusive prefix
        int tot = s[255];
        __syncthreads();
        if (tid == 0) carry += tot;
        __syncthreads();
    }
    if (tid == 0) off[n] = carry;
}

__global__ __launch_bounds__(256)
void fill_kernel(const int* __restrict__ src, const int* __restrict__ dst, int E,
                 const int* __restrict__ off, int* __restrict__ cur, int* __restrict__ col) {
    int i = blockIdx.x * 256 + threadIdx.x;
    if (i < E) {
        int d = dst[i];
        int p = off[d] + atomicAdd(&cur[d], 1);
        col[p] = src[i];
    }
}

// One wave per destination row; each lane owns 2 columns (float2).
__global__ __launch_bounds__(256)
void agg_mean_kernel(const float* __restrict__ X,
                     const int* __restrict__ off, const int* __restrict__ col,
                     float* __restrict__ Y, int n) {
    int gw   = (blockIdx.x * 256 + threadIdx.x) >> 6;
    int lane = threadIdx.x & 63;
    if (gw >= n) return;
    int e0 = off[gw], e1 = off[gw + 1];
    float ax = 0.f, ay = 0.f;
    for (int e = e0; e < e1; ++e) {
        int s = col[e];
        const float2 v = *(const float2*)&X[(size_t)s * 128 + (lane << 1)];
        ax += v.x; ay += v.y;
    }
    int deg = e1 - e0;
    float inv = 1.0f / (float)(deg > 0 ? deg : 1);
    float2 o; o.x = ax * inv; o.y = ay * inv;
    *(float2*)&Y[(size_t)gw * 128 + (lane << 1)] = o;
}

// W[0]=0.5*cWl, W[1]=0.5*aWl, W[2]=0.5*(cWr+aWr); b=0.5*(cbl+abl)
__global__ __launch_bounds__(256)
void prep_weights_kernel(const float* __restrict__ cWl, const float* __restrict__ cbl,
                         const float* __restrict__ cWr,
                         const float* __restrict__ aWl, const float* __restrict__ abl,
                         const float* __restrict__ aWr,
                         float* __restrict__ W, float* __restrict__ b) {
    int i = blockIdx.x * 256 + threadIdx.x;
    if (i < 16384) {
        W[i]         = 0.5f * cWl[i];
        W[16384 + i] = 0.5f * aWl[i];
        W[32768 + i] = 0.5f * (cWr[i] + aWr[i]);
    }
    if (i < 128) b[i] = 0.5f * (cbl[i] + abl[i]);
}

// Y[i,:] = act( sum_p A_p[i,:] @ W_p^T + bias ), W_p row-major [128 out][128 in].
// Tile: 64 rows x 128 cols per block (256 thr). Thread: 8 rows x 4 cols.
// Staging: global_load_lds only (zero staging VGPRs). A tile linear (reads are
// jg-broadcast -> conflict-free); W tile slot-XOR-swizzled via pre-swizzled
// global source addresses (linear DMA dest + matching swizzled ds_read).
template <int PAIRS, bool RELU>
__global__ __launch_bounds__(256)
void transform_kernel(const float* A0, const float* A1, const float* A2,
                      const float* __restrict__ W0, const float* __restrict__ W1p,
                      const float* __restrict__ W2p,
                      const float* __restrict__ bias, float* Y, int N) {
    __shared__ float As[64 * 32];    //  8 KB: [row][k4*4+e], linear
    __shared__ float Ws[128 * 32];   // 16 KB: slot s=j*8+(k4^((j>>2)&7))
    const int tid  = threadIdx.x;
    const int lane = tid & 63;
    const int wv   = tid >> 6;       // wave 0..3
    const int jg   = tid & 31;       // col group: cols jg*4..+3
    const int rg   = tid >> 5;       // row group: rows rg*8..+7
    const int r0   = blockIdx.x * 64;

    float acc[8][4];
#pragma unroll
    for (int r = 0; r < 8; ++r)
#pragma unroll
        for (int c = 0; c < 4; ++c) acc[r][c] = 0.f;

#pragma unroll
    for (int p = 0; p < PAIRS; ++p) {
        const float* A  = (p == 0) ? A0 : (p == 1) ? A1 : A2;
        const float* Wm = (p == 0) ? W0 : (p == 1) ? W1p : W2p;
#pragma unroll 1
        for (int kc = 0; kc < 4; ++kc) {
            // ---- stage A tile 64x32: 8 wave-issues of 1 KB (2 per wave) ----
#pragma unroll
            for (int q = 0; q < 2; ++q) {
                const int chunk = wv * 2 + q;              // 0..7
                const int rr    = chunk * 8 + (lane >> 3); // 0..63
                const int f4    = lane & 7;
                int row = r0 + rr;
                if (row >= N) row = N - 1;                 // clamp (last block only)
                gload_lds16(A + (size_t)row * 128 + kc * 32 + (f4 << 2),
                            As + chunk * 256);
            }
            // ---- stage W tile 128x32 swizzled: 16 wave-issues (4 per wave) ----
#pragma unroll
            for (int q = 0; q < 4; ++q) {
                const int s   = (wv * 4 + q) * 64 + lane;  // physical f4 slot 0..1023
                const int jj  = s >> 3;
                const int k4  = (s & 7) ^ ((jj >> 2) & 7); // inverse swizzle on source
                gload_lds16(Wm + (size_t)jj * 128 + kc * 32 + (k4 << 2),
                            Ws + ((wv * 4 + q) << 8));
            }
            __syncthreads();
            // ---- compute: 8 k4-steps ----
#pragma unroll
            for (int k4 = 0; k4 < 8; ++k4) {
                float4 a[8];
#pragma unroll
                for (int r = 0; r < 8; ++r)
                    a[r] = *(const float4*)&As[((rg << 3) + r) * 32 + (k4 << 2)];
#pragma unroll
                for (int c = 0; c < 4; ++c) {
                    const int slot = (((jg << 2) + c) << 3) + (k4 ^ (jg & 7));
                    float4 w = *(const float4*)&Ws[slot << 2];
#pragma unroll
                    for (int r = 0; r < 8; ++r)
                        acc[r][c] += a[r].x * w.x + a[r].y * w.y
                                   + a[r].z * w.z + a[r].w * w.w;
                }
            }
            __syncthreads();
        }
    }
    float4 bv = *(const float4*)&bias[jg << 2];
#pragma unroll
    for (int r = 0; r < 8; ++r) {
        int row = r0 + (rg << 3) + r;
        if (row < N) {
            float4 o;
            o.x = acc[r][0] + bv.x; o.y = acc[r][1] + bv.y;
            o.z = acc[r][2] + bv.z; o.w = acc[r][3] + bv.w;
            if (RELU) {
                o.x = fmaxf(o.x, 0.f); o.y = fmaxf(o.y, 0.f);
                o.z = fmaxf(o.z, 0.f); o.w = fmaxf(o.w, 0.f);
            }
            *(float4*)&Y[(size_t)row * 128 + (jg << 2)] = o;
        }
    }
}

__global__ __launch_bounds__(256)
void final_linear_kernel(const float* __restrict__ P, const float* __restrict__ Wt,
                         const float* __restrict__ bb, float* __restrict__ out, int N) {
    __shared__ float lw[1024];
    __shared__ float lb[8];
    for (int i = threadIdx.x; i < 1024; i += 256) lw[i] = Wt[i];
    if (threadIdx.x < 8) lb[threadIdx.x] = bb[threadIdx.x];
    __syncthreads();
    int idx = blockIdx.x * 256 + threadIdx.x;
    if (idx >= N * 8) return;
    int row = idx >> 3, c = idx & 7;
    const float* pr = &P[(size_t)row * 128];
    const float* wr = &lw[c << 7];
    float s = 0.f;
#pragma unroll
    for (int k = 0; k < 128; k += 4) {
        float4 pv = *(const float4*)&pr[k];
        float4 wv = *(const float4*)&wr[k];
        s += pv.x * wv.x + pv.y * wv.y + pv.z * wv.z + pv.w * wv.w;
    }
    out[idx] = s + lb[c];
}

extern "C" void kernel_launch(void* const* d_in, const int* in_sizes, int n_in,
                              void* d_out, int out_size, void* d_ws, size_t ws_size,
                              hipStream_t stream) {
    const float* x_p = (const float*)d_in[0];
    const float* x_a = (const float*)d_in[1];
    const int* c_src = (const int*)d_in[2];
    const int* c_dst = (const int*)d_in[3];
    const int* a_src = (const int*)d_in[4];
    const int* a_dst = (const int*)d_in[5];
    const int* h_src = (const int*)d_in[6];
    const int* h_dst = (const int*)d_in[7];
    const float* l1c_Wl = (const float*)d_in[8];
    const float* l1c_bl = (const float*)d_in[9];
    const float* l1c_Wr = (const float*)d_in[10];
    const float* l1a_Wl = (const float*)d_in[11];
    const float* l1a_bl = (const float*)d_in[12];
    const float* l1a_Wr = (const float*)d_in[13];
    const float* l1h_Wl = (const float*)d_in[14];
    const float* l1h_bl = (const float*)d_in[15];
    const float* l1h_Wr = (const float*)d_in[16];
    const float* l2c_Wl = (const float*)d_in[17];
    const float* l2c_bl = (const float*)d_in[18];
    const float* l2c_Wr = (const float*)d_in[19];
    const float* l2a_Wl = (const float*)d_in[20];
    const float* l2a_bl = (const float*)d_in[21];
    const float* l2a_Wr = (const float*)d_in[22];
    const float* linW   = (const float*)d_in[26];
    const float* linb   = (const float*)d_in[27];

    const int NP = in_sizes[0] / 128;
    const int NA = in_sizes[1] / 128;
    const int Ec = in_sizes[2];
    const int Ea = in_sizes[4];
    const int Eh = in_sizes[6];

    // ---- carve workspace ----
    char* base = (char*)d_ws;
    size_t cur = 0;
    auto carve = [&](size_t bytes) -> char* {
        char* p = base + cur;
        cur = (cur + bytes + 255) & ~(size_t)255;
        return p;
    };
    float* S1 = (float*)carve((size_t)NP * 128 * 4);   // agg_c1 -> p1 (in place)
    float* S2 = (float*)carve((size_t)NP * 128 * 4);   // agg_a1 -> agg_c2 -> p2 (in place)
    float* S3 = (float*)carve((size_t)NP * 128 * 4);   // agg_a2
    float* SH = (float*)carve((size_t)NA * 128 * 4);   // agg_h1 -> a1 (in place)
    float* W1 = (float*)carve(3 * 16384 * 4);
    float* b1 = (float*)carve(512);
    float* W2 = (float*)carve(3 * 16384 * 4);
    float* b2 = (float*)carve(512);
    int* off_c = (int*)carve((size_t)(NP + 1) * 4);
    int* off_a = (int*)carve((size_t)(NP + 1) * 4);
    int* off_h = (int*)carve((size_t)(NA + 1) * 4);
    int* col_c = (int*)carve((size_t)Ec * 4);
    int* col_a = (int*)carve((size_t)Ea * 4);
    int* col_h = (int*)carve((size_t)Eh * 4);
    char* cntBase = base + cur;
    int* cnt_c = (int*)carve((size_t)NP * 4);
    int* cnt_a = (int*)carve((size_t)NP * 4);
    int* cnt_h = (int*)carve((size_t)NA * 4);
    size_t cntBytes = (size_t)((base + cur) - cntBase);
    if (cur > ws_size) return;  // insufficient workspace -> loud failure

    // ---- CSR build (reused by both layers) ----
    hipMemsetAsync(cntBase, 0, cntBytes, stream);
    hist_kernel<<<(Ec + 255) / 256, 256, 0, stream>>>(c_dst, Ec, cnt_c);
    hist_kernel<<<(Ea + 255) / 256, 256, 0, stream>>>(a_dst, Ea, cnt_a);
    hist_kernel<<<(Eh + 255) / 256, 256, 0, stream>>>(h_dst, Eh, cnt_h);
    scan3_kernel<<<3, 256, 0, stream>>>(cnt_c, off_c, NP, cnt_a, off_a, NP, cnt_h, off_h, NA);
    hipMemsetAsync(cntBase, 0, cntBytes, stream);
    fill_kernel<<<(Ec + 255) / 256, 256, 0, stream>>>(c_src, c_dst, Ec, off_c, cnt_c, col_c);
    fill_kernel<<<(Ea + 255) / 256, 256, 0, stream>>>(a_src, a_dst, Ea, off_a, cnt_a, col_a);
    fill_kernel<<<(Eh + 255) / 256, 256, 0, stream>>>(h_src, h_dst, Eh, off_h, cnt_h, col_h);

    // ---- combined weights for the fused 0.5*(c + a) transforms ----
    prep_weights_kernel<<<64, 256, 0, stream>>>(l1c_Wl, l1c_bl, l1c_Wr,
                                                l1a_Wl, l1a_bl, l1a_Wr, W1, b1);
    prep_weights_kernel<<<64, 256, 0, stream>>>(l2c_Wl, l2c_bl, l2c_Wr,
                                                l2a_Wl, l2a_bl, l2a_Wr, W2, b2);

    // ---- layer 1 ----
    agg_mean_kernel<<<(NP + 3) / 4, 256, 0, stream>>>(x_p, off_c, col_c, S1, NP);
    agg_mean_kernel<<<(NP + 3) / 4, 256, 0, stream>>>(x_a, off_a, col_a, S2, NP);
    agg_mean_kernel<<<(NA + 3) / 4, 256, 0, stream>>>(x_p, off_h, col_h, SH, NA);
    transform_kernel<3, true><<<(NP + 63) / 64, 256, 0, stream>>>(
        S1, S2, x_p, W1, W1 + 16384, W1 + 32768, b1, S1, NP);            // p1 (in place)
    transform_kernel<2, true><<<(NA + 63) / 64, 256, 0, stream>>>(
        SH, x_a, nullptr, l1h_Wl, l1h_Wr, nullptr, l1h_bl, SH, NA);      // a1 (in place)

    // ---- layer 2 ----
    agg_mean_kernel<<<(NP + 3) / 4, 256, 0, stream>>>(S1, off_c, col_c, S2, NP);
    agg_mean_kernel<<<(NP + 3) / 4, 256, 0, stream>>>(SH, off_a, col_a, S3, NP);
    transform_kernel<3, true><<<(NP + 63) / 64, 256, 0, stream>>>(
        S2, S3, S1, W2, W2 + 16384, W2 + 32768, b2, S2, NP);             // p2 (in place)

    // ---- head ----
    final_linear_kernel<<<((NP * 8) + 255) / 256, 256, 0, stream>>>(
        S2, linW, linb, (float*)d_out, NP);
}

// Round 3
// 983.531 us; speedup vs baseline: 18.5585x; 1.5377x over previous
//
#include <hip/hip_runtime.h>
#include <hip/hip_bf16.h>
#include <cstdint>

// ---------------------------------------------------------------------------
// FullHeteroGCN: 2-layer hetero GraphSAGE (mean aggr), f32.
//   1. build CSR per relation (hist -> 3-kernel multiblock scan -> fill)
//   2. prep combined/scaled weights for the 3-pair transforms
//   3. layer1: agg x3, transform p1 (3-pair), transform a1 (2-pair)
//   4. layer2: agg x2 (from p1/a1), transform p2 (3-pair)
//   5. final 128->8 linear head
// R3: replace 430us 3-block serial scan with multiblock scan (~20us);
//     unroll agg gather x4 (4 row-loads in flight per wave).
// ---------------------------------------------------------------------------

__device__ __forceinline__ void gload_lds16(const void* g, void* l) {
    __builtin_amdgcn_global_load_lds(
        (const __attribute__((address_space(1))) unsigned int*)g,
        (__attribute__((address_space(3))) unsigned int*)l,
        16, 0, 0);
}

__global__ __launch_bounds__(256)
void hist_kernel(const int* __restrict__ dst, int E, int* __restrict__ cnt) {
    int i = blockIdx.x * 256 + threadIdx.x;
    if (i < E) atomicAdd(&cnt[dst[i]], 1);
}

// ---- multiblock exclusive scan over 3 relations, 1024 elems/block ----
__global__ __launch_bounds__(256)
void scan_bsum_kernel(const int* c0, int n0, int nb0,
                      const int* c1, int n1, int nb1,
                      const int* c2, int n2, int nb2, int* __restrict__ bsum) {
    int b = blockIdx.x;
    const int* cnt; int n; int lb;
    if (b < nb0)            { cnt = c0; n = n0; lb = b; }
    else if (b < nb0 + nb1) { cnt = c1; n = n1; lb = b - nb0; }
    else                    { cnt = c2; n = n2; lb = b - nb0 - nb1; }
    const int tid = threadIdx.x;
    const int base = lb * 1024 + tid * 4;
    int s = 0;
    if (base + 4 <= n) {
        int4 v = *(const int4*)&cnt[base];
        s = v.x + v.y + v.z + v.w;
    } else {
        for (int k = 0; k < 4; ++k) if (base + k < n) s += cnt[base + k];
    }
    __shared__ int sm[256];
    sm[tid] = s; __syncthreads();
    for (int d = 128; d > 0; d >>= 1) {
        if (tid < d) sm[tid] += sm[tid + d];
        __syncthreads();
    }
    if (tid == 0) bsum[b] = sm[0];
}

__global__ __launch_bounds__(256)
void scan_spine_kernel(int nb0, int nb1, int nb2, int* __restrict__ bsum,
                       int* o0, int n0, int* o1, int n1, int* o2, int n2) {
    const int r  = blockIdx.x;
    const int sb = (r == 0) ? 0 : (r == 1) ? nb0 : nb0 + nb1;
    const int nb = (r == 0) ? nb0 : (r == 1) ? nb1 : nb2;
    int* off     = (r == 0) ? o0 : (r == 1) ? o1 : o2;
    const int n  = (r == 0) ? n0 : (r == 1) ? n1 : n2;
    const int tid = threadIdx.x;
    int v = (tid < nb) ? bsum[sb + tid] : 0;    // nb <= 256 guaranteed
    __shared__ int sm[256];
    sm[tid] = v; __syncthreads();
    for (int d = 1; d < 256; d <<= 1) {
        int t = (tid >= d) ? sm[tid - d] : 0;
        __syncthreads();
        sm[tid] += t;
        __syncthreads();
    }
    if (tid < nb) bsum[sb + tid] = sm[tid] - v; // exclusive
    if (tid == 0) off[n] = sm[255];             // relation total
}

__global__ __launch_bounds__(256)
void scan_write_kernel(const int* c0, int* o0, int n0, int nb0,
                       const int* c1, int* o1, int n1, int nb1,
                       const int* c2, int* o2, int n2, int nb2,
                       const int* __restrict__ bsum) {
    int b = blockIdx.x;
    const int* cnt; int* off; int n; int lb;
    if (b < nb0)            { cnt = c0; off = o0; n = n0; lb = b; }
    else if (b < nb0 + nb1) { cnt = c1; off = o1; n = n1; lb = b - nb0; }
    else                    { cnt = c2; off = o2; n = n2; lb = b - nb0 - nb1; }
    const int tid = threadIdx.x;
    const int base = lb * 1024 + tid * 4;
    int4 v = make_int4(0, 0, 0, 0);
    if (base + 4 <= n) v = *(const int4*)&cnt[base];
    else {
        if (base + 0 < n) v.x = cnt[base + 0];
        if (base + 1 < n) v.y = cnt[base + 1];
        if (base + 2 < n) v.z = cnt[base + 2];
        if (base + 3 < n) v.w = cnt[base + 3];
    }
    const int s = v.x + v.y + v.z + v.w;
    __shared__ int sm[256];
    sm[tid] = s; __syncthreads();
    for (int d = 1; d < 256; d <<= 1) {
        int t = (tid >= d) ? sm[tid - d] : 0;
        __syncthreads();
        sm[tid] += t;
        __syncthreads();
    }
    const int pre = bsum[b] + sm[tid] - s;
    int4 o;
    o.x = pre; o.y = pre + v.x; o.z = pre + v.x + v.y; o.w = pre + v.x + v.y + v.z;
    if (base + 4 <= n) *(int4*)&off[base] = o;
    else {
        if (base + 0 < n) off[base + 0] = o.x;
        if (base + 1 < n) off[base + 1] = o.y;
        if (base + 2 < n) off[base + 2] = o.z;
        if (base + 3 < n) off[base + 3] = o.w;
    }
}

__global__ __launch_bounds__(256)
void fill_kernel(const int* __restrict__ src, const int* __restrict__ dst, int E,
                 const int* __restrict__ off, int* __restrict__ cur, int* __restrict__ col) {
    int i = blockIdx.x * 256 + threadIdx.x;
    if (i < E) {
        int d = dst[i];
        int p = off[d] + atomicAdd(&cur[d], 1);
        col[p] = src[i];
    }
}

// One wave per destination row; lane owns 2 cols. Unroll x4: 4 gathers in flight.
__global__ __launch_bounds__(256)
void agg_mean_kernel(const float* __restrict__ X,
                     const int* __restrict__ off, const int* __restrict__ col,
                     float* __restrict__ Y, int n) {
    int gw   = (blockIdx.x * 256 + threadIdx.x) >> 6;
    int lane = threadIdx.x & 63;
    if (gw >= n) return;
    const int e0 = off[gw], e1 = off[gw + 1];
    const int lo = lane << 1;
    float ax = 0.f, ay = 0.f, bx = 0.f, by = 0.f;
    float cx = 0.f, cy = 0.f, dx = 0.f, dy = 0.f;
    int e = e0;
    for (; e + 4 <= e1; e += 4) {
        int s0 = col[e], s1 = col[e + 1], s2 = col[e + 2], s3 = col[e + 3];
        float2 v0 = *(const float2*)&X[(size_t)s0 * 128 + lo];
        float2 v1 = *(const float2*)&X[(size_t)s1 * 128 + lo];
        float2 v2 = *(const float2*)&X[(size_t)s2 * 128 + lo];
        float2 v3 = *(const float2*)&X[(size_t)s3 * 128 + lo];
        ax += v0.x; ay += v0.y; bx += v1.x; by += v1.y;
        cx += v2.x; cy += v2.y; dx += v3.x; dy += v3.y;
    }
    for (; e < e1; ++e) {
        int s0 = col[e];
        float2 v = *(const float2*)&X[(size_t)s0 * 128 + lo];
        ax += v.x; ay += v.y;
    }
    ax += bx + cx + dx; ay += by + cy + dy;
    const int deg = e1 - e0;
    const float inv = 1.0f / (float)(deg > 0 ? deg : 1);
    float2 o; o.x = ax * inv; o.y = ay * inv;
    *(float2*)&Y[(size_t)gw * 128 + lo] = o;
}

// W[0]=0.5*cWl, W[1]=0.5*aWl, W[2]=0.5*(cWr+aWr); b=0.5*(cbl+abl)
__global__ __launch_bounds__(256)
void prep_weights_kernel(const float* __restrict__ cWl, const float* __restrict__ cbl,
                         const float* __restrict__ cWr,
                         const float* __restrict__ aWl, const float* __restrict__ abl,
                         const float* __restrict__ aWr,
                         float* __restrict__ W, float* __restrict__ b) {
    int i = blockIdx.x * 256 + threadIdx.x;
    if (i < 16384) {
        W[i]         = 0.5f * cWl[i];
        W[16384 + i] = 0.5f * aWl[i];
        W[32768 + i] = 0.5f * (cWr[i] + aWr[i]);
    }
    if (i < 128) b[i] = 0.5f * (cbl[i] + abl[i]);
}

// Y[i,:] = act( sum_p A_p[i,:] @ W_p^T + bias ), W_p row-major [128 out][128 in].
// Tile: 64 rows x 128 cols per block (256 thr). Thread: 8 rows x 4 cols.
// Staging via global_load_lds only (zero staging VGPRs); W slot-XOR-swizzled
// via pre-swizzled global source addresses.
template <int PAIRS, bool RELU>
__global__ __launch_bounds__(256)
void transform_kernel(const float* A0, const float* A1, const float* A2,
                      const float* __restrict__ W0, const float* __restrict__ W1p,
                      const float* __restrict__ W2p,
                      const float* __restrict__ bias, float* Y, int N) {
    __shared__ float As[64 * 32];    //  8 KB: [row][k4*4+e], linear
    __shared__ float Ws[128 * 32];   // 16 KB: slot s=j*8+(k4^((j>>2)&7))
    const int tid  = threadIdx.x;
    const int lane = tid & 63;
    const int wv   = tid >> 6;       // wave 0..3
    const int jg   = tid & 31;       // col group: cols jg*4..+3
    const int rg   = tid >> 5;       // row group: rows rg*8..+7
    const int r0   = blockIdx.x * 64;

    float acc[8][4];
#pragma unroll
    for (int r = 0; r < 8; ++r)
#pragma unroll
        for (int c = 0; c < 4; ++c) acc[r][c] = 0.f;

#pragma unroll
    for (int p = 0; p < PAIRS; ++p) {
        const float* A  = (p == 0) ? A0 : (p == 1) ? A1 : A2;
        const float* Wm = (p == 0) ? W0 : (p == 1) ? W1p : W2p;
#pragma unroll 1
        for (int kc = 0; kc < 4; ++kc) {
            // ---- stage A tile 64x32: 8 wave-issues of 1 KB (2 per wave) ----
#pragma unroll
            for (int q = 0; q < 2; ++q) {
                const int chunk = wv * 2 + q;              // 0..7
                const int rr    = chunk * 8 + (lane >> 3); // 0..63
                const int f4    = lane & 7;
                int row = r0 + rr;
                if (row >= N) row = N - 1;                 // clamp (last block only)
                gload_lds16(A + (size_t)row * 128 + kc * 32 + (f4 << 2),
                            As + chunk * 256);
            }
            // ---- stage W tile 128x32 swizzled: 16 wave-issues (4 per wave) ----
#pragma unroll
            for (int q = 0; q < 4; ++q) {
                const int s   = (wv * 4 + q) * 64 + lane;  // physical f4 slot 0..1023
                const int jj  = s >> 3;
                const int k4  = (s & 7) ^ ((jj >> 2) & 7); // inverse swizzle on source
                gload_lds16(Wm + (size_t)jj * 128 + kc * 32 + (k4 << 2),
                            Ws + ((wv * 4 + q) << 8));
            }
            __syncthreads();
            // ---- compute: 8 k4-steps ----
#pragma unroll
            for (int k4 = 0; k4 < 8; ++k4) {
                float4 a[8];
#pragma unroll
                for (int r = 0; r < 8; ++r)
                    a[r] = *(const float4*)&As[((rg << 3) + r) * 32 + (k4 << 2)];
#pragma unroll
                for (int c = 0; c < 4; ++c) {
                    const int slot = (((jg << 2) + c) << 3) + (k4 ^ (jg & 7));
                    float4 w = *(const float4*)&Ws[slot << 2];
#pragma unroll
                    for (int r = 0; r < 8; ++r)
                        acc[r][c] += a[r].x * w.x + a[r].y * w.y
                                   + a[r].z * w.z + a[r].w * w.w;
                }
            }
            __syncthreads();
        }
    }
    float4 bv = *(const float4*)&bias[jg << 2];
#pragma unroll
    for (int r = 0; r < 8; ++r) {
        int row = r0 + (rg << 3) + r;
        if (row < N) {
            float4 o;
            o.x = acc[r][0] + bv.x; o.y = acc[r][1] + bv.y;
            o.z = acc[r][2] + bv.z; o.w = acc[r][3] + bv.w;
            if (RELU) {
                o.x = fmaxf(o.x, 0.f); o.y = fmaxf(o.y, 0.f);
                o.z = fmaxf(o.z, 0.f); o.w = fmaxf(o.w, 0.f);
            }
            *(float4*)&Y[(size_t)row * 128 + (jg << 2)] = o;
        }
    }
}

__global__ __launch_bounds__(256)
void final_linear_kernel(const float* __restrict__ P, const float* __restrict__ Wt,
                         const float* __restrict__ bb, float* __restrict__ out, int N) {
    __shared__ float lw[1024];
    __shared__ float lb[8];
    for (int i = threadIdx.x; i < 1024; i += 256) lw[i] = Wt[i];
    if (threadIdx.x < 8) lb[threadIdx.x] = bb[threadIdx.x];
    __syncthreads();
    int idx = blockIdx.x * 256 + threadIdx.x;
    if (idx >= N * 8) return;
    int row = idx >> 3, c = idx & 7;
    const float* pr = &P[(size_t)row * 128];
    const float* wr = &lw[c << 7];
    float s = 0.f;
#pragma unroll
    for (int k = 0; k < 128; k += 4) {
        float4 pv = *(const float4*)&pr[k];
        float4 wv = *(const float4*)&wr[k];
        s += pv.x * wv.x + pv.y * wv.y + pv.z * wv.z + pv.w * wv.w;
    }
    out[idx] = s + lb[c];
}

extern "C" void kernel_launch(void* const* d_in, const int* in_sizes, int n_in,
                              void* d_out, int out_size, void* d_ws, size_t ws_size,
                              hipStream_t stream) {
    const float* x_p = (const float*)d_in[0];
    const float* x_a = (const float*)d_in[1];
    const int* c_src = (const int*)d_in[2];
    const int* c_dst = (const int*)d_in[3];
    const int* a_src = (const int*)d_in[4];
    const int* a_dst = (const int*)d_in[5];
    const int* h_src = (const int*)d_in[6];
    const int* h_dst = (const int*)d_in[7];
    const float* l1c_Wl = (const float*)d_in[8];
    const float* l1c_bl = (const float*)d_in[9];
    const float* l1c_Wr = (const float*)d_in[10];
    const float* l1a_Wl = (const float*)d_in[11];
    const float* l1a_bl = (const float*)d_in[12];
    const float* l1a_Wr = (const float*)d_in[13];
    const float* l1h_Wl = (const float*)d_in[14];
    const float* l1h_bl = (const float*)d_in[15];
    const float* l1h_Wr = (const float*)d_in[16];
    const float* l2c_Wl = (const float*)d_in[17];
    const float* l2c_bl = (const float*)d_in[18];
    const float* l2c_Wr = (const float*)d_in[19];
    const float* l2a_Wl = (const float*)d_in[20];
    const float* l2a_bl = (const float*)d_in[21];
    const float* l2a_Wr = (const float*)d_in[22];
    const float* linW   = (const float*)d_in[26];
    const float* linb   = (const float*)d_in[27];

    const int NP = in_sizes[0] / 128;
    const int NA = in_sizes[1] / 128;
    const int Ec = in_sizes[2];
    const int Ea = in_sizes[4];
    const int Eh = in_sizes[6];

    // ---- carve workspace ----
    char* base = (char*)d_ws;
    size_t cur = 0;
    auto carve = [&](size_t bytes) -> char* {
        char* p = base + cur;
        cur = (cur + bytes + 255) & ~(size_t)255;
        return p;
    };
    float* S1 = (float*)carve((size_t)NP * 128 * 4);   // agg_c1 -> p1 (in place)
    float* S2 = (float*)carve((size_t)NP * 128 * 4);   // agg_a1 -> agg_c2 -> p2 (in place)
    float* S3 = (float*)carve((size_t)NP * 128 * 4);   // agg_a2
    float* SH = (float*)carve((size_t)NA * 128 * 4);   // agg_h1 -> a1 (in place)
    float* W1 = (float*)carve(3 * 16384 * 4);
    float* b1 = (float*)carve(512);
    float* W2 = (float*)carve(3 * 16384 * 4);
    float* b2 = (float*)carve(512);
    int* off_c = (int*)carve((size_t)(NP + 1) * 4);
    int* off_a = (int*)carve((size_t)(NP + 1) * 4);
    int* off_h = (int*)carve((size_t)(NA + 1) * 4);
    int* col_c = (int*)carve((size_t)Ec * 4);
    int* col_a = (int*)carve((size_t)Ea * 4);
    int* col_h = (int*)carve((size_t)Eh * 4);
    int* bsum  = (int*)carve(4096);
    char* cntBase = base + cur;
    int* cnt_c = (int*)carve((size_t)NP * 4);
    int* cnt_a = (int*)carve((size_t)NP * 4);
    int* cnt_h = (int*)carve((size_t)NA * 4);
    size_t cntBytes = (size_t)((base + cur) - cntBase);
    if (cur > ws_size) return;  // insufficient workspace -> loud failure

    const int nb_c = (NP + 1023) / 1024;
    const int nb_a = (NP + 1023) / 1024;
    const int nb_h = (NA + 1023) / 1024;
    const int nb_tot = nb_c + nb_a + nb_h;   // <= 256 per relation required

    // ---- CSR build (reused by both layers) ----
    hipMemsetAsync(cntBase, 0, cntBytes, stream);
    hist_kernel<<<(Ec + 255) / 256, 256, 0, stream>>>(c_dst, Ec, cnt_c);
    hist_kernel<<<(Ea + 255) / 256, 256, 0, stream>>>(a_dst, Ea, cnt_a);
    hist_kernel<<<(Eh + 255) / 256, 256, 0, stream>>>(h_dst, Eh, cnt_h);
    scan_bsum_kernel<<<nb_tot, 256, 0, stream>>>(cnt_c, NP, nb_c, cnt_a, NP, nb_a,
                                                 cnt_h, NA, nb_h, bsum);
    scan_spine_kernel<<<3, 256, 0, stream>>>(nb_c, nb_a, nb_h, bsum,
                                             off_c, NP, off_a, NP, off_h, NA);
    scan_write_kernel<<<nb_tot, 256, 0, stream>>>(cnt_c, off_c, NP, nb_c,
                                                  cnt_a, off_a, NP, nb_a,
                                                  cnt_h, off_h, NA, nb_h, bsum);
    hipMemsetAsync(cntBase, 0, cntBytes, stream);
    fill_kernel<<<(Ec + 255) / 256, 256, 0, stream>>>(c_src, c_dst, Ec, off_c, cnt_c, col_c);
    fill_kernel<<<(Ea + 255) / 256, 256, 0, stream>>>(a_src, a_dst, Ea, off_a, cnt_a, col_a);
    fill_kernel<<<(Eh + 255) / 256, 256, 0, stream>>>(h_src, h_dst, Eh, off_h, cnt_h, col_h);

    // ---- combined weights for the fused 0.5*(c + a) transforms ----
    prep_weights_kernel<<<64, 256, 0, stream>>>(l1c_Wl, l1c_bl, l1c_Wr,
                                                l1a_Wl, l1a_bl, l1a_Wr, W1, b1);
    prep_weights_kernel<<<64, 256, 0, stream>>>(l2c_Wl, l2c_bl, l2c_Wr,
                                                l2a_Wl, l2a_bl, l2a_Wr, W2, b2);

    // ---- layer 1 ----
    agg_mean_kernel<<<(NP + 3) / 4, 256, 0, stream>>>(x_p, off_c, col_c, S1, NP);
    agg_mean_kernel<<<(NP + 3) / 4, 256, 0, stream>>>(x_a, off_a, col_a, S2, NP);
    agg_mean_kernel<<<(NA + 3) / 4, 256, 0, stream>>>(x_p, off_h, col_h, SH, NA);
    transform_kernel<3, true><<<(NP + 63) / 64, 256, 0, stream>>>(
        S1, S2, x_p, W1, W1 + 16384, W1 + 32768, b1, S1, NP);            // p1 (in place)
    transform_kernel<2, true><<<(NA + 63) / 64, 256, 0, stream>>>(
        SH, x_a, nullptr, l1h_Wl, l1h_Wr, nullptr, l1h_bl, SH, NA);      // a1 (in place)

    // ---- layer 2 ----
    agg_mean_kernel<<<(NP + 3) / 4, 256, 0, stream>>>(S1, off_c, col_c, S2, NP);
    agg_mean_kernel<<<(NP + 3) / 4, 256, 0, stream>>>(SH, off_a, col_a, S3, NP);
    transform_kernel<3, true><<<(NP + 63) / 64, 256, 0, stream>>>(
        S2, S3, S1, W2, W2 + 16384, W2 + 32768, b2, S2, NP);             // p2 (in place)

    // ---- head ----
    final_linear_kernel<<<((NP * 8) + 255) / 256, 256, 0, stream>>>(
        S2, linW, linb, (float*)d_out, NP);
}

// Round 4
// 645.997 us; speedup vs baseline: 28.2554x; 1.5225x over previous
//
#include <hip/hip_runtime.h>
#include <hip/hip_bf16.h>
#include <cstdint>

// ---------------------------------------------------------------------------
// FullHeteroGCN: 2-layer hetero GraphSAGE (mean aggr).
// R4: transforms on MFMA via split-bf16 (hi/lo) — 3 MFMA per logical f32 op.
// All activations stored as interleaved {hi16,lo16} dwords (value =
// asf(d<<16)+asf(d&0xFFFF0000)), same bytes as f32. Transform kernel:
// no LDS, no barriers; 1 wave = 32 output rows x 128 cols.
// ---------------------------------------------------------------------------

typedef __attribute__((ext_vector_type(8))) short bf16x8;
typedef __attribute__((ext_vector_type(4))) float f32x4;

union FU { bf16x8 v; uint32_t u[4]; };

__device__ __forceinline__ uint32_t prm(uint32_t a, uint32_t b, uint32_t s) {
    return __builtin_amdgcn_perm(a, b, s);
}
__device__ __forceinline__ f32x4 mfma16(bf16x8 a, bf16x8 b, f32x4 c) {
    return __builtin_amdgcn_mfma_f32_16x16x32_bf16(a, b, c, 0, 0, 0);
}
// value -> interleaved dword {lo16:hi16}
__device__ __forceinline__ uint32_t pack_hl(float o) {
    uint32_t u = __float_as_uint(o);
    float lo = o - __uint_as_float(u & 0xFFFF0000u);
    return (__float_as_uint(lo) & 0xFFFF0000u) | (u >> 16);
}
__device__ __forceinline__ float unpack_hl(uint32_t d) {
    return __uint_as_float(d << 16) + __uint_as_float(d & 0xFFFF0000u);
}

// 8 interleaved dwords -> hi-frag + lo-frag (8 bf16 each)
__device__ __forceinline__ void unzip_ilv(const uint32_t* ap, FU& ah, FU& al) {
    uint4 q0 = *(const uint4*)ap;
    uint4 q1 = *(const uint4*)(ap + 4);
    ah.u[0] = prm(q0.y, q0.x, 0x05040100u); al.u[0] = prm(q0.y, q0.x, 0x07060302u);
    ah.u[1] = prm(q0.w, q0.z, 0x05040100u); al.u[1] = prm(q0.w, q0.z, 0x07060302u);
    ah.u[2] = prm(q1.y, q1.x, 0x05040100u); al.u[2] = prm(q1.y, q1.x, 0x07060302u);
    ah.u[3] = prm(q1.w, q1.z, 0x05040100u); al.u[3] = prm(q1.w, q1.z, 0x07060302u);
}
// 8 raw f32 dwords -> hi/lo frags (truncation split)
__device__ __forceinline__ void split_raw(const uint32_t* ap, FU& ah, FU& al) {
    uint4 q0 = *(const uint4*)ap;
    uint4 q1 = *(const uint4*)(ap + 4);
    uint32_t e[8] = {q0.x, q0.y, q0.z, q0.w, q1.x, q1.y, q1.z, q1.w};
    uint32_t lo[8];
#pragma unroll
    for (int i = 0; i < 8; ++i)
        lo[i] = __float_as_uint(__uint_as_float(e[i]) -
                                __uint_as_float(e[i] & 0xFFFF0000u));
    ah.u[0] = prm(e[1], e[0], 0x07060302u);  al.u[0] = prm(lo[1], lo[0], 0x07060302u);
    ah.u[1] = prm(e[3], e[2], 0x07060302u);  al.u[1] = prm(lo[3], lo[2], 0x07060302u);
    ah.u[2] = prm(e[5], e[4], 0x07060302u);  al.u[2] = prm(lo[5], lo[4], 0x07060302u);
    ah.u[3] = prm(e[7], e[6], 0x07060302u);  al.u[3] = prm(lo[7], lo[6], 0x07060302u);
}

__global__ __launch_bounds__(256)
void hist_kernel(const int* __restrict__ dst, int E, int* __restrict__ cnt) {
    int i = blockIdx.x * 256 + threadIdx.x;
    if (i < E) atomicAdd(&cnt[dst[i]], 1);
}

// ---- multiblock exclusive scan over 3 relations, 1024 elems/block ----
__global__ __launch_bounds__(256)
void scan_bsum_kernel(const int* c0, int n0, int nb0,
                      const int* c1, int n1, int nb1,
                      const int* c2, int n2, int nb2, int* __restrict__ bsum) {
    int b = blockIdx.x;
    const int* cnt; int n; int lb;
    if (b < nb0)            { cnt = c0; n = n0; lb = b; }
    else if (b < nb0 + nb1) { cnt = c1; n = n1; lb = b - nb0; }
    else                    { cnt = c2; n = n2; lb = b - nb0 - nb1; }
    const int tid = threadIdx.x;
    const int base = lb * 1024 + tid * 4;
    int s = 0;
    if (base + 4 <= n) {
        int4 v = *(const int4*)&cnt[base];
        s = v.x + v.y + v.z + v.w;
    } else {
        for (int k = 0; k < 4; ++k) if (base + k < n) s += cnt[base + k];
    }
    __shared__ int sm[256];
    sm[tid] = s; __syncthreads();
    for (int d = 128; d > 0; d >>= 1) {
        if (tid < d) sm[tid] += sm[tid + d];
        __syncthreads();
    }
    if (tid == 0) bsum[b] = sm[0];
}

__global__ __launch_bounds__(256)
void scan_spine_kernel(int nb0, int nb1, int nb2, int* __restrict__ bsum,
                       int* o0, int n0, int* o1, int n1, int* o2, int n2) {
    const int r  = blockIdx.x;
    const int sb = (r == 0) ? 0 : (r == 1) ? nb0 : nb0 + nb1;
    const int nb = (r == 0) ? nb0 : (r == 1) ? nb1 : nb2;
    int* off     = (r == 0) ? o0 : (r == 1) ? o1 : o2;
    const int n  = (r == 0) ? n0 : (r == 1) ? n1 : n2;
    const int tid = threadIdx.x;
    int v = (tid < nb) ? bsum[sb + tid] : 0;
    __shared__ int sm[256];
    sm[tid] = v; __syncthreads();
    for (int d = 1; d < 256; d <<= 1) {
        int t = (tid >= d) ? sm[tid - d] : 0;
        __syncthreads();
        sm[tid] += t;
        __syncthreads();
    }
    if (tid < nb) bsum[sb + tid] = sm[tid] - v; // exclusive
    if (tid == 0) off[n] = sm[255];
}

__global__ __launch_bounds__(256)
void scan_write_kernel(const int* c0, int* o0, int n0, int nb0,
                       const int* c1, int* o1, int n1, int nb1,
                       const int* c2, int* o2, int n2, int nb2,
                       const int* __restrict__ bsum) {
    int b = blockIdx.x;
    const int* cnt; int* off; int n; int lb;
    if (b < nb0)            { cnt = c0; off = o0; n = n0; lb = b; }
    else if (b < nb0 + nb1) { cnt = c1; off = o1; n = n1; lb = b - nb0; }
    else                    { cnt = c2; off = o2; n = n2; lb = b - nb0 - nb1; }
    const int tid = threadIdx.x;
    const int base = lb * 1024 + tid * 4;
    int4 v = make_int4(0, 0, 0, 0);
    if (base + 4 <= n) v = *(const int4*)&cnt[base];
    else {
        if (base + 0 < n) v.x = cnt[base + 0];
        if (base + 1 < n) v.y = cnt[base + 1];
        if (base + 2 < n) v.z = cnt[base + 2];
        if (base + 3 < n) v.w = cnt[base + 3];
    }
    const int s = v.x + v.y + v.z + v.w;
    __shared__ int sm[256];
    sm[tid] = s; __syncthreads();
    for (int d = 1; d < 256; d <<= 1) {
        int t = (tid >= d) ? sm[tid - d] : 0;
        __syncthreads();
        sm[tid] += t;
        __syncthreads();
    }
    const int pre = bsum[b] + sm[tid] - s;
    int4 o;
    o.x = pre; o.y = pre + v.x; o.z = pre + v.x + v.y; o.w = pre + v.x + v.y + v.z;
    if (base + 4 <= n) *(int4*)&off[base] = o;
    else {
        if (base + 0 < n) off[base + 0] = o.x;
        if (base + 1 < n) off[base + 1] = o.y;
        if (base + 2 < n) off[base + 2] = o.z;
        if (base + 3 < n) off[base + 3] = o.w;
    }
}

__global__ __launch_bounds__(256)
void fill_kernel(const int* __restrict__ src, const int* __restrict__ dst, int E,
                 const int* __restrict__ off, int* __restrict__ cur, int* __restrict__ col) {
    int i = blockIdx.x * 256 + threadIdx.x;
    if (i < E) {
        int d = dst[i];
        int p = off[d] + atomicAdd(&cur[d], 1);
        col[p] = src[i];
    }
}

// One wave per destination row; lane owns 2 cols; 4 gathers in flight.
// ILV: input is interleaved hi/lo; else raw f32. Output always interleaved.
template <bool ILV>
__global__ __launch_bounds__(256)
void agg_mean_kernel(const uint32_t* __restrict__ X,
                     const int* __restrict__ off, const int* __restrict__ col,
                     uint32_t* __restrict__ Y, int n) {
    int gw   = (blockIdx.x * 256 + threadIdx.x) >> 6;
    int lane = threadIdx.x & 63;
    if (gw >= n) return;
    const int e0 = off[gw], e1 = off[gw + 1];
    const int lo2 = lane << 1;
    float a0 = 0.f, a1 = 0.f, b0 = 0.f, b1 = 0.f;
    float c0 = 0.f, c1 = 0.f, d0 = 0.f, d1 = 0.f;
    int e = e0;
    for (; e + 4 <= e1; e += 4) {
        int s0 = col[e], s1 = col[e + 1], s2 = col[e + 2], s3 = col[e + 3];
        if constexpr (ILV) {
            uint2 v0 = *(const uint2*)(X + (size_t)s0 * 128 + lo2);
            uint2 v1 = *(const uint2*)(X + (size_t)s1 * 128 + lo2);
            uint2 v2 = *(const uint2*)(X + (size_t)s2 * 128 + lo2);
            uint2 v3 = *(const uint2*)(X + (size_t)s3 * 128 + lo2);
            a0 += unpack_hl(v0.x); a1 += unpack_hl(v0.y);
            b0 += unpack_hl(v1.x); b1 += unpack_hl(v1.y);
            c0 += unpack_hl(v2.x); c1 += unpack_hl(v2.y);
            d0 += unpack_hl(v3.x); d1 += unpack_hl(v3.y);
        } else {
            float2 v0 = *(const float2*)((const float*)X + (size_t)s0 * 128 + lo2);
            float2 v1 = *(const float2*)((const float*)X + (size_t)s1 * 128 + lo2);
            float2 v2 = *(const float2*)((const float*)X + (size_t)s2 * 128 + lo2);
            float2 v3 = *(const float2*)((const float*)X + (size_t)s3 * 128 + lo2);
            a0 += v0.x; a1 += v0.y; b0 += v1.x; b1 += v1.y;
            c0 += v2.x; c1 += v2.y; d0 += v3.x; d1 += v3.y;
        }
    }
    for (; e < e1; ++e) {
        int s0 = col[e];
        if constexpr (ILV) {
            uint2 v = *(const uint2*)(X + (size_t)s0 * 128 + lo2);
            a0 += unpack_hl(v.x); a1 += unpack_hl(v.y);
        } else {
            float2 v = *(const float2*)((const float*)X + (size_t)s0 * 128 + lo2);
            a0 += v.x; a1 += v.y;
        }
    }
    a0 += b0 + c0 + d0; a1 += b1 + c1 + d1;
    const int deg = e1 - e0;
    const float inv = 1.0f / (float)(deg > 0 ? deg : 1);
    uint2 o; o.x = pack_hl(a0 * inv); o.y = pack_hl(a1 * inv);
    *(uint2*)(Y + (size_t)gw * 128 + lo2) = o;
}

__device__ __forceinline__ void split_store(float w, unsigned short* hi,
                                            unsigned short* lo, int i) {
    uint32_t u = __float_as_uint(w);
    hi[i] = (unsigned short)(u >> 16);
    float l = w - __uint_as_float(u & 0xFFFF0000u);
    lo[i] = (unsigned short)(__float_as_uint(l) >> 16);
}

// W[0]=0.5*cWl, W[1]=0.5*aWl, W[2]=0.5*(cWr+aWr); b=0.5*(cbl+abl); hi/lo bf16
__global__ __launch_bounds__(256)
void prep_w3_kernel(const float* __restrict__ cWl, const float* __restrict__ cbl,
                    const float* __restrict__ cWr,
                    const float* __restrict__ aWl, const float* __restrict__ abl,
                    const float* __restrict__ aWr,
                    unsigned short* __restrict__ Whi, unsigned short* __restrict__ Wlo,
                    float* __restrict__ b) {
    int i = blockIdx.x * 256 + threadIdx.x;
    if (i < 16384) {
        split_store(0.5f * cWl[i], Whi, Wlo, i);
        split_store(0.5f * aWl[i], Whi, Wlo, 16384 + i);
        split_store(0.5f * (cWr[i] + aWr[i]), Whi, Wlo, 32768 + i);
    }
    if (i < 128) b[i] = 0.5f * (cbl[i] + abl[i]);
}

__global__ __launch_bounds__(256)
void prep_w2_kernel(const float* __restrict__ Wl, const float* __restrict__ Wr,
                    unsigned short* __restrict__ Whi, unsigned short* __restrict__ Wlo) {
    int i = blockIdx.x * 256 + threadIdx.x;
    if (i < 16384) {
        split_store(Wl[i], Whi, Wlo, i);
        split_store(Wr[i], Whi, Wlo, 16384 + i);
    }
}

// Y[i,:] = relu( sum_p A_p[i,:] @ W_p^T + bias ): split-bf16 MFMA.
// 1 wave per 32 rows x 128 cols; no LDS, no barriers.
// A/B frag layout (16x16x32): lane l holds row/col (l&15), k=(l>>4)*8..+7.
// C/D layout (m89-verified): col = l&15, row = (l>>4)*4 + reg.
template <int PAIRS, int RAW_LAST>
__global__ __launch_bounds__(64, 3)
void transform_mfma(const uint32_t* A0, const uint32_t* A1, const uint32_t* A2,
                    const unsigned short* __restrict__ Whi,
                    const unsigned short* __restrict__ Wlo,
                    const float* __restrict__ bias, uint32_t* Y, int N) {
    const int l    = threadIdx.x;
    const int lrow = l & 15;
    const int lkg  = l >> 4;
    const int r0   = blockIdx.x * 32;

    f32x4 acc0[8], acc1[8];
#pragma unroll
    for (int t = 0; t < 8; ++t) {
        acc0[t] = (f32x4){0.f, 0.f, 0.f, 0.f};
        acc1[t] = (f32x4){0.f, 0.f, 0.f, 0.f};
    }

    int arow0 = r0 + lrow;      if (arow0 >= N) arow0 = N - 1;
    int arow1 = r0 + 16 + lrow; if (arow1 >= N) arow1 = N - 1;
    const int kbase = lkg << 3;

#pragma unroll
    for (int p = 0; p < PAIRS; ++p) {
        const uint32_t* A = (p == 0) ? A0 : (p == 1) ? A1 : A2;
        const bool raw = RAW_LAST && (p == PAIRS - 1);
#pragma unroll
        for (int kc = 0; kc < 4; ++kc) {
            FU ah0, al0, ah1, al1;
            const uint32_t* ap0 = A + (size_t)arow0 * 128 + kc * 32 + kbase;
            const uint32_t* ap1 = A + (size_t)arow1 * 128 + kc * 32 + kbase;
            if (raw) { split_raw(ap0, ah0, al0); split_raw(ap1, ah1, al1); }
            else     { unzip_ilv(ap0, ah0, al0); unzip_ilv(ap1, ah1, al1); }
#pragma unroll
            for (int t = 0; t < 8; ++t) {
                const int wb = ((p * 128 + t * 16 + lrow) << 7) + kc * 32 + kbase;
                bf16x8 bh = *(const bf16x8*)(Whi + wb);
                bf16x8 bl = *(const bf16x8*)(Wlo + wb);
                acc0[t] = mfma16(ah0.v, bh, acc0[t]);
                acc1[t] = mfma16(ah1.v, bh, acc1[t]);
                acc0[t] = mfma16(ah0.v, bl, acc0[t]);
                acc1[t] = mfma16(ah1.v, bl, acc1[t]);
                acc0[t] = mfma16(al0.v, bh, acc0[t]);
                acc1[t] = mfma16(al1.v, bh, acc1[t]);
            }
        }
    }
#pragma unroll
    for (int t = 0; t < 8; ++t) {
        const int c = t * 16 + lrow;
        const float bv = bias[c];
#pragma unroll
        for (int r = 0; r < 4; ++r) {
            int row0 = r0 + (lkg << 2) + r;
            if (row0 < N)
                Y[(size_t)row0 * 128 + c] = pack_hl(fmaxf(acc0[t][r] + bv, 0.f));
            int row1 = row0 + 16;
            if (row1 < N)
                Y[(size_t)row1 * 128 + c] = pack_hl(fmaxf(acc1[t][r] + bv, 0.f));
        }
    }
}

__global__ __launch_bounds__(256)
void final_linear_kernel(const uint32_t* __restrict__ P, const float* __restrict__ Wt,
                         const float* __restrict__ bb, float* __restrict__ out, int N) {
    __shared__ float lw[1024];
    __shared__ float lb[8];
    for (int i = threadIdx.x; i < 1024; i += 256) lw[i] = Wt[i];
    if (threadIdx.x < 8) lb[threadIdx.x] = bb[threadIdx.x];
    __syncthreads();
    int idx = blockIdx.x * 256 + threadIdx.x;
    if (idx >= N * 8) return;
    int row = idx >> 3, c = idx & 7;
    const uint32_t* pr = P + (size_t)row * 128;
    const float* wr = &lw[c << 7];
    float s = 0.f;
#pragma unroll
    for (int k = 0; k < 128; k += 4) {
        uint4 q = *(const uint4*)(pr + k);
        float4 wv = *(const float4*)&wr[k];
        s += unpack_hl(q.x) * wv.x + unpack_hl(q.y) * wv.y
           + unpack_hl(q.z) * wv.z + unpack_hl(q.w) * wv.w;
    }
    out[idx] = s + lb[c];
}

extern "C" void kernel_launch(void* const* d_in, const int* in_sizes, int n_in,
                              void* d_out, int out_size, void* d_ws, size_t ws_size,
                              hipStream_t stream) {
    const uint32_t* x_p = (const uint32_t*)d_in[0];
    const uint32_t* x_a = (const uint32_t*)d_in[1];
    const int* c_src = (const int*)d_in[2];
    const int* c_dst = (const int*)d_in[3];
    const int* a_src = (const int*)d_in[4];
    const int* a_dst = (const int*)d_in[5];
    const int* h_src = (const int*)d_in[6];
    const int* h_dst = (const int*)d_in[7];
    const float* l1c_Wl = (const float*)d_in[8];
    const float* l1c_bl = (const float*)d_in[9];
    const float* l1c_Wr = (const float*)d_in[10];
    const float* l1a_Wl = (const float*)d_in[11];
    const float* l1a_bl = (const float*)d_in[12];
    const float* l1a_Wr = (const float*)d_in[13];
    const float* l1h_Wl = (const float*)d_in[14];
    const float* l1h_bl = (const float*)d_in[15];
    const float* l1h_Wr = (const float*)d_in[16];
    const float* l2c_Wl = (const float*)d_in[17];
    const float* l2c_bl = (const float*)d_in[18];
    const float* l2c_Wr = (const float*)d_in[19];
    const float* l2a_Wl = (const float*)d_in[20];
    const float* l2a_bl = (const float*)d_in[21];
    const float* l2a_Wr = (const float*)d_in[22];
    const float* linW   = (const float*)d_in[26];
    const float* linb   = (const float*)d_in[27];

    const int NP = in_sizes[0] / 128;
    const int NA = in_sizes[1] / 128;
    const int Ec = in_sizes[2];
    const int Ea = in_sizes[4];
    const int Eh = in_sizes[6];

    // ---- carve workspace ----
    char* base = (char*)d_ws;
    size_t cur = 0;
    auto carve = [&](size_t bytes) -> char* {
        char* p = base + cur;
        cur = (cur + bytes + 255) & ~(size_t)255;
        return p;
    };
    uint32_t* S1 = (uint32_t*)carve((size_t)NP * 128 * 4);  // agg_c1 -> p1 (in place)
    uint32_t* S2 = (uint32_t*)carve((size_t)NP * 128 * 4);  // agg_a1 -> agg_c2 -> p2
    uint32_t* S3 = (uint32_t*)carve((size_t)NP * 128 * 4);  // agg_a2
    uint32_t* SH = (uint32_t*)carve((size_t)NA * 128 * 4);  // agg_h1 -> a1 (in place)
    unsigned short* W1hi = (unsigned short*)carve(3 * 16384 * 2);
    unsigned short* W1lo = (unsigned short*)carve(3 * 16384 * 2);
    unsigned short* W2hi = (unsigned short*)carve(3 * 16384 * 2);
    unsigned short* W2lo = (unsigned short*)carve(3 * 16384 * 2);
    unsigned short* WHhi = (unsigned short*)carve(2 * 16384 * 2);
    unsigned short* WHlo = (unsigned short*)carve(2 * 16384 * 2);
    float* b1 = (float*)carve(512);
    float* b2 = (float*)carve(512);
    int* off_c = (int*)carve((size_t)(NP + 1) * 4);
    int* off_a = (int*)carve((size_t)(NP + 1) * 4);
    int* off_h = (int*)carve((size_t)(NA + 1) * 4);
    int* col_c = (int*)carve((size_t)Ec * 4);
    int* col_a = (int*)carve((size_t)Ea * 4);
    int* col_h = (int*)carve((size_t)Eh * 4);
    int* bsum  = (int*)carve(4096);
    char* cntBase = base + cur;
    int* cnt_c = (int*)carve((size_t)NP * 4);
    int* cnt_a = (int*)carve((size_t)NP * 4);
    int* cnt_h = (int*)carve((size_t)NA * 4);
    size_t cntBytes = (size_t)((base + cur) - cntBase);
    if (cur > ws_size) return;

    const int nb_c = (NP + 1023) / 1024;
    const int nb_a = (NP + 1023) / 1024;
    const int nb_h = (NA + 1023) / 1024;
    const int nb_tot = nb_c + nb_a + nb_h;

    // ---- CSR build (reused by both layers) ----
    hipMemsetAsync(cntBase, 0, cntBytes, stream);
    hist_kernel<<<(Ec + 255) / 256, 256, 0, stream>>>(c_dst, Ec, cnt_c);
    hist_kernel<<<(Ea + 255) / 256, 256, 0, stream>>>(a_dst, Ea, cnt_a);
    hist_kernel<<<(Eh + 255) / 256, 256, 0, stream>>>(h_dst, Eh, cnt_h);
    scan_bsum_kernel<<<nb_tot, 256, 0, stream>>>(cnt_c, NP, nb_c, cnt_a, NP, nb_a,
                                                 cnt_h, NA, nb_h, bsum);
    scan_spine_kernel<<<3, 256, 0, stream>>>(nb_c, nb_a, nb_h, bsum,
                                             off_c, NP, off_a, NP, off_h, NA);
    scan_write_kernel<<<nb_tot, 256, 0, stream>>>(cnt_c, off_c, NP, nb_c,
                                                  cnt_a, off_a, NP, nb_a,
                                                  cnt_h, off_h, NA, nb_h, bsum);
    hipMemsetAsync(cntBase, 0, cntBytes, stream);
    fill_kernel<<<(Ec + 255) / 256, 256, 0, stream>>>(c_src, c_dst, Ec, off_c, cnt_c, col_c);
    fill_kernel<<<(Ea + 255) / 256, 256, 0, stream>>>(a_src, a_dst, Ea, off_a, cnt_a, col_a);
    fill_kernel<<<(Eh + 255) / 256, 256, 0, stream>>>(h_src, h_dst, Eh, off_h, cnt_h, col_h);

    // ---- weights -> split-bf16 hi/lo ----
    prep_w3_kernel<<<64, 256, 0, stream>>>(l1c_Wl, l1c_bl, l1c_Wr,
                                           l1a_Wl, l1a_bl, l1a_Wr, W1hi, W1lo, b1);
    prep_w3_kernel<<<64, 256, 0, stream>>>(l2c_Wl, l2c_bl, l2c_Wr,
                                           l2a_Wl, l2a_bl, l2a_Wr, W2hi, W2lo, b2);
    prep_w2_kernel<<<64, 256, 0, stream>>>(l1h_Wl, l1h_Wr, WHhi, WHlo);

    // ---- layer 1 ----
    agg_mean_kernel<false><<<(NP + 3) / 4, 256, 0, stream>>>(x_p, off_c, col_c, S1, NP);
    agg_mean_kernel<false><<<(NP + 3) / 4, 256, 0, stream>>>(x_a, off_a, col_a, S2, NP);
    agg_mean_kernel<false><<<(NA + 3) / 4, 256, 0, stream>>>(x_p, off_h, col_h, SH, NA);
    transform_mfma<3, 1><<<(NP + 31) / 32, 64, 0, stream>>>(
        S1, S2, x_p, W1hi, W1lo, b1, S1, NP);                 // p1 (in place)
    transform_mfma<2, 1><<<(NA + 31) / 32, 64, 0, stream>>>(
        SH, x_a, nullptr, WHhi, WHlo, l1h_bl, SH, NA);        // a1 (in place)

    // ---- layer 2 ----
    agg_mean_kernel<true><<<(NP + 3) / 4, 256, 0, stream>>>(S1, off_c, col_c, S2, NP);
    agg_mean_kernel<true><<<(NP + 3) / 4, 256, 0, stream>>>(SH, off_a, col_a, S3, NP);
    transform_mfma<3, 0><<<(NP + 31) / 32, 64, 0, stream>>>(
        S2, S3, S1, W2hi, W2lo, b2, S2, NP);                  // p2 (in place)

    // ---- head ----
    final_linear_kernel<<<((NP * 8) + 255) / 256, 256, 0, stream>>>(
        S2, linW, linb, (float*)d_out, NP);
}

// Round 5
// 568.344 us; speedup vs baseline: 32.1159x; 1.1366x over previous
//
#include <hip/hip_runtime.h>
#include <hip/hip_bf16.h>
#include <cstdint>

// ---------------------------------------------------------------------------
// FullHeteroGCN: 2-layer hetero GraphSAGE (mean aggr).
// R5: transform = 4-wave/128-row blocks, W(p) hi/lo staged per-block into
// XOR-swizzled LDS (pre-swizzled global source for global_load_lds), B-frags
// via conflict-free ds_read_b128. R4 was latency-bound (MfmaUtil 8%,
// VALUBusy 6%: serialized per-wave global B-loads at 1.5 waves/SIMD).
// Aggs: gather unroll x8.
// ---------------------------------------------------------------------------

typedef __attribute__((ext_vector_type(8))) short bf16x8;
typedef __attribute__((ext_vector_type(4))) float f32x4;

union FU { bf16x8 v; uint32_t u[4]; };

__device__ __forceinline__ void gload_lds16(const void* g, void* l) {
    __builtin_amdgcn_global_load_lds(
        (const __attribute__((address_space(1))) unsigned int*)g,
        (__attribute__((address_space(3))) unsigned int*)l,
        16, 0, 0);
}
__device__ __forceinline__ uint32_t prm(uint32_t a, uint32_t b, uint32_t s) {
    return __builtin_amdgcn_perm(a, b, s);
}
__device__ __forceinline__ f32x4 mfma16(bf16x8 a, bf16x8 b, f32x4 c) {
    return __builtin_amdgcn_mfma_f32_16x16x32_bf16(a, b, c, 0, 0, 0);
}
// value -> interleaved dword {lo16:hi16}
__device__ __forceinline__ uint32_t pack_hl(float o) {
    uint32_t u = __float_as_uint(o);
    float lo = o - __uint_as_float(u & 0xFFFF0000u);
    return (__float_as_uint(lo) & 0xFFFF0000u) | (u >> 16);
}
__device__ __forceinline__ float unpack_hl(uint32_t d) {
    return __uint_as_float(d << 16) + __uint_as_float(d & 0xFFFF0000u);
}

// 8 interleaved dwords -> hi-frag + lo-frag (8 bf16 each)
__device__ __forceinline__ void unzip_ilv(const uint32_t* ap, FU& ah, FU& al) {
    uint4 q0 = *(const uint4*)ap;
    uint4 q1 = *(const uint4*)(ap + 4);
    ah.u[0] = prm(q0.y, q0.x, 0x05040100u); al.u[0] = prm(q0.y, q0.x, 0x07060302u);
    ah.u[1] = prm(q0.w, q0.z, 0x05040100u); al.u[1] = prm(q0.w, q0.z, 0x07060302u);
    ah.u[2] = prm(q1.y, q1.x, 0x05040100u); al.u[2] = prm(q1.y, q1.x, 0x07060302u);
    ah.u[3] = prm(q1.w, q1.z, 0x05040100u); al.u[3] = prm(q1.w, q1.z, 0x07060302u);
}
// 8 raw f32 dwords -> hi/lo frags (truncation split)
__device__ __forceinline__ void split_raw(const uint32_t* ap, FU& ah, FU& al) {
    uint4 q0 = *(const uint4*)ap;
    uint4 q1 = *(const uint4*)(ap + 4);
    uint32_t e[8] = {q0.x, q0.y, q0.z, q0.w, q1.x, q1.y, q1.z, q1.w};
    uint32_t lo[8];
#pragma unroll
    for (int i = 0; i < 8; ++i)
        lo[i] = __float_as_uint(__uint_as_float(e[i]) -
                                __uint_as_float(e[i] & 0xFFFF0000u));
    ah.u[0] = prm(e[1], e[0], 0x07060302u);  al.u[0] = prm(lo[1], lo[0], 0x07060302u);
    ah.u[1] = prm(e[3], e[2], 0x07060302u);  al.u[1] = prm(lo[3], lo[2], 0x07060302u);
    ah.u[2] = prm(e[5], e[4], 0x07060302u);  al.u[2] = prm(lo[5], lo[4], 0x07060302u);
    ah.u[3] = prm(e[7], e[6], 0x07060302u);  al.u[3] = prm(lo[7], lo[6], 0x07060302u);
}

__global__ __launch_bounds__(256)
void hist_kernel(const int* __restrict__ dst, int E, int* __restrict__ cnt) {
    int i = blockIdx.x * 256 + threadIdx.x;
    if (i < E) atomicAdd(&cnt[dst[i]], 1);
}

// ---- multiblock exclusive scan over 3 relations, 1024 elems/block ----
__global__ __launch_bounds__(256)
void scan_bsum_kernel(const int* c0, int n0, int nb0,
                      const int* c1, int n1, int nb1,
                      const int* c2, int n2, int nb2, int* __restrict__ bsum) {
    int b = blockIdx.x;
    const int* cnt; int n; int lb;
    if (b < nb0)            { cnt = c0; n = n0; lb = b; }
    else if (b < nb0 + nb1) { cnt = c1; n = n1; lb = b - nb0; }
    else                    { cnt = c2; n = n2; lb = b - nb0 - nb1; }
    const int tid = threadIdx.x;
    const int base = lb * 1024 + tid * 4;
    int s = 0;
    if (base + 4 <= n) {
        int4 v = *(const int4*)&cnt[base];
        s = v.x + v.y + v.z + v.w;
    } else {
        for (int k = 0; k < 4; ++k) if (base + k < n) s += cnt[base + k];
    }
    __shared__ int sm[256];
    sm[tid] = s; __syncthreads();
    for (int d = 128; d > 0; d >>= 1) {
        if (tid < d) sm[tid] += sm[tid + d];
        __syncthreads();
    }
    if (tid == 0) bsum[b] = sm[0];
}

__global__ __launch_bounds__(256)
void scan_spine_kernel(int nb0, int nb1, int nb2, int* __restrict__ bsum,
                       int* o0, int n0, int* o1, int n1, int* o2, int n2) {
    const int r  = blockIdx.x;
    const int sb = (r == 0) ? 0 : (r == 1) ? nb0 : nb0 + nb1;
    const int nb = (r == 0) ? nb0 : (r == 1) ? nb1 : nb2;
    int* off     = (r == 0) ? o0 : (r == 1) ? o1 : o2;
    const int n  = (r == 0) ? n0 : (r == 1) ? n1 : n2;
    const int tid = threadIdx.x;
    int v = (tid < nb) ? bsum[sb + tid] : 0;
    __shared__ int sm[256];
    sm[tid] = v; __syncthreads();
    for (int d = 1; d < 256; d <<= 1) {
        int t = (tid >= d) ? sm[tid - d] : 0;
        __syncthreads();
        sm[tid] += t;
        __syncthreads();
    }
    if (tid < nb) bsum[sb + tid] = sm[tid] - v; // exclusive
    if (tid == 0) off[n] = sm[255];
}

__global__ __launch_bounds__(256)
void scan_write_kernel(const int* c0, int* o0, int n0, int nb0,
                       const int* c1, int* o1, int n1, int nb1,
                       const int* c2, int* o2, int n2, int nb2,
                       const int* __restrict__ bsum) {
    int b = blockIdx.x;
    const int* cnt; int* off; int n; int lb;
    if (b < nb0)            { cnt = c0; off = o0; n = n0; lb = b; }
    else if (b < nb0 + nb1) { cnt = c1; off = o1; n = n1; lb = b - nb0; }
    else                    { cnt = c2; off = o2; n = n2; lb = b - nb0 - nb1; }
    const int tid = threadIdx.x;
    const int base = lb * 1024 + tid * 4;
    int4 v = make_int4(0, 0, 0, 0);
    if (base + 4 <= n) v = *(const int4*)&cnt[base];
    else {
        if (base + 0 < n) v.x = cnt[base + 0];
        if (base + 1 < n) v.y = cnt[base + 1];
        if (base + 2 < n) v.z = cnt[base + 2];
        if (base + 3 < n) v.w = cnt[base + 3];
    }
    const int s = v.x + v.y + v.z + v.w;
    __shared__ int sm[256];
    sm[tid] = s; __syncthreads();
    for (int d = 1; d < 256; d <<= 1) {
        int t = (tid >= d) ? sm[tid - d] : 0;
        __syncthreads();
        sm[tid] += t;
        __syncthreads();
    }
    const int pre = bsum[b] + sm[tid] - s;
    int4 o;
    o.x = pre; o.y = pre + v.x; o.z = pre + v.x + v.y; o.w = pre + v.x + v.y + v.z;
    if (base + 4 <= n) *(int4*)&off[base] = o;
    else {
        if (base + 0 < n) off[base + 0] = o.x;
        if (base + 1 < n) off[base + 1] = o.y;
        if (base + 2 < n) off[base + 2] = o.z;
        if (base + 3 < n) off[base + 3] = o.w;
    }
}

__global__ __launch_bounds__(256)
void fill_kernel(const int* __restrict__ src, const int* __restrict__ dst, int E,
                 const int* __restrict__ off, int* __restrict__ cur, int* __restrict__ col) {
    int i = blockIdx.x * 256 + threadIdx.x;
    if (i < E) {
        int d = dst[i];
        int p = off[d] + atomicAdd(&cur[d], 1);
        col[p] = src[i];
    }
}

// One wave per destination row; lane owns 2 cols; 8 gathers in flight.
template <bool ILV>
__global__ __launch_bounds__(256)
void agg_mean_kernel(const uint32_t* __restrict__ X,
                     const int* __restrict__ off, const int* __restrict__ col,
                     uint32_t* __restrict__ Y, int n) {
    int gw   = (blockIdx.x * 256 + threadIdx.x) >> 6;
    int lane = threadIdx.x & 63;
    if (gw >= n) return;
    const int e0 = off[gw], e1 = off[gw + 1];
    const int lo2 = lane << 1;
    float a0 = 0.f, a1 = 0.f, b0 = 0.f, b1 = 0.f;
    float c0 = 0.f, c1 = 0.f, d0 = 0.f, d1 = 0.f;
    int e = e0;
    for (; e + 8 <= e1; e += 8) {
        int s[8];
#pragma unroll
        for (int i = 0; i < 8; ++i) s[i] = col[e + i];
        if constexpr (ILV) {
            uint2 v[8];
#pragma unroll
            for (int i = 0; i < 8; ++i)
                v[i] = *(const uint2*)(X + (size_t)s[i] * 128 + lo2);
            a0 += unpack_hl(v[0].x) + unpack_hl(v[4].x);
            a1 += unpack_hl(v[0].y) + unpack_hl(v[4].y);
            b0 += unpack_hl(v[1].x) + unpack_hl(v[5].x);
            b1 += unpack_hl(v[1].y) + unpack_hl(v[5].y);
            c0 += unpack_hl(v[2].x) + unpack_hl(v[6].x);
            c1 += unpack_hl(v[2].y) + unpack_hl(v[6].y);
            d0 += unpack_hl(v[3].x) + unpack_hl(v[7].x);
            d1 += unpack_hl(v[3].y) + unpack_hl(v[7].y);
        } else {
            float2 v[8];
#pragma unroll
            for (int i = 0; i < 8; ++i)
                v[i] = *(const float2*)((const float*)X + (size_t)s[i] * 128 + lo2);
            a0 += v[0].x + v[4].x; a1 += v[0].y + v[4].y;
            b0 += v[1].x + v[5].x; b1 += v[1].y + v[5].y;
            c0 += v[2].x + v[6].x; c1 += v[2].y + v[6].y;
            d0 += v[3].x + v[7].x; d1 += v[3].y + v[7].y;
        }
    }
    for (; e < e1; ++e) {
        int s0 = col[e];
        if constexpr (ILV) {
            uint2 v = *(const uint2*)(X + (size_t)s0 * 128 + lo2);
            a0 += unpack_hl(v.x); a1 += unpack_hl(v.y);
        } else {
            float2 v = *(const float2*)((const float*)X + (size_t)s0 * 128 + lo2);
            a0 += v.x; a1 += v.y;
        }
    }
    a0 += b0 + c0 + d0; a1 += b1 + c1 + d1;
    const int deg = e1 - e0;
    const float inv = 1.0f / (float)(deg > 0 ? deg : 1);
    uint2 o; o.x = pack_hl(a0 * inv); o.y = pack_hl(a1 * inv);
    *(uint2*)(Y + (size_t)gw * 128 + lo2) = o;
}

__device__ __forceinline__ void split_store(float w, unsigned short* hi,
                                            unsigned short* lo, int i) {
    uint32_t u = __float_as_uint(w);
    hi[i] = (unsigned short)(u >> 16);
    float l = w - __uint_as_float(u & 0xFFFF0000u);
    lo[i] = (unsigned short)(__float_as_uint(l) >> 16);
}

// W[0]=0.5*cWl, W[1]=0.5*aWl, W[2]=0.5*(cWr+aWr); b=0.5*(cbl+abl); hi/lo bf16
__global__ __launch_bounds__(256)
void prep_w3_kernel(const float* __restrict__ cWl, const float* __restrict__ cbl,
                    const float* __restrict__ cWr,
                    const float* __restrict__ aWl, const float* __restrict__ abl,
                    const float* __restrict__ aWr,
                    unsigned short* __restrict__ Whi, unsigned short* __restrict__ Wlo,
                    float* __restrict__ b) {
    int i = blockIdx.x * 256 + threadIdx.x;
    if (i < 16384) {
        split_store(0.5f * cWl[i], Whi, Wlo, i);
        split_store(0.5f * aWl[i], Whi, Wlo, 16384 + i);
        split_store(0.5f * (cWr[i] + aWr[i]), Whi, Wlo, 32768 + i);
    }
    if (i < 128) b[i] = 0.5f * (cbl[i] + abl[i]);
}

__global__ __launch_bounds__(256)
void prep_w2_kernel(const float* __restrict__ Wl, const float* __restrict__ Wr,
                    unsigned short* __restrict__ Whi, unsigned short* __restrict__ Wlo) {
    int i = blockIdx.x * 256 + threadIdx.x;
    if (i < 16384) {
        split_store(Wl[i], Whi, Wlo, i);
        split_store(Wr[i], Whi, Wlo, 16384 + i);
    }
}

// Y[i,:] = relu( sum_p A_p[i,:] @ W_p^T + bias ): split-bf16 MFMA.
// Block: 4 waves x 32 rows = 128 rows x 128 cols. W(p) hi/lo staged per-block
// into XOR-swizzled LDS (swizzle: byte_off ^= (row&7)<<4, applied to the
// GLOBAL source of global_load_lds and to the ds_read address — linear dest).
// A/B frag (16x16x32): lane l holds row/col (l&15), k=(l>>4)*8..+7.
// C/D (m89-verified): col = l&15, row = (l>>4)*4 + reg.
template <int PAIRS, int RAW_LAST>
__global__ __launch_bounds__(256, 2)
void transform_mfma(const uint32_t* A0, const uint32_t* A1, const uint32_t* A2,
                    const unsigned short* __restrict__ Whi,
                    const unsigned short* __restrict__ Wlo,
                    const float* __restrict__ bias, uint32_t* Y, int N) {
    __shared__ unsigned short Bhi[128 * 128];   // 32 KB, swizzled rows
    __shared__ unsigned short Blo[128 * 128];   // 32 KB, swizzled rows
    const int tid  = threadIdx.x;
    const int l    = tid & 63;
    const int wv   = tid >> 6;          // wave 0..3
    const int lrow = l & 15;
    const int lkg  = l >> 4;            // 0..3
    const int rw   = blockIdx.x * 128 + wv * 32;

    f32x4 acc0[8], acc1[8];
#pragma unroll
    for (int t = 0; t < 8; ++t) {
        acc0[t] = (f32x4){0.f, 0.f, 0.f, 0.f};
        acc1[t] = (f32x4){0.f, 0.f, 0.f, 0.f};
    }

    int arow0 = rw + lrow;      if (arow0 >= N) arow0 = N - 1;
    int arow1 = rw + 16 + lrow; if (arow1 >= N) arow1 = N - 1;
    const int kbase = lkg << 3;
    const int cb    = lkg << 4;         // byte col offset of this lane's k-octet

#pragma unroll 1
    for (int p = 0; p < PAIRS; ++p) {
        // ---- stage W(p): 32 KB hi + 32 KB lo, pre-swizzled source ----
        {
            const char* srcH = (const char*)(Whi + (p << 14));
            const char* srcL = (const char*)(Wlo + (p << 14));
#pragma unroll
            for (int it = 0; it < 8; ++it) {
                const int L   = it * 4096 + tid * 16;       // linear LDS byte
                const int j   = L >> 8;                     // W row
                const int g   = (j << 8) + ((L & 255) ^ ((j & 7) << 4));
                gload_lds16(srcH + g, (char*)Bhi + L);
                gload_lds16(srcL + g, (char*)Blo + L);
            }
        }
        __syncthreads();
        const uint32_t* A = (p == 0) ? A0 : (p == 1) ? A1 : A2;
        const bool raw = RAW_LAST && (p == PAIRS - 1);
#pragma unroll
        for (int kc = 0; kc < 4; ++kc) {
            FU ah0, al0, ah1, al1;
            const uint32_t* ap0 = A + (size_t)arow0 * 128 + kc * 32 + kbase;
            const uint32_t* ap1 = A + (size_t)arow1 * 128 + kc * 32 + kbase;
            if (raw) { split_raw(ap0, ah0, al0); split_raw(ap1, ah1, al1); }
            else     { unzip_ilv(ap0, ah0, al0); unzip_ilv(ap1, ah1, al1); }
            const int cbk = kc * 64 + cb;
#pragma unroll
            for (int t = 0; t < 8; ++t) {
                const int jt   = (t << 4) + lrow;
                const int addr = (jt << 8) + (cbk ^ ((jt & 7) << 4));
                bf16x8 bh = *(const bf16x8*)((const char*)Bhi + addr);
                bf16x8 bl = *(const bf16x8*)((const char*)Blo + addr);
                acc0[t] = mfma16(ah0.v, bh, acc0[t]);
                acc1[t] = mfma16(ah1.v, bh, acc1[t]);
                acc0[t] = mfma16(ah0.v, bl, acc0[t]);
                acc1[t] = mfma16(ah1.v, bl, acc1[t]);
                acc0[t] = mfma16(al0.v, bh, acc0[t]);
                acc1[t] = mfma16(al1.v, bh, acc1[t]);
            }
        }
        __syncthreads();
    }
#pragma unroll
    for (int t = 0; t < 8; ++t) {
        const int c = t * 16 + lrow;
        const float bv = bias[c];
#pragma unroll
        for (int r = 0; r < 4; ++r) {
            int row0 = rw + (lkg << 2) + r;
            if (row0 < N)
                Y[(size_t)row0 * 128 + c] = pack_hl(fmaxf(acc0[t][r] + bv, 0.f));
            int row1 = row0 + 16;
            if (row1 < N)
                Y[(size_t)row1 * 128 + c] = pack_hl(fmaxf(acc1[t][r] + bv, 0.f));
        }
    }
}

__global__ __launch_bounds__(256)
void final_linear_kernel(const uint32_t* __restrict__ P, const float* __restrict__ Wt,
                         const float* __restrict__ bb, float* __restrict__ out, int N) {
    __shared__ float lw[1024];
    __shared__ float lb[8];
    for (int i = threadIdx.x; i < 1024; i += 256) lw[i] = Wt[i];
    if (threadIdx.x < 8) lb[threadIdx.x] = bb[threadIdx.x];
    __syncthreads();
    int idx = blockIdx.x * 256 + threadIdx.x;
    if (idx >= N * 8) return;
    int row = idx >> 3, c = idx & 7;
    const uint32_t* pr = P + (size_t)row * 128;
    const float* wr = &lw[c << 7];
    float s = 0.f;
#pragma unroll
    for (int k = 0; k < 128; k += 4) {
        uint4 q = *(const uint4*)(pr + k);
        float4 wv = *(const float4*)&wr[k];
        s += unpack_hl(q.x) * wv.x + unpack_hl(q.y) * wv.y
           + unpack_hl(q.z) * wv.z + unpack_hl(q.w) * wv.w;
    }
    out[idx] = s + lb[c];
}

extern "C" void kernel_launch(void* const* d_in, const int* in_sizes, int n_in,
                              void* d_out, int out_size, void* d_ws, size_t ws_size,
                              hipStream_t stream) {
    const uint32_t* x_p = (const uint32_t*)d_in[0];
    const uint32_t* x_a = (const uint32_t*)d_in[1];
    const int* c_src = (const int*)d_in[2];
    const int* c_dst = (const int*)d_in[3];
    const int* a_src = (const int*)d_in[4];
    const int* a_dst = (const int*)d_in[5];
    const int* h_src = (const int*)d_in[6];
    const int* h_dst = (const int*)d_in[7];
    const float* l1c_Wl = (const float*)d_in[8];
    const float* l1c_bl = (const float*)d_in[9];
    const float* l1c_Wr = (const float*)d_in[10];
    const float* l1a_Wl = (const float*)d_in[11];
    const float* l1a_bl = (const float*)d_in[12];
    const float* l1a_Wr = (const float*)d_in[13];
    const float* l1h_Wl = (const float*)d_in[14];
    const float* l1h_bl = (const float*)d_in[15];
    const float* l1h_Wr = (const float*)d_in[16];
    const float* l2c_Wl = (const float*)d_in[17];
    const float* l2c_bl = (const float*)d_in[18];
    const float* l2c_Wr = (const float*)d_in[19];
    const float* l2a_Wl = (const float*)d_in[20];
    const float* l2a_bl = (const float*)d_in[21];
    const float* l2a_Wr = (const float*)d_in[22];
    const float* linW   = (const float*)d_in[26];
    const float* linb   = (const float*)d_in[27];

    const int NP = in_sizes[0] / 128;
    const int NA = in_sizes[1] / 128;
    const int Ec = in_sizes[2];
    const int Ea = in_sizes[4];
    const int Eh = in_sizes[6];

    // ---- carve workspace ----
    char* base = (char*)d_ws;
    size_t cur = 0;
    auto carve = [&](size_t bytes) -> char* {
        char* p = base + cur;
        cur = (cur + bytes + 255) & ~(size_t)255;
        return p;
    };
    uint32_t* S1 = (uint32_t*)carve((size_t)NP * 128 * 4);  // agg_c1 -> p1 (in place)
    uint32_t* S2 = (uint32_t*)carve((size_t)NP * 128 * 4);  // agg_a1 -> agg_c2 -> p2
    uint32_t* S3 = (uint32_t*)carve((size_t)NP * 128 * 4);  // agg_a2
    uint32_t* SH = (uint32_t*)carve((size_t)NA * 128 * 4);  // agg_h1 -> a1 (in place)
    unsigned short* W1hi = (unsigned short*)carve(3 * 16384 * 2);
    unsigned short* W1lo = (unsigned short*)carve(3 * 16384 * 2);
    unsigned short* W2hi = (unsigned short*)carve(3 * 16384 * 2);
    unsigned short* W2lo = (unsigned short*)carve(3 * 16384 * 2);
    unsigned short* WHhi = (unsigned short*)carve(2 * 16384 * 2);
    unsigned short* WHlo = (unsigned short*)carve(2 * 16384 * 2);
    float* b1 = (float*)carve(512);
    float* b2 = (float*)carve(512);
    int* off_c = (int*)carve((size_t)(NP + 1) * 4);
    int* off_a = (int*)carve((size_t)(NP + 1) * 4);
    int* off_h = (int*)carve((size_t)(NA + 1) * 4);
    int* col_c = (int*)carve((size_t)Ec * 4);
    int* col_a = (int*)carve((size_t)Ea * 4);
    int* col_h = (int*)carve((size_t)Eh * 4);
    int* bsum  = (int*)carve(4096);
    char* cntBase = base + cur;
    int* cnt_c = (int*)carve((size_t)NP * 4);
    int* cnt_a = (int*)carve((size_t)NP * 4);
    int* cnt_h = (int*)carve((size_t)NA * 4);
    size_t cntBytes = (size_t)((base + cur) - cntBase);
    if (cur > ws_size) return;

    const int nb_c = (NP + 1023) / 1024;
    const int nb_a = (NP + 1023) / 1024;
    const int nb_h = (NA + 1023) / 1024;
    const int nb_tot = nb_c + nb_a + nb_h;

    // ---- CSR build (reused by both layers) ----
    hipMemsetAsync(cntBase, 0, cntBytes, stream);
    hist_kernel<<<(Ec + 255) / 256, 256, 0, stream>>>(c_dst, Ec, cnt_c);
    hist_kernel<<<(Ea + 255) / 256, 256, 0, stream>>>(a_dst, Ea, cnt_a);
    hist_kernel<<<(Eh + 255) / 256, 256, 0, stream>>>(h_dst, Eh, cnt_h);
    scan_bsum_kernel<<<nb_tot, 256, 0, stream>>>(cnt_c, NP, nb_c, cnt_a, NP, nb_a,
                                                 cnt_h, NA, nb_h, bsum);
    scan_spine_kernel<<<3, 256, 0, stream>>>(nb_c, nb_a, nb_h, bsum,
                                             off_c, NP, off_a, NP, off_h, NA);
    scan_write_kernel<<<nb_tot, 256, 0, stream>>>(cnt_c, off_c, NP, nb_c,
                                                  cnt_a, off_a, NP, nb_a,
                                                  cnt_h, off_h, NA, nb_h, bsum);
    hipMemsetAsync(cntBase, 0, cntBytes, stream);
    fill_kernel<<<(Ec + 255) / 256, 256, 0, stream>>>(c_src, c_dst, Ec, off_c, cnt_c, col_c);
    fill_kernel<<<(Ea + 255) / 256, 256, 0, stream>>>(a_src, a_dst, Ea, off_a, cnt_a, col_a);
    fill_kernel<<<(Eh + 255) / 256, 256, 0, stream>>>(h_src, h_dst, Eh, off_h, cnt_h, col_h);

    // ---- weights -> split-bf16 hi/lo ----
    prep_w3_kernel<<<64, 256, 0, stream>>>(l1c_Wl, l1c_bl, l1c_Wr,
                                           l1a_Wl, l1a_bl, l1a_Wr, W1hi, W1lo, b1);
    prep_w3_kernel<<<64, 256, 0, stream>>>(l2c_Wl, l2c_bl, l2c_Wr,
                                           l2a_Wl, l2a_bl, l2a_Wr, W2hi, W2lo, b2);
    prep_w2_kernel<<<64, 256, 0, stream>>>(l1h_Wl, l1h_Wr, WHhi, WHlo);

    // ---- layer 1 ----
    agg_mean_kernel<false><<<(NP + 3) / 4, 256, 0, stream>>>(x_p, off_c, col_c, S1, NP);
    agg_mean_kernel<false><<<(NP + 3) / 4, 256, 0, stream>>>(x_a, off_a, col_a, S2, NP);
    agg_mean_kernel<false><<<(NA + 3) / 4, 256, 0, stream>>>(x_p, off_h, col_h, SH, NA);
    transform_mfma<3, 1><<<(NP + 127) / 128, 256, 0, stream>>>(
        S1, S2, x_p, W1hi, W1lo, b1, S1, NP);                 // p1 (in place)
    transform_mfma<2, 1><<<(NA + 127) / 128, 256, 0, stream>>>(
        SH, x_a, nullptr, WHhi, WHlo, l1h_bl, SH, NA);        // a1 (in place)

    // ---- layer 2 ----
    agg_mean_kernel<true><<<(NP + 3) / 4, 256, 0, stream>>>(S1, off_c, col_c, S2, NP);
    agg_mean_kernel<true><<<(NP + 3) / 4, 256, 0, stream>>>(SH, off_a, col_a, S3, NP);
    transform_mfma<3, 0><<<(NP + 127) / 128, 256, 0, stream>>>(
        S2, S3, S1, W2hi, W2lo, b2, S2, NP);                  // p2 (in place)

    // ---- head ----
    final_linear_kernel<<<((NP * 8) + 255) / 256, 256, 0, stream>>>(
        S2, linW, linb, (float*)d_out, NP);
}

// Round 6
// 503.929 us; speedup vs baseline: 36.2212x; 1.1278x over previous
//
#include <hip/hip_runtime.h>
#include <hip/hip_bf16.h>
#include <cstdint>

// ---------------------------------------------------------------------------
// FullHeteroGCN: 2-layer hetero GraphSAGE (mean aggr).
// R6: all ACTIVATIONS in bf16 (RNE) — halves the BW-bound gather bytes
// (R5: agg = 5 x 60us at 3.2 TB/s beyond-L2, 135MB FETCH/dispatch).
// Weights stay hi/lo split-bf16 (2 MFMA per tile) so weight error ~2^-17;
// accumulation f32 everywhere; f32->bf16 stores use round-to-nearest-even
// (unbiased; truncation bias would survive the mean).
// ---------------------------------------------------------------------------

typedef __attribute__((ext_vector_type(8))) short bf16x8;
typedef __attribute__((ext_vector_type(4))) float f32x4;

__device__ __forceinline__ void gload_lds16(const void* g, void* l) {
    __builtin_amdgcn_global_load_lds(
        (const __attribute__((address_space(1))) unsigned int*)g,
        (__attribute__((address_space(3))) unsigned int*)l,
        16, 0, 0);
}
__device__ __forceinline__ f32x4 mfma16(bf16x8 a, bf16x8 b, f32x4 c) {
    return __builtin_amdgcn_mfma_f32_16x16x32_bf16(a, b, c, 0, 0, 0);
}
__device__ __forceinline__ uint32_t rne_bf16(float x) {
    uint32_t u = __float_as_uint(x);
    u += 0x7FFFu + ((u >> 16) & 1u);
    return u >> 16;
}
__device__ __forceinline__ uint32_t rne2(float lo, float hi) {
    return rne_bf16(lo) | (rne_bf16(hi) << 16);
}
__device__ __forceinline__ float blo(uint32_t v) { return __uint_as_float(v << 16); }
__device__ __forceinline__ float bhi(uint32_t v) { return __uint_as_float(v & 0xFFFF0000u); }

__global__ __launch_bounds__(256)
void hist_kernel(const int* __restrict__ dst, int E, int* __restrict__ cnt) {
    int i = blockIdx.x * 256 + threadIdx.x;
    if (i < E) atomicAdd(&cnt[dst[i]], 1);
}

// ---- multiblock exclusive scan over 3 relations, 1024 elems/block ----
__global__ __launch_bounds__(256)
void scan_bsum_kernel(const int* c0, int n0, int nb0,
                      const int* c1, int n1, int nb1,
                      const int* c2, int n2, int nb2, int* __restrict__ bsum) {
    int b = blockIdx.x;
    const int* cnt; int n; int lb;
    if (b < nb0)            { cnt = c0; n = n0; lb = b; }
    else if (b < nb0 + nb1) { cnt = c1; n = n1; lb = b - nb0; }
    else                    { cnt = c2; n = n2; lb = b - nb0 - nb1; }
    const int tid = threadIdx.x;
    const int base = lb * 1024 + tid * 4;
    int s = 0;
    if (base + 4 <= n) {
        int4 v = *(const int4*)&cnt[base];
        s = v.x + v.y + v.z + v.w;
    } else {
        for (int k = 0; k < 4; ++k) if (base + k < n) s += cnt[base + k];
    }
    __shared__ int sm[256];
    sm[tid] = s; __syncthreads();
    for (int d = 128; d > 0; d >>= 1) {
        if (tid < d) sm[tid] += sm[tid + d];
        __syncthreads();
    }
    if (tid == 0) bsum[b] = sm[0];
}

__global__ __launch_bounds__(256)
void scan_spine_kernel(int nb0, int nb1, int nb2, int* __restrict__ bsum,
                       int* o0, int n0, int* o1, int n1, int* o2, int n2) {
    const int r  = blockIdx.x;
    const int sb = (r == 0) ? 0 : (r == 1) ? nb0 : nb0 + nb1;
    const int nb = (r == 0) ? nb0 : (r == 1) ? nb1 : nb2;
    int* off     = (r == 0) ? o0 : (r == 1) ? o1 : o2;
    const int n  = (r == 0) ? n0 : (r == 1) ? n1 : n2;
    const int tid = threadIdx.x;
    int v = (tid < nb) ? bsum[sb + tid] : 0;
    __shared__ int sm[256];
    sm[tid] = v; __syncthreads();
    for (int d = 1; d < 256; d <<= 1) {
        int t = (tid >= d) ? sm[tid - d] : 0;
        __syncthreads();
        sm[tid] += t;
        __syncthreads();
    }
    if (tid < nb) bsum[sb + tid] = sm[tid] - v; // exclusive
    if (tid == 0) off[n] = sm[255];
}

__global__ __launch_bounds__(256)
void scan_write_kernel(const int* c0, int* o0, int n0, int nb0,
                       const int* c1, int* o1, int n1, int nb1,
                       const int* c2, int* o2, int n2, int nb2,
                       const int* __restrict__ bsum) {
    int b = blockIdx.x;
    const int* cnt; int* off; int n; int lb;
    if (b < nb0)            { cnt = c0; off = o0; n = n0; lb = b; }
    else if (b < nb0 + nb1) { cnt = c1; off = o1; n = n1; lb = b - nb0; }
    else                    { cnt = c2; off = o2; n = n2; lb = b - nb0 - nb1; }
    const int tid = threadIdx.x;
    const int base = lb * 1024 + tid * 4;
    int4 v = make_int4(0, 0, 0, 0);
    if (base + 4 <= n) v = *(const int4*)&cnt[base];
    else {
        if (base + 0 < n) v.x = cnt[base + 0];
        if (base + 1 < n) v.y = cnt[base + 1];
        if (base + 2 < n) v.z = cnt[base + 2];
        if (base + 3 < n) v.w = cnt[base + 3];
    }
    const int s = v.x + v.y + v.z + v.w;
    __shared__ int sm[256];
    sm[tid] = s; __syncthreads();
    for (int d = 1; d < 256; d <<= 1) {
        int t = (tid >= d) ? sm[tid - d] : 0;
        __syncthreads();
        sm[tid] += t;
        __syncthreads();
    }
    const int pre = bsum[b] + sm[tid] - s;
    int4 o;
    o.x = pre; o.y = pre + v.x; o.z = pre + v.x + v.y; o.w = pre + v.x + v.y + v.z;
    if (base + 4 <= n) *(int4*)&off[base] = o;
    else {
        if (base + 0 < n) off[base + 0] = o.x;
        if (base + 1 < n) off[base + 1] = o.y;
        if (base + 2 < n) off[base + 2] = o.z;
        if (base + 3 < n) off[base + 3] = o.w;
    }
}

__global__ __launch_bounds__(256)
void fill_kernel(const int* __restrict__ src, const int* __restrict__ dst, int E,
                 const int* __restrict__ off, int* __restrict__ cur, int* __restrict__ col) {
    int i = blockIdx.x * 256 + threadIdx.x;
    if (i < E) {
        int d = dst[i];
        int p = off[d] + atomicAdd(&cur[d], 1);
        col[p] = src[i];
    }
}

// f32 -> bf16(RNE) table convert; 8 elems per thread
__global__ __launch_bounds__(256)
void cvt_bf16_kernel(const float* __restrict__ X, uint32_t* __restrict__ Y, int n8) {
    int i = blockIdx.x * 256 + threadIdx.x;
    if (i >= n8) return;
    float4 v0 = *(const float4*)(X + (size_t)i * 8);
    float4 v1 = *(const float4*)(X + (size_t)i * 8 + 4);
    uint4 o;
    o.x = rne2(v0.x, v0.y); o.y = rne2(v0.z, v0.w);
    o.z = rne2(v1.x, v1.y); o.w = rne2(v1.z, v1.w);
    *(uint4*)(Y + (size_t)i * 4) = o;
}

// One wave per destination row (bf16 rows, 256 B); lane owns 2 cols (1 uint);
// 8 gathers in flight; f32 accumulate; RNE bf16 store.
__global__ __launch_bounds__(256)
void agg_mean_bf16(const uint32_t* __restrict__ X,
                   const int* __restrict__ off, const int* __restrict__ col,
                   uint32_t* __restrict__ Y, int n) {
    int gw   = (blockIdx.x * 256 + threadIdx.x) >> 6;
    int lane = threadIdx.x & 63;
    if (gw >= n) return;
    const int e0 = off[gw], e1 = off[gw + 1];
    float a0 = 0.f, a1 = 0.f, b0 = 0.f, b1 = 0.f;
    float c0 = 0.f, c1 = 0.f, d0 = 0.f, d1 = 0.f;
    int e = e0;
    for (; e + 8 <= e1; e += 8) {
        int s[8];
#pragma unroll
        for (int i = 0; i < 8; ++i) s[i] = col[e + i];
        uint32_t v[8];
#pragma unroll
        for (int i = 0; i < 8; ++i) v[i] = X[(size_t)s[i] * 64 + lane];
        a0 += blo(v[0]) + blo(v[4]); a1 += bhi(v[0]) + bhi(v[4]);
        b0 += blo(v[1]) + blo(v[5]); b1 += bhi(v[1]) + bhi(v[5]);
        c0 += blo(v[2]) + blo(v[6]); c1 += bhi(v[2]) + bhi(v[6]);
        d0 += blo(v[3]) + blo(v[7]); d1 += bhi(v[3]) + bhi(v[7]);
    }
    for (; e < e1; ++e) {
        uint32_t v = X[(size_t)col[e] * 64 + lane];
        a0 += blo(v); a1 += bhi(v);
    }
    a0 += b0 + c0 + d0; a1 += b1 + c1 + d1;
    const int deg = e1 - e0;
    const float inv = 1.0f / (float)(deg > 0 ? deg : 1);
    Y[(size_t)gw * 64 + lane] = rne2(a0 * inv, a1 * inv);
}

__device__ __forceinline__ void split_store(float w, unsigned short* hi,
                                            unsigned short* lo, int i) {
    uint32_t u = __float_as_uint(w);
    hi[i] = (unsigned short)(u >> 16);
    float l = w - __uint_as_float(u & 0xFFFF0000u);
    lo[i] = (unsigned short)(__float_as_uint(l) >> 16);
}

// W[0]=0.5*cWl, W[1]=0.5*aWl, W[2]=0.5*(cWr+aWr); b=0.5*(cbl+abl); hi/lo bf16
__global__ __launch_bounds__(256)
void prep_w3_kernel(const float* __restrict__ cWl, const float* __restrict__ cbl,
                    const float* __restrict__ cWr,
                    const float* __restrict__ aWl, const float* __restrict__ abl,
                    const float* __restrict__ aWr,
                    unsigned short* __restrict__ Whi, unsigned short* __restrict__ Wlo,
                    float* __restrict__ b) {
    int i = blockIdx.x * 256 + threadIdx.x;
    if (i < 16384) {
        split_store(0.5f * cWl[i], Whi, Wlo, i);
        split_store(0.5f * aWl[i], Whi, Wlo, 16384 + i);
        split_store(0.5f * (cWr[i] + aWr[i]), Whi, Wlo, 32768 + i);
    }
    if (i < 128) b[i] = 0.5f * (cbl[i] + abl[i]);
}

__global__ __launch_bounds__(256)
void prep_w2_kernel(const float* __restrict__ Wl, const float* __restrict__ Wr,
                    unsigned short* __restrict__ Whi, unsigned short* __restrict__ Wlo) {
    int i = blockIdx.x * 256 + threadIdx.x;
    if (i < 16384) {
        split_store(Wl[i], Whi, Wlo, i);
        split_store(Wr[i], Whi, Wlo, 16384 + i);
    }
}

// Y[i,:] = relu( sum_p A_p[i,:] @ W_p^T + bias ); A bf16, W hi/lo split.
// Block: 4 waves x 32 rows = 128 rows x 128 cols. W(p) hi/lo staged per-block
// into XOR-swizzled LDS (swizzle byte_off ^= (row&7)<<4 on the GLOBAL source
// of global_load_lds and on the ds_read address — linear dest).
// A/B frag (16x16x32): lane l holds row/col (l&15), k=(l>>4)*8..+7.
// C/D (m89-verified): col = l&15, row = (l>>4)*4 + reg.
template <int PAIRS>
__global__ __launch_bounds__(256, 2)
void transform_mfma(const unsigned short* A0, const unsigned short* A1,
                    const unsigned short* A2,
                    const unsigned short* __restrict__ Whi,
                    const unsigned short* __restrict__ Wlo,
                    const float* __restrict__ bias, unsigned short* Y, int N) {
    __shared__ unsigned short Bhi[128 * 128];   // 32 KB, swizzled rows
    __shared__ unsigned short Blo[128 * 128];   // 32 KB, swizzled rows
    const int tid  = threadIdx.x;
    const int l    = tid & 63;
    const int wv   = tid >> 6;          // wave 0..3
    const int lrow = l & 15;
    const int lkg  = l >> 4;            // 0..3
    const int rw   = blockIdx.x * 128 + wv * 32;

    f32x4 acc0[8], acc1[8];
#pragma unroll
    for (int t = 0; t < 8; ++t) {
        acc0[t] = (f32x4){0.f, 0.f, 0.f, 0.f};
        acc1[t] = (f32x4){0.f, 0.f, 0.f, 0.f};
    }

    int arow0 = rw + lrow;      if (arow0 >= N) arow0 = N - 1;
    int arow1 = rw + 16 + lrow; if (arow1 >= N) arow1 = N - 1;
    const int kbase = lkg << 3;         // elem offset of this lane's k-octet
    const int cb    = lkg << 4;         // byte offset of this lane's k-octet

#pragma unroll 1
    for (int p = 0; p < PAIRS; ++p) {
        // ---- stage W(p): 32 KB hi + 32 KB lo, pre-swizzled source ----
        {
            const char* srcH = (const char*)(Whi + (p << 14));
            const char* srcL = (const char*)(Wlo + (p << 14));
#pragma unroll
            for (int it = 0; it < 8; ++it) {
                const int L   = it * 4096 + tid * 16;       // linear LDS byte
                const int j   = L >> 8;                     // W row
                const int g   = (j << 8) + ((L & 255) ^ ((j & 7) << 4));
                gload_lds16(srcH + g, (char*)Bhi + L);
                gload_lds16(srcL + g, (char*)Blo + L);
            }
        }
        __syncthreads();
        const unsigned short* A = (p == 0) ? A0 : (p == 1) ? A1 : A2;
#pragma unroll
        for (int kc = 0; kc < 4; ++kc) {
            bf16x8 a0 = *(const bf16x8*)(A + (size_t)arow0 * 128 + kc * 32 + kbase);
            bf16x8 a1 = *(const bf16x8*)(A + (size_t)arow1 * 128 + kc * 32 + kbase);
            const int cbk = kc * 64 + cb;
#pragma unroll
            for (int t = 0; t < 8; ++t) {
                const int jt   = (t << 4) + lrow;
                const int addr = (jt << 8) + (cbk ^ ((jt & 7) << 4));
                bf16x8 bh = *(const bf16x8*)((const char*)Bhi + addr);
                bf16x8 bl = *(const bf16x8*)((const char*)Blo + addr);
                acc0[t] = mfma16(a0, bh, acc0[t]);
                acc1[t] = mfma16(a1, bh, acc1[t]);
                acc0[t] = mfma16(a0, bl, acc0[t]);
                acc1[t] = mfma16(a1, bl, acc1[t]);
            }
        }
        __syncthreads();
    }
#pragma unroll
    for (int t = 0; t < 8; ++t) {
        const int c = t * 16 + lrow;
        const float bv = bias[c];
#pragma unroll
        for (int r = 0; r < 4; ++r) {
            int row0 = rw + (lkg << 2) + r;
            if (row0 < N)
                Y[(size_t)row0 * 128 + c] =
                    (unsigned short)rne_bf16(fmaxf(acc0[t][r] + bv, 0.f));
            int row1 = row0 + 16;
            if (row1 < N)
                Y[(size_t)row1 * 128 + c] =
                    (unsigned short)rne_bf16(fmaxf(acc1[t][r] + bv, 0.f));
        }
    }
}

__global__ __launch_bounds__(256)
void final_linear_kernel(const uint32_t* __restrict__ P, const float* __restrict__ Wt,
                         const float* __restrict__ bb, float* __restrict__ out, int N) {
    __shared__ float lw[1024];
    __shared__ float lb[8];
    for (int i = threadIdx.x; i < 1024; i += 256) lw[i] = Wt[i];
    if (threadIdx.x < 8) lb[threadIdx.x] = bb[threadIdx.x];
    __syncthreads();
    int idx = blockIdx.x * 256 + threadIdx.x;
    if (idx >= N * 8) return;
    int row = idx >> 3, c = idx & 7;
    const uint32_t* pr = P + (size_t)row * 64;   // 64 uints = 128 bf16
    const float* wr = &lw[c << 7];
    float s = 0.f;
#pragma unroll
    for (int k = 0; k < 64; k += 4) {
        uint4 q = *(const uint4*)(pr + k);
        const float* w = wr + (k << 1);
        s += blo(q.x) * w[0] + bhi(q.x) * w[1]
           + blo(q.y) * w[2] + bhi(q.y) * w[3]
           + blo(q.z) * w[4] + bhi(q.z) * w[5]
           + blo(q.w) * w[6] + bhi(q.w) * w[7];
    }
    out[idx] = s + lb[c];
}

extern "C" void kernel_launch(void* const* d_in, const int* in_sizes, int n_in,
                              void* d_out, int out_size, void* d_ws, size_t ws_size,
                              hipStream_t stream) {
    const float* x_p = (const float*)d_in[0];
    const float* x_a = (const float*)d_in[1];
    const int* c_src = (const int*)d_in[2];
    const int* c_dst = (const int*)d_in[3];
    const int* a_src = (const int*)d_in[4];
    const int* a_dst = (const int*)d_in[5];
    const int* h_src = (const int*)d_in[6];
    const int* h_dst = (const int*)d_in[7];
    const float* l1c_Wl = (const float*)d_in[8];
    const float* l1c_bl = (const float*)d_in[9];
    const float* l1c_Wr = (const float*)d_in[10];
    const float* l1a_Wl = (const float*)d_in[11];
    const float* l1a_bl = (const float*)d_in[12];
    const float* l1a_Wr = (const float*)d_in[13];
    const float* l1h_Wl = (const float*)d_in[14];
    const float* l1h_bl = (const float*)d_in[15];
    const float* l1h_Wr = (const float*)d_in[16];
    const float* l2c_Wl = (const float*)d_in[17];
    const float* l2c_bl = (const float*)d_in[18];
    const float* l2c_Wr = (const float*)d_in[19];
    const float* l2a_Wl = (const float*)d_in[20];
    const float* l2a_bl = (const float*)d_in[21];
    const float* l2a_Wr = (const float*)d_in[22];
    const float* linW   = (const float*)d_in[26];
    const float* linb   = (const float*)d_in[27];

    const int NP = in_sizes[0] / 128;
    const int NA = in_sizes[1] / 128;
    const int Ec = in_sizes[2];
    const int Ea = in_sizes[4];
    const int Eh = in_sizes[6];

    // ---- carve workspace ----
    char* base = (char*)d_ws;
    size_t cur = 0;
    auto carve = [&](size_t bytes) -> char* {
        char* p = base + cur;
        cur = (cur + bytes + 255) & ~(size_t)255;
        return p;
    };
    uint32_t* xb_p = (uint32_t*)carve((size_t)NP * 128 * 2);  // bf16 x_patent
    uint32_t* xb_a = (uint32_t*)carve((size_t)NA * 128 * 2);  // bf16 x_author
    uint32_t* S1 = (uint32_t*)carve((size_t)NP * 128 * 2);    // agg_c1 -> p1 (in place)
    uint32_t* S2 = (uint32_t*)carve((size_t)NP * 128 * 2);    // agg_a1 -> agg_c2 -> p2
    uint32_t* S3 = (uint32_t*)carve((size_t)NP * 128 * 2);    // agg_a2
    uint32_t* SH = (uint32_t*)carve((size_t)NA * 128 * 2);    // agg_h1 -> a1 (in place)
    unsigned short* W1hi = (unsigned short*)carve(3 * 16384 * 2);
    unsigned short* W1lo = (unsigned short*)carve(3 * 16384 * 2);
    unsigned short* W2hi = (unsigned short*)carve(3 * 16384 * 2);
    unsigned short* W2lo = (unsigned short*)carve(3 * 16384 * 2);
    unsigned short* WHhi = (unsigned short*)carve(2 * 16384 * 2);
    unsigned short* WHlo = (unsigned short*)carve(2 * 16384 * 2);
    float* b1 = (float*)carve(512);
    float* b2 = (float*)carve(512);
    int* off_c = (int*)carve((size_t)(NP + 1) * 4);
    int* off_a = (int*)carve((size_t)(NP + 1) * 4);
    int* off_h = (int*)carve((size_t)(NA + 1) * 4);
    int* col_c = (int*)carve((size_t)Ec * 4);
    int* col_a = (int*)carve((size_t)Ea * 4);
    int* col_h = (int*)carve((size_t)Eh * 4);
    int* bsum  = (int*)carve(4096);
    char* cntBase = base + cur;
    int* cnt_c = (int*)carve((size_t)NP * 4);
    int* cnt_a = (int*)carve((size_t)NP * 4);
    int* cnt_h = (int*)carve((size_t)NA * 4);
    size_t cntBytes = (size_t)((base + cur) - cntBase);
    if (cur > ws_size) return;

    const int nb_c = (NP + 1023) / 1024;
    const int nb_a = (NP + 1023) / 1024;
    const int nb_h = (NA + 1023) / 1024;
    const int nb_tot = nb_c + nb_a + nb_h;

    // ---- CSR build (reused by both layers) ----
    hipMemsetAsync(cntBase, 0, cntBytes, stream);
    hist_kernel<<<(Ec + 255) / 256, 256, 0, stream>>>(c_dst, Ec, cnt_c);
    hist_kernel<<<(Ea + 255) / 256, 256, 0, stream>>>(a_dst, Ea, cnt_a);
    hist_kernel<<<(Eh + 255) / 256, 256, 0, stream>>>(h_dst, Eh, cnt_h);
    scan_bsum_kernel<<<nb_tot, 256, 0, stream>>>(cnt_c, NP, nb_c, cnt_a, NP, nb_a,
                                                 cnt_h, NA, nb_h, bsum);
    scan_spine_kernel<<<3, 256, 0, stream>>>(nb_c, nb_a, nb_h, bsum,
                                             off_c, NP, off_a, NP, off_h, NA);
    scan_write_kernel<<<nb_tot, 256, 0, stream>>>(cnt_c, off_c, NP, nb_c,
                                                  cnt_a, off_a, NP, nb_a,
                                                  cnt_h, off_h, NA, nb_h, bsum);
    hipMemsetAsync(cntBase, 0, cntBytes, stream);
    fill_kernel<<<(Ec + 255) / 256, 256, 0, stream>>>(c_src, c_dst, Ec, off_c, cnt_c, col_c);
    fill_kernel<<<(Ea + 255) / 256, 256, 0, stream>>>(a_src, a_dst, Ea, off_a, cnt_a, col_a);
    fill_kernel<<<(Eh + 255) / 256, 256, 0, stream>>>(h_src, h_dst, Eh, off_h, cnt_h, col_h);

    // ---- x -> bf16 tables; weights -> split-bf16 hi/lo ----
    cvt_bf16_kernel<<<(NP * 16 + 255) / 256, 256, 0, stream>>>(x_p, xb_p, NP * 16);
    cvt_bf16_kernel<<<(NA * 16 + 255) / 256, 256, 0, stream>>>(x_a, xb_a, NA * 16);
    prep_w3_kernel<<<64, 256, 0, stream>>>(l1c_Wl, l1c_bl, l1c_Wr,
                                           l1a_Wl, l1a_bl, l1a_Wr, W1hi, W1lo, b1);
    prep_w3_kernel<<<64, 256, 0, stream>>>(l2c_Wl, l2c_bl, l2c_Wr,
                                           l2a_Wl, l2a_bl, l2a_Wr, W2hi, W2lo, b2);
    prep_w2_kernel<<<64, 256, 0, stream>>>(l1h_Wl, l1h_Wr, WHhi, WHlo);

    // ---- layer 1 ----
    agg_mean_bf16<<<(NP + 3) / 4, 256, 0, stream>>>(xb_p, off_c, col_c, S1, NP);
    agg_mean_bf16<<<(NP + 3) / 4, 256, 0, stream>>>(xb_a, off_a, col_a, S2, NP);
    agg_mean_bf16<<<(NA + 3) / 4, 256, 0, stream>>>(xb_p, off_h, col_h, SH, NA);
    transform_mfma<3><<<(NP + 127) / 128, 256, 0, stream>>>(
        (const unsigned short*)S1, (const unsigned short*)S2,
        (const unsigned short*)xb_p, W1hi, W1lo, b1,
        (unsigned short*)S1, NP);                             // p1 (in place)
    transform_mfma<2><<<(NA + 127) / 128, 256, 0, stream>>>(
        (const unsigned short*)SH, (const unsigned short*)xb_a, nullptr,
        WHhi, WHlo, l1h_bl, (unsigned short*)SH, NA);         // a1 (in place)

    // ---- layer 2 ----
    agg_mean_bf16<<<(NP + 3) / 4, 256, 0, stream>>>(S1, off_c, col_c, S2, NP);
    agg_mean_bf16<<<(NP + 3) / 4, 256, 0, stream>>>(SH, off_a, col_a, S3, NP);
    transform_mfma<3><<<(NP + 127) / 128, 256, 0, stream>>>(
        (const unsigned short*)S2, (const unsigned short*)S3,
        (const unsigned short*)S1, W2hi, W2lo, b2,
        (unsigned short*)S2, NP);                             // p2 (in place)

    // ---- head ----
    final_linear_kernel<<<((NP * 8) + 255) / 256, 256, 0, stream>>>(
        S2, linW, linb, (float*)d_out, NP);
}

// Round 7
// 436.124 us; speedup vs baseline: 41.8525x; 1.1555x over previous
//
#include <hip/hip_runtime.h>
#include <hip/hip_bf16.h>
#include <cstdint>

// ---------------------------------------------------------------------------
// FullHeteroGCN: 2-layer hetero GraphSAGE (mean aggr).
// R7: aggs are VMEM-instruction-bound (R5 vs R6: same instr count, half
// bytes, ~same time). Quad-edge gather: uint4/lane => 4 edges per load
// instruction (0.5 VMEM/edge vs 2), shfl_xor cross-group combine.
// Kernel merges: hist x3 -> 1, fill x3 -> 1, cvt x2 -> 1, L1 aggs x3 -> 1,
// L2 aggs x2 -> 1 (fewer dispatch tails, better wave mixing).
// Activations bf16 (RNE); weights hi/lo split-bf16 (2 MFMA/tile); f32 accum.
// ---------------------------------------------------------------------------

typedef __attribute__((ext_vector_type(8))) short bf16x8;
typedef __attribute__((ext_vector_type(4))) float f32x4;

__device__ __forceinline__ void gload_lds16(const void* g, void* l) {
    __builtin_amdgcn_global_load_lds(
        (const __attribute__((address_space(1))) unsigned int*)g,
        (__attribute__((address_space(3))) unsigned int*)l,
        16, 0, 0);
}
__device__ __forceinline__ f32x4 mfma16(bf16x8 a, bf16x8 b, f32x4 c) {
    return __builtin_amdgcn_mfma_f32_16x16x32_bf16(a, b, c, 0, 0, 0);
}
__device__ __forceinline__ uint32_t rne_bf16(float x) {
    uint32_t u = __float_as_uint(x);
    u += 0x7FFFu + ((u >> 16) & 1u);
    return u >> 16;
}
__device__ __forceinline__ uint32_t rne2(float lo, float hi) {
    return rne_bf16(lo) | (rne_bf16(hi) << 16);
}
__device__ __forceinline__ float blo(uint32_t v) { return __uint_as_float(v << 16); }
__device__ __forceinline__ float bhi(uint32_t v) { return __uint_as_float(v & 0xFFFF0000u); }

// ---- CSR build ----
__global__ __launch_bounds__(256)
void hist3_kernel(const int* __restrict__ d0, int E0,
                  const int* __restrict__ d1, int E1,
                  const int* __restrict__ d2, int E2,
                  int* __restrict__ c0, int* __restrict__ c1, int* __restrict__ c2) {
    int i = blockIdx.x * 256 + threadIdx.x;
    if (i < E0) atomicAdd(&c0[d0[i]], 1);
    else if (i < E0 + E1) atomicAdd(&c1[d1[i - E0]], 1);
    else if (i < E0 + E1 + E2) atomicAdd(&c2[d2[i - E0 - E1]], 1);
}

__global__ __launch_bounds__(256)
void fill3_kernel(const int* __restrict__ s0, const int* __restrict__ d0, int E0,
                  const int* __restrict__ o0, int* __restrict__ u0, int* __restrict__ l0,
                  const int* __restrict__ s1, const int* __restrict__ d1, int E1,
                  const int* __restrict__ o1, int* __restrict__ u1, int* __restrict__ l1,
                  const int* __restrict__ s2, const int* __restrict__ d2, int E2,
                  const int* __restrict__ o2, int* __restrict__ u2, int* __restrict__ l2) {
    int i = blockIdx.x * 256 + threadIdx.x;
    const int* src; const int* dst; const int* off; int* curp; int* colp; int j;
    if (i < E0)           { src = s0; dst = d0; off = o0; curp = u0; colp = l0; j = i; }
    else if (i < E0 + E1) { src = s1; dst = d1; off = o1; curp = u1; colp = l1; j = i - E0; }
    else if (i < E0 + E1 + E2) { src = s2; dst = d2; off = o2; curp = u2; colp = l2; j = i - E0 - E1; }
    else return;
    int d = dst[j];
    int p = off[d] + atomicAdd(&curp[d], 1);
    colp[p] = src[j];
}

// ---- multiblock exclusive scan over 3 relations, 1024 elems/block ----
__global__ __launch_bounds__(256)
void scan_bsum_kernel(const int* c0, int n0, int nb0,
                      const int* c1, int n1, int nb1,
                      const int* c2, int n2, int nb2, int* __restrict__ bsum) {
    int b = blockIdx.x;
    const int* cnt; int n; int lb;
    if (b < nb0)            { cnt = c0; n = n0; lb = b; }
    else if (b < nb0 + nb1) { cnt = c1; n = n1; lb = b - nb0; }
    else                    { cnt = c2; n = n2; lb = b - nb0 - nb1; }
    const int tid = threadIdx.x;
    const int base = lb * 1024 + tid * 4;
    int s = 0;
    if (base + 4 <= n) {
        int4 v = *(const int4*)&cnt[base];
        s = v.x + v.y + v.z + v.w;
    } else {
        for (int k = 0; k < 4; ++k) if (base + k < n) s += cnt[base + k];
    }
    __shared__ int sm[256];
    sm[tid] = s; __syncthreads();
    for (int d = 128; d > 0; d >>= 1) {
        if (tid < d) sm[tid] += sm[tid + d];
        __syncthreads();
    }
    if (tid == 0) bsum[b] = sm[0];
}

__global__ __launch_bounds__(256)
void scan_spine_kernel(int nb0, int nb1, int nb2, int* __restrict__ bsum,
                       int* o0, int n0, int* o1, int n1, int* o2, int n2) {
    const int r  = blockIdx.x;
    const int sb = (r == 0) ? 0 : (r == 1) ? nb0 : nb0 + nb1;
    const int nb = (r == 0) ? nb0 : (r == 1) ? nb1 : nb2;
    int* off     = (r == 0) ? o0 : (r == 1) ? o1 : o2;
    const int n  = (r == 0) ? n0 : (r == 1) ? n1 : n2;
    const int tid = threadIdx.x;
    int v = (tid < nb) ? bsum[sb + tid] : 0;
    __shared__ int sm[256];
    sm[tid] = v; __syncthreads();
    for (int d = 1; d < 256; d <<= 1) {
        int t = (tid >= d) ? sm[tid - d] : 0;
        __syncthreads();
        sm[tid] += t;
        __syncthreads();
    }
    if (tid < nb) bsum[sb + tid] = sm[tid] - v; // exclusive
    if (tid == 0) off[n] = sm[255];
}

__global__ __launch_bounds__(256)
void scan_write_kernel(const int* c0, int* o0, int n0, int nb0,
                       const int* c1, int* o1, int n1, int nb1,
                       const int* c2, int* o2, int n2, int nb2,
                       const int* __restrict__ bsum) {
    int b = blockIdx.x;
    const int* cnt; int* off; int n; int lb;
    if (b < nb0)            { cnt = c0; off = o0; n = n0; lb = b; }
    else if (b < nb0 + nb1) { cnt = c1; off = o1; n = n1; lb = b - nb0; }
    else                    { cnt = c2; off = o2; n = n2; lb = b - nb0 - nb1; }
    const int tid = threadIdx.x;
    const int base = lb * 1024 + tid * 4;
    int4 v = make_int4(0, 0, 0, 0);
    if (base + 4 <= n) v = *(const int4*)&cnt[base];
    else {
        if (base + 0 < n) v.x = cnt[base + 0];
        if (base + 1 < n) v.y = cnt[base + 1];
        if (base + 2 < n) v.z = cnt[base + 2];
        if (base + 3 < n) v.w = cnt[base + 3];
    }
    const int s = v.x + v.y + v.z + v.w;
    __shared__ int sm[256];
    sm[tid] = s; __syncthreads();
    for (int d = 1; d < 256; d <<= 1) {
        int t = (tid >= d) ? sm[tid - d] : 0;
        __syncthreads();
        sm[tid] += t;
        __syncthreads();
    }
    const int pre = bsum[b] + sm[tid] - s;
    int4 o;
    o.x = pre; o.y = pre + v.x; o.z = pre + v.x + v.y; o.w = pre + v.x + v.y + v.z;
    if (base + 4 <= n) *(int4*)&off[base] = o;
    else {
        if (base + 0 < n) off[base + 0] = o.x;
        if (base + 1 < n) off[base + 1] = o.y;
        if (base + 2 < n) off[base + 2] = o.z;
        if (base + 3 < n) off[base + 3] = o.w;
    }
}

// ---- f32 -> bf16(RNE): both tables in one dispatch ----
__global__ __launch_bounds__(256)
void cvt2_bf16_kernel(const float* __restrict__ X0, uint32_t* __restrict__ Y0, int n80,
                      const float* __restrict__ X1, uint32_t* __restrict__ Y1, int n81) {
    int i = blockIdx.x * 256 + threadIdx.x;
    const float* X; uint32_t* Y; int j;
    if (i < n80)            { X = X0; Y = Y0; j = i; }
    else if (i < n80 + n81) { X = X1; Y = Y1; j = i - n80; }
    else return;
    float4 v0 = *(const float4*)(X + (size_t)j * 8);
    float4 v1 = *(const float4*)(X + (size_t)j * 8 + 4);
    uint4 o;
    o.x = rne2(v0.x, v0.y); o.y = rne2(v0.z, v0.w);
    o.z = rne2(v1.x, v1.y); o.w = rne2(v1.z, v1.w);
    *(uint4*)(Y + (size_t)j * 4) = o;
}

// ---- quad-edge gather mean: 1 wave per row, uint4/lane = 4 edges/load ----
// group g=lane>>4 handles edge e+g; sublane t=lane&15 holds elems 8t..8t+7.
__device__ __forceinline__ void agg_row_quad(const uint32_t* __restrict__ X,
                                             const int* __restrict__ off,
                                             const int* __restrict__ col,
                                             uint32_t* __restrict__ Y, int row) {
    const int lane = threadIdx.x & 63;
    const int g = lane >> 4, t = lane & 15;
    const int e0 = off[row], e1 = off[row + 1];
    float accA[8] = {0.f, 0.f, 0.f, 0.f, 0.f, 0.f, 0.f, 0.f};
    float accB[8] = {0.f, 0.f, 0.f, 0.f, 0.f, 0.f, 0.f, 0.f};
    int e = e0;
    for (; e + 8 <= e1; e += 8) {
        int sA = col[e + g];
        int sB = col[e + 4 + g];
        uint4 qA = *(const uint4*)(X + (size_t)sA * 64 + (t << 2));
        uint4 qB = *(const uint4*)(X + (size_t)sB * 64 + (t << 2));
        accA[0] += blo(qA.x); accA[1] += bhi(qA.x);
        accA[2] += blo(qA.y); accA[3] += bhi(qA.y);
        accA[4] += blo(qA.z); accA[5] += bhi(qA.z);
        accA[6] += blo(qA.w); accA[7] += bhi(qA.w);
        accB[0] += blo(qB.x); accB[1] += bhi(qB.x);
        accB[2] += blo(qB.y); accB[3] += bhi(qB.y);
        accB[4] += blo(qB.z); accB[5] += bhi(qB.z);
        accB[6] += blo(qB.w); accB[7] += bhi(qB.w);
    }
    if (e + 4 <= e1) {
        int s = col[e + g];
        uint4 q = *(const uint4*)(X + (size_t)s * 64 + (t << 2));
        accA[0] += blo(q.x); accA[1] += bhi(q.x);
        accA[2] += blo(q.y); accA[3] += bhi(q.y);
        accA[4] += blo(q.z); accA[5] += bhi(q.z);
        accA[6] += blo(q.w); accA[7] += bhi(q.w);
        e += 4;
    }
    if (e < e1) {
        int idx = e + g;
        bool valid = idx < e1;
        int s = col[valid ? idx : e1 - 1];
        uint4 q = *(const uint4*)(X + (size_t)s * 64 + (t << 2));
        if (valid) {
            accB[0] += blo(q.x); accB[1] += bhi(q.x);
            accB[2] += blo(q.y); accB[3] += bhi(q.y);
            accB[4] += blo(q.z); accB[5] += bhi(q.z);
            accB[6] += blo(q.w); accB[7] += bhi(q.w);
        }
    }
    const int deg = e1 - e0;
    const float inv = 1.0f / (float)(deg > 0 ? deg : 1);
    float a[8];
#pragma unroll
    for (int j = 0; j < 8; ++j) {
        float v = accA[j] + accB[j];
        v += __shfl_xor(v, 16, 64);
        v += __shfl_xor(v, 32, 64);
        a[j] = v * inv;
    }
    if (g == 0) {
        uint4 o;
        o.x = rne2(a[0], a[1]); o.y = rne2(a[2], a[3]);
        o.z = rne2(a[4], a[5]); o.w = rne2(a[6], a[7]);
        *(uint4*)(Y + (size_t)row * 64 + (t << 2)) = o;
    }
}

// L1: all 3 relations in one dispatch (rows: NP cites | NP ao | NA ha)
__global__ __launch_bounds__(256)
void agg_l1_kernel(const uint32_t* __restrict__ xb_p, const uint32_t* __restrict__ xb_a,
                   const int* __restrict__ off_c, const int* __restrict__ col_c,
                   const int* __restrict__ off_a, const int* __restrict__ col_a,
                   const int* __restrict__ off_h, const int* __restrict__ col_h,
                   uint32_t* __restrict__ S1, uint32_t* __restrict__ S2,
                   uint32_t* __restrict__ SH, int NP, int NA) {
    int gw = (blockIdx.x * 256 + threadIdx.x) >> 6;
    if (gw < NP)               agg_row_quad(xb_p, off_c, col_c, S1, gw);
    else if (gw < 2 * NP)      agg_row_quad(xb_a, off_a, col_a, S2, gw - NP);
    else if (gw < 2 * NP + NA) agg_row_quad(xb_p, off_h, col_h, SH, gw - 2 * NP);
}

// L2: both relations in one dispatch (rows: NP cites-from-p1 | NP ao-from-a1)
__global__ __launch_bounds__(256)
void agg_l2_kernel(const uint32_t* __restrict__ P1, const uint32_t* __restrict__ A1,
                   const int* __restrict__ off_c, const int* __restrict__ col_c,
                   const int* __restrict__ off_a, const int* __restrict__ col_a,
                   uint32_t* __restrict__ S2, uint32_t* __restrict__ S3, int NP) {
    int gw = (blockIdx.x * 256 + threadIdx.x) >> 6;
    if (gw < NP)          agg_row_quad(P1, off_c, col_c, S2, gw);
    else if (gw < 2 * NP) agg_row_quad(A1, off_a, col_a, S3, gw - NP);
}

__device__ __forceinline__ void split_store(float w, unsigned short* hi,
                                            unsigned short* lo, int i) {
    uint32_t u = __float_as_uint(w);
    hi[i] = (unsigned short)(u >> 16);
    float l = w - __uint_as_float(u & 0xFFFF0000u);
    lo[i] = (unsigned short)(__float_as_uint(l) >> 16);
}

// W[0]=0.5*cWl, W[1]=0.5*aWl, W[2]=0.5*(cWr+aWr); b=0.5*(cbl+abl); hi/lo bf16
__global__ __launch_bounds__(256)
void prep_w3_kernel(const float* __restrict__ cWl, const float* __restrict__ cbl,
                    const float* __restrict__ cWr,
                    const float* __restrict__ aWl, const float* __restrict__ abl,
                    const float* __restrict__ aWr,
                    unsigned short* __restrict__ Whi, unsigned short* __restrict__ Wlo,
                    float* __restrict__ b) {
    int i = blockIdx.x * 256 + threadIdx.x;
    if (i < 16384) {
        split_store(0.5f * cWl[i], Whi, Wlo, i);
        split_store(0.5f * aWl[i], Whi, Wlo, 16384 + i);
        split_store(0.5f * (cWr[i] + aWr[i]), Whi, Wlo, 32768 + i);
    }
    if (i < 128) b[i] = 0.5f * (cbl[i] + abl[i]);
}

__global__ __launch_bounds__(256)
void prep_w2_kernel(const float* __restrict__ Wl, const float* __restrict__ Wr,
                    unsigned short* __restrict__ Whi, unsigned short* __restrict__ Wlo) {
    int i = blockIdx.x * 256 + threadIdx.x;
    if (i < 16384) {
        split_store(Wl[i], Whi, Wlo, i);
        split_store(Wr[i], Whi, Wlo, 16384 + i);
    }
}

// Y[i,:] = relu( sum_p A_p[i,:] @ W_p^T + bias ); A bf16, W hi/lo split.
// Block: 4 waves x 32 rows = 128 rows x 128 cols; W(p) staged into
// XOR-swizzled LDS (swizzle on the GLOBAL source + matching ds_read).
template <int PAIRS>
__global__ __launch_bounds__(256, 2)
void transform_mfma(const unsigned short* A0, const unsigned short* A1,
                    const unsigned short* A2,
                    const unsigned short* __restrict__ Whi,
                    const unsigned short* __restrict__ Wlo,
                    const float* __restrict__ bias, unsigned short* Y, int N) {
    __shared__ unsigned short Bhi[128 * 128];   // 32 KB, swizzled rows
    __shared__ unsigned short Blo[128 * 128];   // 32 KB, swizzled rows
    const int tid  = threadIdx.x;
    const int l    = tid & 63;
    const int wv   = tid >> 6;          // wave 0..3
    const int lrow = l & 15;
    const int lkg  = l >> 4;            // 0..3
    const int rw   = blockIdx.x * 128 + wv * 32;

    f32x4 acc0[8], acc1[8];
#pragma unroll
    for (int t = 0; t < 8; ++t) {
        acc0[t] = (f32x4){0.f, 0.f, 0.f, 0.f};
        acc1[t] = (f32x4){0.f, 0.f, 0.f, 0.f};
    }

    int arow0 = rw + lrow;      if (arow0 >= N) arow0 = N - 1;
    int arow1 = rw + 16 + lrow; if (arow1 >= N) arow1 = N - 1;
    const int kbase = lkg << 3;         // elem offset of this lane's k-octet
    const int cb    = lkg << 4;         // byte offset of this lane's k-octet

#pragma unroll 1
    for (int p = 0; p < PAIRS; ++p) {
        // ---- stage W(p): 32 KB hi + 32 KB lo, pre-swizzled source ----
        {
            const char* srcH = (const char*)(Whi + (p << 14));
            const char* srcL = (const char*)(Wlo + (p << 14));
#pragma unroll
            for (int it = 0; it < 8; ++it) {
                const int L   = it * 4096 + tid * 16;       // linear LDS byte
                const int j   = L >> 8;                     // W row
                const int g   = (j << 8) + ((L & 255) ^ ((j & 7) << 4));
                gload_lds16(srcH + g, (char*)Bhi + L);
                gload_lds16(srcL + g, (char*)Blo + L);
            }
        }
        __syncthreads();
        const unsigned short* A = (p == 0) ? A0 : (p == 1) ? A1 : A2;
#pragma unroll
        for (int kc = 0; kc < 4; ++kc) {
            bf16x8 a0 = *(const bf16x8*)(A + (size_t)arow0 * 128 + kc * 32 + kbase);
            bf16x8 a1 = *(const bf16x8*)(A + (size_t)arow1 * 128 + kc * 32 + kbase);
            const int cbk = kc * 64 + cb;
#pragma unroll
            for (int t = 0; t < 8; ++t) {
                const int jt   = (t << 4) + lrow;
                const int addr = (jt << 8) + (cbk ^ ((jt & 7) << 4));
                bf16x8 bh = *(const bf16x8*)((const char*)Bhi + addr);
                bf16x8 bl = *(const bf16x8*)((const char*)Blo + addr);
                acc0[t] = mfma16(a0, bh, acc0[t]);
                acc1[t] = mfma16(a1, bh, acc1[t]);
                acc0[t] = mfma16(a0, bl, acc0[t]);
                acc1[t] = mfma16(a1, bl, acc1[t]);
            }
        }
        __syncthreads();
    }
#pragma unroll
    for (int t = 0; t < 8; ++t) {
        const int c = t * 16 + lrow;
        const float bv = bias[c];
#pragma unroll
        for (int r = 0; r < 4; ++r) {
            int row0 = rw + (lkg << 2) + r;
            if (row0 < N)
                Y[(size_t)row0 * 128 + c] =
                    (unsigned short)rne_bf16(fmaxf(acc0[t][r] + bv, 0.f));
            int row1 = row0 + 16;
            if (row1 < N)
                Y[(size_t)row1 * 128 + c] =
                    (unsigned short)rne_bf16(fmaxf(acc1[t][r] + bv, 0.f));
        }
    }
}

__global__ __launch_bounds__(256)
void final_linear_kernel(const uint32_t* __restrict__ P, const float* __restrict__ Wt,
                         const float* __restrict__ bb, float* __restrict__ out, int N) {
    __shared__ float lw[1024];
    __shared__ float lb[8];
    for (int i = threadIdx.x; i < 1024; i += 256) lw[i] = Wt[i];
    if (threadIdx.x < 8) lb[threadIdx.x] = bb[threadIdx.x];
    __syncthreads();
    int idx = blockIdx.x * 256 + threadIdx.x;
    if (idx >= N * 8) return;
    int row = idx >> 3, c = idx & 7;
    const uint32_t* pr = P + (size_t)row * 64;   // 64 uints = 128 bf16
    const float* wr = &lw[c << 7];
    float s = 0.f;
#pragma unroll
    for (int k = 0; k < 64; k += 4) {
        uint4 q = *(const uint4*)(pr + k);
        const float* w = wr + (k << 1);
        s += blo(q.x) * w[0] + bhi(q.x) * w[1]
           + blo(q.y) * w[2] + bhi(q.y) * w[3]
           + blo(q.z) * w[4] + bhi(q.z) * w[5]
           + blo(q.w) * w[6] + bhi(q.w) * w[7];
    }
    out[idx] = s + lb[c];
}

extern "C" void kernel_launch(void* const* d_in, const int* in_sizes, int n_in,
                              void* d_out, int out_size, void* d_ws, size_t ws_size,
                              hipStream_t stream) {
    const float* x_p = (const float*)d_in[0];
    const float* x_a = (const float*)d_in[1];
    const int* c_src = (const int*)d_in[2];
    const int* c_dst = (const int*)d_in[3];
    const int* a_src = (const int*)d_in[4];
    const int* a_dst = (const int*)d_in[5];
    const int* h_src = (const int*)d_in[6];
    const int* h_dst = (const int*)d_in[7];
    const float* l1c_Wl = (const float*)d_in[8];
    const float* l1c_bl = (const float*)d_in[9];
    const float* l1c_Wr = (const float*)d_in[10];
    const float* l1a_Wl = (const float*)d_in[11];
    const float* l1a_bl = (const float*)d_in[12];
    const float* l1a_Wr = (const float*)d_in[13];
    const float* l1h_Wl = (const float*)d_in[14];
    const float* l1h_bl = (const float*)d_in[15];
    const float* l1h_Wr = (const float*)d_in[16];
    const float* l2c_Wl = (const float*)d_in[17];
    const float* l2c_bl = (const float*)d_in[18];
    const float* l2c_Wr = (const float*)d_in[19];
    const float* l2a_Wl = (const float*)d_in[20];
    const float* l2a_bl = (const float*)d_in[21];
    const float* l2a_Wr = (const float*)d_in[22];
    const float* linW   = (const float*)d_in[26];
    const float* linb   = (const float*)d_in[27];

    const int NP = in_sizes[0] / 128;
    const int NA = in_sizes[1] / 128;
    const int Ec = in_sizes[2];
    const int Ea = in_sizes[4];
    const int Eh = in_sizes[6];

    // ---- carve workspace ----
    char* base = (char*)d_ws;
    size_t cur = 0;
    auto carve = [&](size_t bytes) -> char* {
        char* p = base + cur;
        cur = (cur + bytes + 255) & ~(size_t)255;
        return p;
    };
    uint32_t* xb_p = (uint32_t*)carve((size_t)NP * 128 * 2);  // bf16 x_patent
    uint32_t* xb_a = (uint32_t*)carve((size_t)NA * 128 * 2);  // bf16 x_author
    uint32_t* S1 = (uint32_t*)carve((size_t)NP * 128 * 2);    // agg_c1 -> p1 (in place)
    uint32_t* S2 = (uint32_t*)carve((size_t)NP * 128 * 2);    // agg_a1 -> agg_c2 -> p2
    uint32_t* S3 = (uint32_t*)carve((size_t)NP * 128 * 2);    // agg_a2
    uint32_t* SH = (uint32_t*)carve((size_t)NA * 128 * 2);    // agg_h1 -> a1 (in place)
    unsigned short* W1hi = (unsigned short*)carve(3 * 16384 * 2);
    unsigned short* W1lo = (unsigned short*)carve(3 * 16384 * 2);
    unsigned short* W2hi = (unsigned short*)carve(3 * 16384 * 2);
    unsigned short* W2lo = (unsigned short*)carve(3 * 16384 * 2);
    unsigned short* WHhi = (unsigned short*)carve(2 * 16384 * 2);
    unsigned short* WHlo = (unsigned short*)carve(2 * 16384 * 2);
    float* b1 = (float*)carve(512);
    float* b2 = (float*)carve(512);
    int* off_c = (int*)carve((size_t)(NP + 1) * 4);
    int* off_a = (int*)carve((size_t)(NP + 1) * 4);
    int* off_h = (int*)carve((size_t)(NA + 1) * 4);
    int* col_c = (int*)carve((size_t)Ec * 4);
    int* col_a = (int*)carve((size_t)Ea * 4);
    int* col_h = (int*)carve((size_t)Eh * 4);
    int* bsum  = (int*)carve(4096);
    char* cntBase = base + cur;
    int* cnt_c = (int*)carve((size_t)NP * 4);
    int* cnt_a = (int*)carve((size_t)NP * 4);
    int* cnt_h = (int*)carve((size_t)NA * 4);
    size_t cntBytes = (size_t)((base + cur) - cntBase);
    if (cur > ws_size) return;

    const int nb_c = (NP + 1023) / 1024;
    const int nb_a = (NP + 1023) / 1024;
    const int nb_h = (NA + 1023) / 1024;
    const int nb_tot = nb_c + nb_a + nb_h;
    const int Etot = Ec + Ea + Eh;

    // ---- CSR build (reused by both layers) ----
    hipMemsetAsync(cntBase, 0, cntBytes, stream);
    hist3_kernel<<<(Etot + 255) / 256, 256, 0, stream>>>(c_dst, Ec, a_dst, Ea, h_dst, Eh,
                                                         cnt_c, cnt_a, cnt_h);
    scan_bsum_kernel<<<nb_tot, 256, 0, stream>>>(cnt_c, NP, nb_c, cnt_a, NP, nb_a,
                                                 cnt_h, NA, nb_h, bsum);
    scan_spine_kernel<<<3, 256, 0, stream>>>(nb_c, nb_a, nb_h, bsum,
                                             off_c, NP, off_a, NP, off_h, NA);
    scan_write_kernel<<<nb_tot, 256, 0, stream>>>(cnt_c, off_c, NP, nb_c,
                                                  cnt_a, off_a, NP, nb_a,
                                                  cnt_h, off_h, NA, nb_h, bsum);
    hipMemsetAsync(cntBase, 0, cntBytes, stream);
    fill3_kernel<<<(Etot + 255) / 256, 256, 0, stream>>>(
        c_src, c_dst, Ec, off_c, cnt_c, col_c,
        a_src, a_dst, Ea, off_a, cnt_a, col_a,
        h_src, h_dst, Eh, off_h, cnt_h, col_h);

    // ---- x -> bf16 tables; weights -> split-bf16 hi/lo ----
    cvt2_bf16_kernel<<<((NP + NA) * 16 + 255) / 256, 256, 0, stream>>>(
        x_p, xb_p, NP * 16, x_a, xb_a, NA * 16);
    prep_w3_kernel<<<64, 256, 0, stream>>>(l1c_Wl, l1c_bl, l1c_Wr,
                                           l1a_Wl, l1a_bl, l1a_Wr, W1hi, W1lo, b1);
    prep_w3_kernel<<<64, 256, 0, stream>>>(l2c_Wl, l2c_bl, l2c_Wr,
                                           l2a_Wl, l2a_bl, l2a_Wr, W2hi, W2lo, b2);
    prep_w2_kernel<<<64, 256, 0, stream>>>(l1h_Wl, l1h_Wr, WHhi, WHlo);

    // ---- layer 1: all 3 aggs in one dispatch ----
    const int rows_l1 = 2 * NP + NA;
    agg_l1_kernel<<<(rows_l1 + 3) / 4, 256, 0, stream>>>(
        xb_p, xb_a, off_c, col_c, off_a, col_a, off_h, col_h, S1, S2, SH, NP, NA);
    transform_mfma<3><<<(NP + 127) / 128, 256, 0, stream>>>(
        (const unsigned short*)S1, (const unsigned short*)S2,
        (const unsigned short*)xb_p, W1hi, W1lo, b1,
        (unsigned short*)S1, NP);                             // p1 (in place)
    transform_mfma<2><<<(NA + 127) / 128, 256, 0, stream>>>(
        (const unsigned short*)SH, (const unsigned short*)xb_a, nullptr,
        WHhi, WHlo, l1h_bl, (unsigned short*)SH, NA);         // a1 (in place)

    // ---- layer 2: both aggs in one dispatch ----
    agg_l2_kernel<<<(2 * NP + 3) / 4, 256, 0, stream>>>(
        S1, SH, off_c, col_c, off_a, col_a, S2, S3, NP);
    transform_mfma<3><<<(NP + 127) / 128, 256, 0, stream>>>(
        (const unsigned short*)S2, (const unsigned short*)S3,
        (const unsigned short*)S1, W2hi, W2lo, b2,
        (unsigned short*)S2, NP);                             // p2 (in place)

    // ---- head ----
    final_linear_kernel<<<((NP * 8) + 255) / 256, 256, 0, stream>>>(
        S2, linW, linb, (float*)d_out, NP);
}

// Round 8
// 314.096 us; speedup vs baseline: 58.1126x; 1.3885x over previous
//
#include <hip/hip_runtime.h>
#include <hip/hip_bf16.h>
#include <cstdint>

// ---------------------------------------------------------------------------
// FullHeteroGCN: 2-layer hetero GraphSAGE (mean aggr).
// R8: CSR build via bucket radix-partition (dst>>7). R7's fill3 was the top
// dispatch (106us): 1.8M device-scope atomic-with-return + random 4B scatter
// (WRITE 123MB for 7.2MB logical = 17x line amplification). New pipeline
// moves the random work into LDS: bucket_hist (LDS hist, ~170k global
// atomics) -> bucket_scan -> partition (LDS sort by bucket, grouped writes)
// -> bucket_build (per-128-dst block: LDS count/scan/scatter, coalesced
// off/col writes, zero global atomics).
// Activations bf16 (RNE), quad-edge gather aggs; weights hi/lo split-bf16
// (2 MFMA/tile) with XOR-swizzled LDS staging; f32 accumulation everywhere.
// ---------------------------------------------------------------------------

typedef __attribute__((ext_vector_type(8))) short bf16x8;
typedef __attribute__((ext_vector_type(4))) float f32x4;

#define HB 2048          // max total buckets (LDS arrays); totB = 1564 here
#define BCAP 6144        // bucket_build col staging capacity (edges)

__device__ __forceinline__ void gload_lds16(const void* g, void* l) {
    __builtin_amdgcn_global_load_lds(
        (const __attribute__((address_space(1))) unsigned int*)g,
        (__attribute__((address_space(3))) unsigned int*)l,
        16, 0, 0);
}
__device__ __forceinline__ f32x4 mfma16(bf16x8 a, bf16x8 b, f32x4 c) {
    return __builtin_amdgcn_mfma_f32_16x16x32_bf16(a, b, c, 0, 0, 0);
}
__device__ __forceinline__ uint32_t rne_bf16(float x) {
    uint32_t u = __float_as_uint(x);
    u += 0x7FFFu + ((u >> 16) & 1u);
    return u >> 16;
}
__device__ __forceinline__ uint32_t rne2(float lo, float hi) {
    return rne_bf16(lo) | (rne_bf16(hi) << 16);
}
__device__ __forceinline__ float blo(uint32_t v) { return __uint_as_float(v << 16); }
__device__ __forceinline__ float bhi(uint32_t v) { return __uint_as_float(v & 0xFFFF0000u); }

// ======================= CSR build (bucket partition) =======================

__global__ __launch_bounds__(256)
void bucket_hist_kernel(const int* __restrict__ dc, int Ec,
                        const int* __restrict__ da, int Ea,
                        const int* __restrict__ dh, int Eh,
                        int nbc, int nba, int totB, int* __restrict__ bcnt) {
    __shared__ int lh[HB];
    const int tid = threadIdx.x;
    for (int b = tid; b < HB; b += 256) lh[b] = 0;
    __syncthreads();
    const int Etot = Ec + Ea + Eh;
    const int start = blockIdx.x * 16384;
    const int end = min(start + 16384, Etot);
    for (int i = start + tid; i < end; i += 256) {
        int bin;
        if (i < Ec)            bin = dc[i] >> 7;
        else if (i < Ec + Ea)  bin = nbc + (da[i - Ec] >> 7);
        else                   bin = nbc + nba + (dh[i - Ec - Ea] >> 7);
        atomicAdd(&lh[bin], 1);
    }
    __syncthreads();
    for (int b = tid; b < totB; b += 256) {
        int v = lh[b];
        if (v) atomicAdd(&bcnt[b], v);
    }
}

// 3 blocks (one per relation): exclusive scan of bucket counts with base
// offsets; writes gboff (concatenated-edge-space) and partition cursors.
__global__ __launch_bounds__(256)
void bucket_scan_kernel(const int* __restrict__ bcnt, int nbc, int nba, int nbh,
                        int Ec, int Ea, int Eh,
                        int* __restrict__ gboff, int* __restrict__ bcur) {
    const int r  = blockIdx.x;
    const int sb = (r == 0) ? 0 : (r == 1) ? nbc : nbc + nba;
    const int nb = (r == 0) ? nbc : (r == 1) ? nba : nbh;
    const int base = (r == 0) ? 0 : (r == 1) ? Ec : Ec + Ea;
    const int tid = threadIdx.x;
    __shared__ int sm[256];
    __shared__ int carry;
    if (tid == 0) carry = base;
    __syncthreads();
    for (int c0 = 0; c0 < nb; c0 += 256) {
        int i = c0 + tid;
        int v = (i < nb) ? bcnt[sb + i] : 0;
        sm[tid] = v; __syncthreads();
        for (int d = 1; d < 256; d <<= 1) {
            int t = (tid >= d) ? sm[tid - d] : 0;
            __syncthreads();
            sm[tid] += t;
            __syncthreads();
        }
        int pre = carry + sm[tid] - v;
        if (i < nb) { gboff[sb + i] = pre; bcur[sb + i] = pre; }
        int tot = sm[255];
        __syncthreads();
        if (tid == 0) carry += tot;
        __syncthreads();
    }
    if (tid == 0 && r == 2) gboff[nbc + nba + nbh] = Ec + Ea + Eh;
}

// Each block: 2048 edges -> LDS sort by bucket -> grouped global writes of
// (src,dst) pairs into reserved per-bucket ranges.
__global__ __launch_bounds__(256)
void partition_kernel(const int* __restrict__ sc, const int* __restrict__ dc, int Ec,
                      const int* __restrict__ sa, const int* __restrict__ da, int Ea,
                      const int* __restrict__ sh, const int* __restrict__ dh, int Eh,
                      int nbc, int nba, int totB,
                      int* __restrict__ bcur, uint2* __restrict__ pairs) {
    __shared__ int lbin[HB];            // counts -> exclusive offsets -> cursors
    __shared__ int gbase[HB];
    __shared__ int swork[256];
    __shared__ uint2 sorted[2048];
    __shared__ unsigned short sbin[2048];
    const int tid = threadIdx.x;
    const int Etot = Ec + Ea + Eh;
    const int start = blockIdx.x * 2048;
    const int cnt = min(2048, Etot - start);
    for (int b = tid; b < HB; b += 256) lbin[b] = 0;
    __syncthreads();
    uint32_t esrc[8], edst[8]; int ebin[8];
#pragma unroll
    for (int k = 0; k < 8; ++k) {
        int i = start + k * 256 + tid;
        int bin = -1; uint32_t s = 0, d = 0;
        if (i < Etot) {
            if (i < Ec)           { s = sc[i];           d = dc[i];           bin = (int)(d >> 7); }
            else if (i < Ec + Ea) { s = sa[i - Ec];      d = da[i - Ec];      bin = nbc + (int)(d >> 7); }
            else                  { s = sh[i - Ec - Ea]; d = dh[i - Ec - Ea]; bin = nbc + nba + (int)(d >> 7); }
            atomicAdd(&lbin[bin], 1);
        }
        esrc[k] = s; edst[k] = d; ebin[k] = bin;
    }
    __syncthreads();
    // exclusive scan over lbin[0..HB) (8 bins/thread + block scan of sums)
    const int base8 = tid * 8;
    int lv[8]; int s0 = 0;
#pragma unroll
    for (int j = 0; j < 8; ++j) { lv[j] = lbin[base8 + j]; s0 += lv[j]; }
    swork[tid] = s0; __syncthreads();
    for (int d = 1; d < 256; d <<= 1) {
        int t = (tid >= d) ? swork[tid - d] : 0;
        __syncthreads();
        swork[tid] += t;
        __syncthreads();
    }
    int run = swork[tid] - s0;
    __syncthreads();                     // all reads of counts done
#pragma unroll
    for (int j = 0; j < 8; ++j) { lbin[base8 + j] = run; run += lv[j]; }
    __syncthreads();
    // reserve global ranges: gbase = g - localoff  (count from offset diff)
    for (int b = tid; b < totB; b += 256) {
        int off = lbin[b];
        int c = lbin[b + 1] - off;       // totB < HB so b+1 is valid
        if (c > 0) gbase[b] = atomicAdd(&bcur[b], c) - off;
    }
    __syncthreads();
    // scatter into LDS sorted order (consumes lbin as cursor)
#pragma unroll
    for (int k = 0; k < 8; ++k) {
        if (ebin[k] >= 0) {
            int p = atomicAdd(&lbin[ebin[k]], 1);
            sorted[p] = make_uint2(esrc[k], edst[k]);
            sbin[p] = (unsigned short)ebin[k];
        }
    }
    __syncthreads();
    for (int p = tid; p < cnt; p += 256)
        pairs[gbase[sbin[p]] + p] = sorted[p];
}

// One block per bucket (<=128 dsts): LDS count/scan -> off; LDS scatter ->
// coalesced col write. No global atomics.
__global__ __launch_bounds__(256)
void bucket_build_kernel(const uint2* __restrict__ pairs,
                         const int* __restrict__ gboff,
                         int nbc, int nba,
                         int NP, int NA, int Ec, int Ea, int Eh,
                         int* __restrict__ off_c, int* __restrict__ off_a,
                         int* __restrict__ off_h, int* __restrict__ colAll) {
    const int bin = blockIdx.x;
    int k, base, n, Er; int* off;
    if (bin < nbc)            { k = bin;             base = 0;       n = NP; Er = Ec; off = off_c; }
    else if (bin < nbc + nba) { k = bin - nbc;       base = Ec;      n = NP; Er = Ea; off = off_a; }
    else                      { k = bin - nbc - nba; base = Ec + Ea; n = NA; Er = Eh; off = off_h; }
    const int d0 = k << 7;
    const int e0 = gboff[bin], e1 = gboff[bin + 1];
    const int cnt = e1 - e0;
    const int tid = threadIdx.x;
    __shared__ int lcnt[128];
    __shared__ int lcur[128];
    __shared__ int colbuf[BCAP];
    if (tid < 128) lcnt[tid] = 0;
    __syncthreads();
    for (int e = e0 + tid; e < e1; e += 256)
        atomicAdd(&lcnt[pairs[e].y - d0], 1);
    __syncthreads();
    // inclusive scan over 128
    for (int d = 1; d < 128; d <<= 1) {
        int t = (tid < 128 && tid >= d) ? lcnt[tid - d] : 0;
        __syncthreads();
        if (tid < 128) lcnt[tid] += t;
        __syncthreads();
    }
    if (tid < 128) {
        int excl = tid ? lcnt[tid - 1] : 0;
        lcur[tid] = excl;
        int d = d0 + tid;
        if (d < n) off[d] = (e0 - base) + excl;
    }
    if (tid == 0 && d0 + 128 >= n) off[n] = Er;
    __syncthreads();
    if (cnt <= BCAP) {
        for (int e = e0 + tid; e < e1; e += 256) {
            uint2 pr = pairs[e];
            int p = atomicAdd(&lcur[pr.y - d0], 1);
            colbuf[p] = (int)pr.x;
        }
        __syncthreads();
        for (int i = tid; i < cnt; i += 256) colAll[e0 + i] = colbuf[i];
    } else {                              // overflow fallback (never on random data)
        for (int e = e0 + tid; e < e1; e += 256) {
            uint2 pr = pairs[e];
            int p = atomicAdd(&lcur[pr.y - d0], 1);
            colAll[e0 + p] = (int)pr.x;
        }
    }
}

// ======================= dtype prep =======================

__global__ __launch_bounds__(256)
void cvt2_bf16_kernel(const float* __restrict__ X0, uint32_t* __restrict__ Y0, int n80,
                      const float* __restrict__ X1, uint32_t* __restrict__ Y1, int n81) {
    int i = blockIdx.x * 256 + threadIdx.x;
    const float* X; uint32_t* Y; int j;
    if (i < n80)            { X = X0; Y = Y0; j = i; }
    else if (i < n80 + n81) { X = X1; Y = Y1; j = i - n80; }
    else return;
    float4 v0 = *(const float4*)(X + (size_t)j * 8);
    float4 v1 = *(const float4*)(X + (size_t)j * 8 + 4);
    uint4 o;
    o.x = rne2(v0.x, v0.y); o.y = rne2(v0.z, v0.w);
    o.z = rne2(v1.x, v1.y); o.w = rne2(v1.z, v1.w);
    *(uint4*)(Y + (size_t)j * 4) = o;
}

__device__ __forceinline__ void split_store(float w, unsigned short* hi,
                                            unsigned short* lo, int i) {
    uint32_t u = __float_as_uint(w);
    hi[i] = (unsigned short)(u >> 16);
    float l = w - __uint_as_float(u & 0xFFFF0000u);
    lo[i] = (unsigned short)(__float_as_uint(l) >> 16);
}

// all weight prep in one dispatch: blocks 0-63 W1, 64-127 W2, 128-191 WH
__global__ __launch_bounds__(256)
void prep_weights_kernel(const float* __restrict__ l1cWl, const float* __restrict__ l1cbl,
                         const float* __restrict__ l1cWr,
                         const float* __restrict__ l1aWl, const float* __restrict__ l1abl,
                         const float* __restrict__ l1aWr,
                         const float* __restrict__ l2cWl, const float* __restrict__ l2cbl,
                         const float* __restrict__ l2cWr,
                         const float* __restrict__ l2aWl, const float* __restrict__ l2abl,
                         const float* __restrict__ l2aWr,
                         const float* __restrict__ lhWl, const float* __restrict__ lhWr,
                         unsigned short* __restrict__ W1hi, unsigned short* __restrict__ W1lo,
                         float* __restrict__ b1,
                         unsigned short* __restrict__ W2hi, unsigned short* __restrict__ W2lo,
                         float* __restrict__ b2,
                         unsigned short* __restrict__ WHhi, unsigned short* __restrict__ WHlo) {
    const int bid = blockIdx.x, tid = threadIdx.x;
    if (bid < 64) {
        int i = bid * 256 + tid;
        split_store(0.5f * l1cWl[i], W1hi, W1lo, i);
        split_store(0.5f * l1aWl[i], W1hi, W1lo, 16384 + i);
        split_store(0.5f * (l1cWr[i] + l1aWr[i]), W1hi, W1lo, 32768 + i);
        if (i < 128) b1[i] = 0.5f * (l1cbl[i] + l1abl[i]);
    } else if (bid < 128) {
        int i = (bid - 64) * 256 + tid;
        split_store(0.5f * l2cWl[i], W2hi, W2lo, i);
        split_store(0.5f * l2aWl[i], W2hi, W2lo, 16384 + i);
        split_store(0.5f * (l2cWr[i] + l2aWr[i]), W2hi, W2lo, 32768 + i);
        if (i < 128) b2[i] = 0.5f * (l2cbl[i] + l2abl[i]);
    } else {
        int i = (bid - 128) * 256 + tid;
        split_store(lhWl[i], WHhi, WHlo, i);
        split_store(lhWr[i], WHhi, WHlo, 16384 + i);
    }
}

// ======================= aggregation =======================

// quad-edge gather mean: 1 wave/row, uint4/lane = 4 edges per load instr.
__device__ __forceinline__ void agg_row_quad(const uint32_t* __restrict__ X,
                                             const int* __restrict__ off,
                                             const int* __restrict__ col,
                                             uint32_t* __restrict__ Y, int row) {
    const int lane = threadIdx.x & 63;
    const int g = lane >> 4, t = lane & 15;
    const int e0 = off[row], e1 = off[row + 1];
    float accA[8] = {0.f, 0.f, 0.f, 0.f, 0.f, 0.f, 0.f, 0.f};
    float accB[8] = {0.f, 0.f, 0.f, 0.f, 0.f, 0.f, 0.f, 0.f};
    int e = e0;
    for (; e + 8 <= e1; e += 8) {
        int sA = col[e + g];
        int sB = col[e + 4 + g];
        uint4 qA = *(const uint4*)(X + (size_t)sA * 64 + (t << 2));
        uint4 qB = *(const uint4*)(X + (size_t)sB * 64 + (t << 2));
        accA[0] += blo(qA.x); accA[1] += bhi(qA.x);
        accA[2] += blo(qA.y); accA[3] += bhi(qA.y);
        accA[4] += blo(qA.z); accA[5] += bhi(qA.z);
        accA[6] += blo(qA.w); accA[7] += bhi(qA.w);
        accB[0] += blo(qB.x); accB[1] += bhi(qB.x);
        accB[2] += blo(qB.y); accB[3] += bhi(qB.y);
        accB[4] += blo(qB.z); accB[5] += bhi(qB.z);
        accB[6] += blo(qB.w); accB[7] += bhi(qB.w);
    }
    if (e + 4 <= e1) {
        int s = col[e + g];
        uint4 q = *(const uint4*)(X + (size_t)s * 64 + (t << 2));
        accA[0] += blo(q.x); accA[1] += bhi(q.x);
        accA[2] += blo(q.y); accA[3] += bhi(q.y);
        accA[4] += blo(q.z); accA[5] += bhi(q.z);
        accA[6] += blo(q.w); accA[7] += bhi(q.w);
        e += 4;
    }
    if (e < e1) {
        int idx = e + g;
        bool valid = idx < e1;
        int s = col[valid ? idx : e1 - 1];
        uint4 q = *(const uint4*)(X + (size_t)s * 64 + (t << 2));
        if (valid) {
            accB[0] += blo(q.x); accB[1] += bhi(q.x);
            accB[2] += blo(q.y); accB[3] += bhi(q.y);
            accB[4] += blo(q.z); accB[5] += bhi(q.z);
            accB[6] += blo(q.w); accB[7] += bhi(q.w);
        }
    }
    const int deg = e1 - e0;
    const float inv = 1.0f / (float)(deg > 0 ? deg : 1);
    float a[8];
#pragma unroll
    for (int j = 0; j < 8; ++j) {
        float v = accA[j] + accB[j];
        v += __shfl_xor(v, 16, 64);
        v += __shfl_xor(v, 32, 64);
        a[j] = v * inv;
    }
    if (g == 0) {
        uint4 o;
        o.x = rne2(a[0], a[1]); o.y = rne2(a[2], a[3]);
        o.z = rne2(a[4], a[5]); o.w = rne2(a[6], a[7]);
        *(uint4*)(Y + (size_t)row * 64 + (t << 2)) = o;
    }
}

__global__ __launch_bounds__(256)
void agg_l1_kernel(const uint32_t* __restrict__ xb_p, const uint32_t* __restrict__ xb_a,
                   const int* __restrict__ off_c, const int* __restrict__ col_c,
                   const int* __restrict__ off_a, const int* __restrict__ col_a,
                   const int* __restrict__ off_h, const int* __restrict__ col_h,
                   uint32_t* __restrict__ S1, uint32_t* __restrict__ S2,
                   uint32_t* __restrict__ SH, int NP, int NA) {
    int gw = (blockIdx.x * 256 + threadIdx.x) >> 6;
    if (gw < NP)               agg_row_quad(xb_p, off_c, col_c, S1, gw);
    else if (gw < 2 * NP)      agg_row_quad(xb_a, off_a, col_a, S2, gw - NP);
    else if (gw < 2 * NP + NA) agg_row_quad(xb_p, off_h, col_h, SH, gw - 2 * NP);
}

__global__ __launch_bounds__(256)
void agg_l2_kernel(const uint32_t* __restrict__ P1, const uint32_t* __restrict__ A1,
                   const int* __restrict__ off_c, const int* __restrict__ col_c,
                   const int* __restrict__ off_a, const int* __restrict__ col_a,
                   uint32_t* __restrict__ S2, uint32_t* __restrict__ S3, int NP) {
    int gw = (blockIdx.x * 256 + threadIdx.x) >> 6;
    if (gw < NP)          agg_row_quad(P1, off_c, col_c, S2, gw);
    else if (gw < 2 * NP) agg_row_quad(A1, off_a, col_a, S3, gw - NP);
}

// ======================= transform (split-bf16 MFMA) =======================

// Y[i,:] = relu( sum_p A_p[i,:] @ W_p^T + bias ); A bf16, W hi/lo split.
// Block: 4 waves x 32 rows = 128 rows x 128 cols; W(p) staged into
// XOR-swizzled LDS (swizzle on the GLOBAL source + matching ds_read).
template <int PAIRS>
__global__ __launch_bounds__(256, 2)
void transform_mfma(const unsigned short* A0, const unsigned short* A1,
                    const unsigned short* A2,
                    const unsigned short* __restrict__ Whi,
                    const unsigned short* __restrict__ Wlo,
                    const float* __restrict__ bias, unsigned short* Y, int N) {
    __shared__ unsigned short Bhi[128 * 128];   // 32 KB, swizzled rows
    __shared__ unsigned short Blo[128 * 128];   // 32 KB, swizzled rows
    const int tid  = threadIdx.x;
    const int l    = tid & 63;
    const int wv   = tid >> 6;
    const int lrow = l & 15;
    const int lkg  = l >> 4;
    const int rw   = blockIdx.x * 128 + wv * 32;

    f32x4 acc0[8], acc1[8];
#pragma unroll
    for (int t = 0; t < 8; ++t) {
        acc0[t] = (f32x4){0.f, 0.f, 0.f, 0.f};
        acc1[t] = (f32x4){0.f, 0.f, 0.f, 0.f};
    }

    int arow0 = rw + lrow;      if (arow0 >= N) arow0 = N - 1;
    int arow1 = rw + 16 + lrow; if (arow1 >= N) arow1 = N - 1;
    const int kbase = lkg << 3;
    const int cb    = lkg << 4;

#pragma unroll 1
    for (int p = 0; p < PAIRS; ++p) {
        {
            const char* srcH = (const char*)(Whi + (p << 14));
            const char* srcL = (const char*)(Wlo + (p << 14));
#pragma unroll
            for (int it = 0; it < 8; ++it) {
                const int L = it * 4096 + tid * 16;
                const int j = L >> 8;
                const int g = (j << 8) + ((L & 255) ^ ((j & 7) << 4));
                gload_lds16(srcH + g, (char*)Bhi + L);
                gload_lds16(srcL + g, (char*)Blo + L);
            }
        }
        __syncthreads();
        const unsigned short* A = (p == 0) ? A0 : (p == 1) ? A1 : A2;
#pragma unroll
        for (int kc = 0; kc < 4; ++kc) {
            bf16x8 a0 = *(const bf16x8*)(A + (size_t)arow0 * 128 + kc * 32 + kbase);
            bf16x8 a1 = *(const bf16x8*)(A + (size_t)arow1 * 128 + kc * 32 + kbase);
            const int cbk = kc * 64 + cb;
#pragma unroll
            for (int t = 0; t < 8; ++t) {
                const int jt   = (t << 4) + lrow;
                const int addr = (jt << 8) + (cbk ^ ((jt & 7) << 4));
                bf16x8 bh = *(const bf16x8*)((const char*)Bhi + addr);
                bf16x8 bl = *(const bf16x8*)((const char*)Blo + addr);
                acc0[t] = mfma16(a0, bh, acc0[t]);
                acc1[t] = mfma16(a1, bh, acc1[t]);
                acc0[t] = mfma16(a0, bl, acc0[t]);
                acc1[t] = mfma16(a1, bl, acc1[t]);
            }
        }
        __syncthreads();
    }
#pragma unroll
    for (int t = 0; t < 8; ++t) {
        const int c = t * 16 + lrow;
        const float bv = bias[c];
#pragma unroll
        for (int r = 0; r < 4; ++r) {
            int row0 = rw + (lkg << 2) + r;
            if (row0 < N)
                Y[(size_t)row0 * 128 + c] =
                    (unsigned short)rne_bf16(fmaxf(acc0[t][r] + bv, 0.f));
            int row1 = row0 + 16;
            if (row1 < N)
                Y[(size_t)row1 * 128 + c] =
                    (unsigned short)rne_bf16(fmaxf(acc1[t][r] + bv, 0.f));
        }
    }
}

__global__ __launch_bounds__(256)
void final_linear_kernel(const uint32_t* __restrict__ P, const float* __restrict__ Wt,
                         const float* __restrict__ bb, float* __restrict__ out, int N) {
    __shared__ float lw[1024];
    __shared__ float lb[8];
    for (int i = threadIdx.x; i < 1024; i += 256) lw[i] = Wt[i];
    if (threadIdx.x < 8) lb[threadIdx.x] = bb[threadIdx.x];
    __syncthreads();
    int idx = blockIdx.x * 256 + threadIdx.x;
    if (idx >= N * 8) return;
    int row = idx >> 3, c = idx & 7;
    const uint32_t* pr = P + (size_t)row * 64;
    const float* wr = &lw[c << 7];
    float s = 0.f;
#pragma unroll
    for (int k = 0; k < 64; k += 4) {
        uint4 q = *(const uint4*)(pr + k);
        const float* w = wr + (k << 1);
        s += blo(q.x) * w[0] + bhi(q.x) * w[1]
           + blo(q.y) * w[2] + bhi(q.y) * w[3]
           + blo(q.z) * w[4] + bhi(q.z) * w[5]
           + blo(q.w) * w[6] + bhi(q.w) * w[7];
    }
    out[idx] = s + lb[c];
}

extern "C" void kernel_launch(void* const* d_in, const int* in_sizes, int n_in,
                              void* d_out, int out_size, void* d_ws, size_t ws_size,
                              hipStream_t stream) {
    const float* x_p = (const float*)d_in[0];
    const float* x_a = (const float*)d_in[1];
    const int* c_src = (const int*)d_in[2];
    const int* c_dst = (const int*)d_in[3];
    const int* a_src = (const int*)d_in[4];
    const int* a_dst = (const int*)d_in[5];
    const int* h_src = (const int*)d_in[6];
    const int* h_dst = (const int*)d_in[7];
    const float* l1c_Wl = (const float*)d_in[8];
    const float* l1c_bl = (const float*)d_in[9];
    const float* l1c_Wr = (const float*)d_in[10];
    const float* l1a_Wl = (const float*)d_in[11];
    const float* l1a_bl = (const float*)d_in[12];
    const float* l1a_Wr = (const float*)d_in[13];
    const float* l1h_Wl = (const float*)d_in[14];
    const float* l1h_bl = (const float*)d_in[15];
    const float* l1h_Wr = (const float*)d_in[16];
    const float* l2c_Wl = (const float*)d_in[17];
    const float* l2c_bl = (const float*)d_in[18];
    const float* l2c_Wr = (const float*)d_in[19];
    const float* l2a_Wl = (const float*)d_in[20];
    const float* l2a_bl = (const float*)d_in[21];
    const float* l2a_Wr = (const float*)d_in[22];
    const float* linW   = (const float*)d_in[26];
    const float* linb   = (const float*)d_in[27];

    const int NP = in_sizes[0] / 128;
    const int NA = in_sizes[1] / 128;
    const int Ec = in_sizes[2];
    const int Ea = in_sizes[4];
    const int Eh = in_sizes[6];
    const int Etot = Ec + Ea + Eh;

    const int nbc = (NP + 127) >> 7;
    const int nba = (NP + 127) >> 7;
    const int nbh = (NA + 127) >> 7;
    const int totB = nbc + nba + nbh;
    if (totB > HB) return;   // loud failure; fixed problem sizes fit (1564)

    // ---- carve workspace ----
    char* base = (char*)d_ws;
    size_t cur = 0;
    auto carve = [&](size_t bytes) -> char* {
        char* p = base + cur;
        cur = (cur + bytes + 255) & ~(size_t)255;
        return p;
    };
    uint32_t* xb_p = (uint32_t*)carve((size_t)NP * 128 * 2);
    uint32_t* xb_a = (uint32_t*)carve((size_t)NA * 128 * 2);
    uint32_t* S1 = (uint32_t*)carve((size_t)NP * 128 * 2);
    uint32_t* S2 = (uint32_t*)carve((size_t)NP * 128 * 2);
    uint32_t* S3 = (uint32_t*)carve((size_t)NP * 128 * 2);
    uint32_t* SH = (uint32_t*)carve((size_t)NA * 128 * 2);
    unsigned short* W1hi = (unsigned short*)carve(3 * 16384 * 2);
    unsigned short* W1lo = (unsigned short*)carve(3 * 16384 * 2);
    unsigned short* W2hi = (unsigned short*)carve(3 * 16384 * 2);
    unsigned short* W2lo = (unsigned short*)carve(3 * 16384 * 2);
    unsigned short* WHhi = (unsigned short*)carve(2 * 16384 * 2);
    unsigned short* WHlo = (unsigned short*)carve(2 * 16384 * 2);
    float* b1 = (float*)carve(512);
    float* b2 = (float*)carve(512);
    int* off_c = (int*)carve((size_t)(NP + 1) * 4);
    int* off_a = (int*)carve((size_t)(NP + 1) * 4);
    int* off_h = (int*)carve((size_t)(NA + 1) * 4);
    int* colAll = (int*)carve((size_t)Etot * 4);
    uint2* pairs = (uint2*)carve((size_t)Etot * 8);
    int* gboff = (int*)carve((size_t)(totB + 1) * 4);
    int* bcur  = (int*)carve((size_t)totB * 4);
    int* bcnt  = (int*)carve((size_t)totB * 4);
    if (cur > ws_size) return;

    // ---- CSR build via bucket partition ----
    hipMemsetAsync(bcnt, 0, (size_t)totB * 4, stream);
    bucket_hist_kernel<<<(Etot + 16383) / 16384, 256, 0, stream>>>(
        c_dst, Ec, a_dst, Ea, h_dst, Eh, nbc, nba, totB, bcnt);
    bucket_scan_kernel<<<3, 256, 0, stream>>>(bcnt, nbc, nba, nbh, Ec, Ea, Eh,
                                              gboff, bcur);
    partition_kernel<<<(Etot + 2047) / 2048, 256, 0, stream>>>(
        c_src, c_dst, Ec, a_src, a_dst, Ea, h_src, h_dst, Eh,
        nbc, nba, totB, bcur, pairs);
    bucket_build_kernel<<<totB, 256, 0, stream>>>(
        pairs, gboff, nbc, nba, NP, NA, Ec, Ea, Eh, off_c, off_a, off_h, colAll);

    const int* col_c = colAll;
    const int* col_a = colAll + Ec;
    const int* col_h = colAll + Ec + Ea;

    // ---- dtype prep ----
    cvt2_bf16_kernel<<<((NP + NA) * 16 + 255) / 256, 256, 0, stream>>>(
        x_p, xb_p, NP * 16, x_a, xb_a, NA * 16);
    prep_weights_kernel<<<192, 256, 0, stream>>>(
        l1c_Wl, l1c_bl, l1c_Wr, l1a_Wl, l1a_bl, l1a_Wr,
        l2c_Wl, l2c_bl, l2c_Wr, l2a_Wl, l2a_bl, l2a_Wr,
        l1h_Wl, l1h_Wr, W1hi, W1lo, b1, W2hi, W2lo, b2, WHhi, WHlo);

    // ---- layer 1 ----
    const int rows_l1 = 2 * NP + NA;
    agg_l1_kernel<<<(rows_l1 + 3) / 4, 256, 0, stream>>>(
        xb_p, xb_a, off_c, col_c, off_a, col_a, off_h, col_h, S1, S2, SH, NP, NA);
    transform_mfma<3><<<(NP + 127) / 128, 256, 0, stream>>>(
        (const unsigned short*)S1, (const unsigned short*)S2,
        (const unsigned short*)xb_p, W1hi, W1lo, b1,
        (unsigned short*)S1, NP);
    transform_mfma<2><<<(NA + 127) / 128, 256, 0, stream>>>(
        (const unsigned short*)SH, (const unsigned short*)xb_a, nullptr,
        WHhi, WHlo, l1h_bl, (unsigned short*)SH, NA);

    // ---- layer 2 ----
    agg_l2_kernel<<<(2 * NP + 3) / 4, 256, 0, stream>>>(
        S1, SH, off_c, col_c, off_a, col_a, S2, S3, NP);
    transform_mfma<3><<<(NP + 127) / 128, 256, 0, stream>>>(
        (const unsigned short*)S2, (const unsigned short*)S3,
        (const unsigned short*)S1, W2hi, W2lo, b2,
        (unsigned short*)S2, NP);

    // ---- head ----
    final_linear_kernel<<<((NP * 8) + 255) / 256, 256, 0, stream>>>(
        S2, linW, linb, (float*)d_out, NP);
}

// Round 9
// 304.192 us; speedup vs baseline: 60.0045x; 1.0326x over previous
//
#include <hip/hip_runtime.h>
#include <hip/hip_bf16.h>
#include <cstdint>

// ---------------------------------------------------------------------------
// FullHeteroGCN: 2-layer hetero GraphSAGE (mean aggr).
// R9: aggs are latency*parallelism bound (R8: 83us vs 20us VALU floor /
// 31us byte floor; ~2 gathers in flight per wave). agg_row_quad v2 issues
// 4 independent quad-gathers back-to-back (16-edge main loop + predicated
// tail quads) -> 3-4 loads in flight. transform_p1+transform_a1 merged into
// one dispatch (both half-grid at 2 blocks/CU).
// CSR build: bucket radix-partition (R8). Activations bf16 RNE; weights
// hi/lo split-bf16 (2 MFMA/tile), XOR-swizzled LDS staging; f32 accum.
// ---------------------------------------------------------------------------

typedef __attribute__((ext_vector_type(8))) short bf16x8;
typedef __attribute__((ext_vector_type(4))) float f32x4;

#define HB 2048          // max total buckets (LDS arrays); totB = 1564 here
#define BCAP 6144        // bucket_build col staging capacity (edges)

__device__ __forceinline__ void gload_lds16(const void* g, void* l) {
    __builtin_amdgcn_global_load_lds(
        (const __attribute__((address_space(1))) unsigned int*)g,
        (__attribute__((address_space(3))) unsigned int*)l,
        16, 0, 0);
}
__device__ __forceinline__ f32x4 mfma16(bf16x8 a, bf16x8 b, f32x4 c) {
    return __builtin_amdgcn_mfma_f32_16x16x32_bf16(a, b, c, 0, 0, 0);
}
__device__ __forceinline__ uint32_t rne_bf16(float x) {
    uint32_t u = __float_as_uint(x);
    u += 0x7FFFu + ((u >> 16) & 1u);
    return u >> 16;
}
__device__ __forceinline__ uint32_t rne2(float lo, float hi) {
    return rne_bf16(lo) | (rne_bf16(hi) << 16);
}
__device__ __forceinline__ float blo(uint32_t v) { return __uint_as_float(v << 16); }
__device__ __forceinline__ float bhi(uint32_t v) { return __uint_as_float(v & 0xFFFF0000u); }

// ======================= CSR build (bucket partition) =======================

__global__ __launch_bounds__(256)
void bucket_hist_kernel(const int* __restrict__ dc, int Ec,
                        const int* __restrict__ da, int Ea,
                        const int* __restrict__ dh, int Eh,
                        int nbc, int nba, int totB, int* __restrict__ bcnt) {
    __shared__ int lh[HB];
    const int tid = threadIdx.x;
    for (int b = tid; b < HB; b += 256) lh[b] = 0;
    __syncthreads();
    const int Etot = Ec + Ea + Eh;
    const int start = blockIdx.x * 16384;
    const int end = min(start + 16384, Etot);
    for (int i = start + tid; i < end; i += 256) {
        int bin;
        if (i < Ec)            bin = dc[i] >> 7;
        else if (i < Ec + Ea)  bin = nbc + (da[i - Ec] >> 7);
        else                   bin = nbc + nba + (dh[i - Ec - Ea] >> 7);
        atomicAdd(&lh[bin], 1);
    }
    __syncthreads();
    for (int b = tid; b < totB; b += 256) {
        int v = lh[b];
        if (v) atomicAdd(&bcnt[b], v);
    }
}

__global__ __launch_bounds__(256)
void bucket_scan_kernel(const int* __restrict__ bcnt, int nbc, int nba, int nbh,
                        int Ec, int Ea, int Eh,
                        int* __restrict__ gboff, int* __restrict__ bcur) {
    const int r  = blockIdx.x;
    const int sb = (r == 0) ? 0 : (r == 1) ? nbc : nbc + nba;
    const int nb = (r == 0) ? nbc : (r == 1) ? nba : nbh;
    const int base = (r == 0) ? 0 : (r == 1) ? Ec : Ec + Ea;
    const int tid = threadIdx.x;
    __shared__ int sm[256];
    __shared__ int carry;
    if (tid == 0) carry = base;
    __syncthreads();
    for (int c0 = 0; c0 < nb; c0 += 256) {
        int i = c0 + tid;
        int v = (i < nb) ? bcnt[sb + i] : 0;
        sm[tid] = v; __syncthreads();
        for (int d = 1; d < 256; d <<= 1) {
            int t = (tid >= d) ? sm[tid - d] : 0;
            __syncthreads();
            sm[tid] += t;
            __syncthreads();
        }
        int pre = carry + sm[tid] - v;
        if (i < nb) { gboff[sb + i] = pre; bcur[sb + i] = pre; }
        int tot = sm[255];
        __syncthreads();
        if (tid == 0) carry += tot;
        __syncthreads();
    }
    if (tid == 0 && r == 2) gboff[nbc + nba + nbh] = Ec + Ea + Eh;
}

__global__ __launch_bounds__(256)
void partition_kernel(const int* __restrict__ sc, const int* __restrict__ dc, int Ec,
                      const int* __restrict__ sa, const int* __restrict__ da, int Ea,
                      const int* __restrict__ sh, const int* __restrict__ dh, int Eh,
                      int nbc, int nba, int totB,
                      int* __restrict__ bcur, uint2* __restrict__ pairs) {
    __shared__ int lbin[HB];
    __shared__ int gbase[HB];
    __shared__ int swork[256];
    __shared__ uint2 sorted[2048];
    __shared__ unsigned short sbin[2048];
    const int tid = threadIdx.x;
    const int Etot = Ec + Ea + Eh;
    const int start = blockIdx.x * 2048;
    const int cnt = min(2048, Etot - start);
    for (int b = tid; b < HB; b += 256) lbin[b] = 0;
    __syncthreads();
    uint32_t esrc[8], edst[8]; int ebin[8];
#pragma unroll
    for (int k = 0; k < 8; ++k) {
        int i = start + k * 256 + tid;
        int bin = -1; uint32_t s = 0, d = 0;
        if (i < Etot) {
            if (i < Ec)           { s = sc[i];           d = dc[i];           bin = (int)(d >> 7); }
            else if (i < Ec + Ea) { s = sa[i - Ec];      d = da[i - Ec];      bin = nbc + (int)(d >> 7); }
            else                  { s = sh[i - Ec - Ea]; d = dh[i - Ec - Ea]; bin = nbc + nba + (int)(d >> 7); }
            atomicAdd(&lbin[bin], 1);
        }
        esrc[k] = s; edst[k] = d; ebin[k] = bin;
    }
    __syncthreads();
    const int base8 = tid * 8;
    int lv[8]; int s0 = 0;
#pragma unroll
    for (int j = 0; j < 8; ++j) { lv[j] = lbin[base8 + j]; s0 += lv[j]; }
    swork[tid] = s0; __syncthreads();
    for (int d = 1; d < 256; d <<= 1) {
        int t = (tid >= d) ? swork[tid - d] : 0;
        __syncthreads();
        swork[tid] += t;
        __syncthreads();
    }
    int run = swork[tid] - s0;
    __syncthreads();
#pragma unroll
    for (int j = 0; j < 8; ++j) { lbin[base8 + j] = run; run += lv[j]; }
    __syncthreads();
    for (int b = tid; b < totB; b += 256) {
        int off = lbin[b];
        int c = lbin[b + 1] - off;
        if (c > 0) gbase[b] = atomicAdd(&bcur[b], c) - off;
    }
    __syncthreads();
#pragma unroll
    for (int k = 0; k < 8; ++k) {
        if (ebin[k] >= 0) {
            int p = atomicAdd(&lbin[ebin[k]], 1);
            sorted[p] = make_uint2(esrc[k], edst[k]);
            sbin[p] = (unsigned short)ebin[k];
        }
    }
    __syncthreads();
    for (int p = tid; p < cnt; p += 256)
        pairs[gbase[sbin[p]] + p] = sorted[p];
}

__global__ __launch_bounds__(256)
void bucket_build_kernel(const uint2* __restrict__ pairs,
                         const int* __restrict__ gboff,
                         int nbc, int nba,
                         int NP, int NA, int Ec, int Ea, int Eh,
                         int* __restrict__ off_c, int* __restrict__ off_a,
                         int* __restrict__ off_h, int* __restrict__ colAll) {
    const int bin = blockIdx.x;
    int k, base, n, Er; int* off;
    if (bin < nbc)            { k = bin;             base = 0;       n = NP; Er = Ec; off = off_c; }
    else if (bin < nbc + nba) { k = bin - nbc;       base = Ec;      n = NP; Er = Ea; off = off_a; }
    else                      { k = bin - nbc - nba; base = Ec + Ea; n = NA; Er = Eh; off = off_h; }
    const int d0 = k << 7;
    const int e0 = gboff[bin], e1 = gboff[bin + 1];
    const int cnt = e1 - e0;
    const int tid = threadIdx.x;
    __shared__ int lcnt[128];
    __shared__ int lcur[128];
    __shared__ int colbuf[BCAP];
    if (tid < 128) lcnt[tid] = 0;
    __syncthreads();
    for (int e = e0 + tid; e < e1; e += 256)
        atomicAdd(&lcnt[pairs[e].y - d0], 1);
    __syncthreads();
    for (int d = 1; d < 128; d <<= 1) {
        int t = (tid < 128 && tid >= d) ? lcnt[tid - d] : 0;
        __syncthreads();
        if (tid < 128) lcnt[tid] += t;
        __syncthreads();
    }
    if (tid < 128) {
        int excl = tid ? lcnt[tid - 1] : 0;
        lcur[tid] = excl;
        int d = d0 + tid;
        if (d < n) off[d] = (e0 - base) + excl;
    }
    if (tid == 0 && d0 + 128 >= n) off[n] = Er;
    __syncthreads();
    if (cnt <= BCAP) {
        for (int e = e0 + tid; e < e1; e += 256) {
            uint2 pr = pairs[e];
            int p = atomicAdd(&lcur[pr.y - d0], 1);
            colbuf[p] = (int)pr.x;
        }
        __syncthreads();
        for (int i = tid; i < cnt; i += 256) colAll[e0 + i] = colbuf[i];
    } else {
        for (int e = e0 + tid; e < e1; e += 256) {
            uint2 pr = pairs[e];
            int p = atomicAdd(&lcur[pr.y - d0], 1);
            colAll[e0 + p] = (int)pr.x;
        }
    }
}

// ======================= dtype prep =======================

__global__ __launch_bounds__(256)
void cvt2_bf16_kernel(const float* __restrict__ X0, uint32_t* __restrict__ Y0, int n80,
                      const float* __restrict__ X1, uint32_t* __restrict__ Y1, int n81) {
    int i = blockIdx.x * 256 + threadIdx.x;
    const float* X; uint32_t* Y; int j;
    if (i < n80)            { X = X0; Y = Y0; j = i; }
    else if (i < n80 + n81) { X = X1; Y = Y1; j = i - n80; }
    else return;
    float4 v0 = *(const float4*)(X + (size_t)j * 8);
    float4 v1 = *(const float4*)(X + (size_t)j * 8 + 4);
    uint4 o;
    o.x = rne2(v0.x, v0.y); o.y = rne2(v0.z, v0.w);
    o.z = rne2(v1.x, v1.y); o.w = rne2(v1.z, v1.w);
    *(uint4*)(Y + (size_t)j * 4) = o;
}

__device__ __forceinline__ void split_store(float w, unsigned short* hi,
                                            unsigned short* lo, int i) {
    uint32_t u = __float_as_uint(w);
    hi[i] = (unsigned short)(u >> 16);
    float l = w - __uint_as_float(u & 0xFFFF0000u);
    lo[i] = (unsigned short)(__float_as_uint(l) >> 16);
}

__global__ __launch_bounds__(256)
void prep_weights_kernel(const float* __restrict__ l1cWl, const float* __restrict__ l1cbl,
                         const float* __restrict__ l1cWr,
                         const float* __restrict__ l1aWl, const float* __restrict__ l1abl,
                         const float* __restrict__ l1aWr,
                         const float* __restrict__ l2cWl, const float* __restrict__ l2cbl,
                         const float* __restrict__ l2cWr,
                         const float* __restrict__ l2aWl, const float* __restrict__ l2abl,
                         const float* __restrict__ l2aWr,
                         const float* __restrict__ lhWl, const float* __restrict__ lhWr,
                         unsigned short* __restrict__ W1hi, unsigned short* __restrict__ W1lo,
                         float* __restrict__ b1,
                         unsigned short* __restrict__ W2hi, unsigned short* __restrict__ W2lo,
                         float* __restrict__ b2,
                         unsigned short* __restrict__ WHhi, unsigned short* __restrict__ WHlo) {
    const int bid = blockIdx.x, tid = threadIdx.x;
    if (bid < 64) {
        int i = bid * 256 + tid;
        split_store(0.5f * l1cWl[i], W1hi, W1lo, i);
        split_store(0.5f * l1aWl[i], W1hi, W1lo, 16384 + i);
        split_store(0.5f * (l1cWr[i] + l1aWr[i]), W1hi, W1lo, 32768 + i);
        if (i < 128) b1[i] = 0.5f * (l1cbl[i] + l1abl[i]);
    } else if (bid < 128) {
        int i = (bid - 64) * 256 + tid;
        split_store(0.5f * l2cWl[i], W2hi, W2lo, i);
        split_store(0.5f * l2aWl[i], W2hi, W2lo, 16384 + i);
        split_store(0.5f * (l2cWr[i] + l2aWr[i]), W2hi, W2lo, 32768 + i);
        if (i < 128) b2[i] = 0.5f * (l2cbl[i] + l2abl[i]);
    } else {
        int i = (bid - 128) * 256 + tid;
        split_store(lhWl[i], WHhi, WHlo, i);
        split_store(lhWr[i], WHhi, WHlo, 16384 + i);
    }
}

// ======================= aggregation =======================

__device__ __forceinline__ void acc8(float* a, uint4 q) {
    a[0] += blo(q.x); a[1] += bhi(q.x);
    a[2] += blo(q.y); a[3] += bhi(q.y);
    a[4] += blo(q.z); a[5] += bhi(q.z);
    a[6] += blo(q.w); a[7] += bhi(q.w);
}

// quad-edge gather mean v2: 1 wave/row, uint4/lane = 4 edges per load; up to
// 4 independent quad-gathers in flight (16-edge main loop + predicated tail).
__device__ __forceinline__ void agg_row_quad(const uint32_t* __restrict__ X,
                                             const int* __restrict__ off,
                                             const int* __restrict__ col,
                                             uint32_t* __restrict__ Y, int row) {
    const int lane = threadIdx.x & 63;
    const int g = lane >> 4, t = lane & 15;
    const int e0 = off[row], e1 = off[row + 1];
    float A0[8] = {0.f, 0.f, 0.f, 0.f, 0.f, 0.f, 0.f, 0.f};
    float A1[8] = {0.f, 0.f, 0.f, 0.f, 0.f, 0.f, 0.f, 0.f};
    int e = e0;
    for (; e + 16 <= e1; e += 16) {
        int s0 = col[e + g];
        int s1 = col[e + 4 + g];
        int s2 = col[e + 8 + g];
        int s3 = col[e + 12 + g];
        uint4 q0 = *(const uint4*)(X + (size_t)s0 * 64 + (t << 2));
        uint4 q1 = *(const uint4*)(X + (size_t)s1 * 64 + (t << 2));
        uint4 q2 = *(const uint4*)(X + (size_t)s2 * 64 + (t << 2));
        uint4 q3 = *(const uint4*)(X + (size_t)s3 * 64 + (t << 2));
        acc8(A0, q0); acc8(A1, q1); acc8(A0, q2); acc8(A1, q3);
    }
    if (e < e1) {
        const int i0 = e + g, i1 = e + 4 + g, i2 = e + 8 + g, i3 = e + 12 + g;
        const bool h1 = (e + 4 < e1), h2 = (e + 8 < e1), h3 = (e + 12 < e1);
        uint4 q0, q1, q2, q3;
        q0 = *(const uint4*)(X + (size_t)col[min(i0, e1 - 1)] * 64 + (t << 2));
        if (h1) q1 = *(const uint4*)(X + (size_t)col[min(i1, e1 - 1)] * 64 + (t << 2));
        if (h2) q2 = *(const uint4*)(X + (size_t)col[min(i2, e1 - 1)] * 64 + (t << 2));
        if (h3) q3 = *(const uint4*)(X + (size_t)col[min(i3, e1 - 1)] * 64 + (t << 2));
        if (i0 < e1) acc8(A0, q0);
        if (h1 && i1 < e1) acc8(A1, q1);
        if (h2 && i2 < e1) acc8(A0, q2);
        if (h3 && i3 < e1) acc8(A1, q3);
    }
    const int deg = e1 - e0;
    const float inv = 1.0f / (float)(deg > 0 ? deg : 1);
    float a[8];
#pragma unroll
    for (int j = 0; j < 8; ++j) {
        float v = A0[j] + A1[j];
        v += __shfl_xor(v, 16, 64);
        v += __shfl_xor(v, 32, 64);
        a[j] = v * inv;
    }
    if (g == 0) {
        uint4 o;
        o.x = rne2(a[0], a[1]); o.y = rne2(a[2], a[3]);
        o.z = rne2(a[4], a[5]); o.w = rne2(a[6], a[7]);
        *(uint4*)(Y + (size_t)row * 64 + (t << 2)) = o;
    }
}

__global__ __launch_bounds__(256)
void agg_l1_kernel(const uint32_t* __restrict__ xb_p, const uint32_t* __restrict__ xb_a,
                   const int* __restrict__ off_c, const int* __restrict__ col_c,
                   const int* __restrict__ off_a, const int* __restrict__ col_a,
                   const int* __restrict__ off_h, const int* __restrict__ col_h,
                   uint32_t* __restrict__ S1, uint32_t* __restrict__ S2,
                   uint32_t* __restrict__ SH, int NP, int NA) {
    int gw = (blockIdx.x * 256 + threadIdx.x) >> 6;
    if (gw < NP)               agg_row_quad(xb_p, off_c, col_c, S1, gw);
    else if (gw < 2 * NP)      agg_row_quad(xb_a, off_a, col_a, S2, gw - NP);
    else if (gw < 2 * NP + NA) agg_row_quad(xb_p, off_h, col_h, SH, gw - 2 * NP);
}

__global__ __launch_bounds__(256)
void agg_l2_kernel(const uint32_t* __restrict__ P1, const uint32_t* __restrict__ A1,
                   const int* __restrict__ off_c, const int* __restrict__ col_c,
                   const int* __restrict__ off_a, const int* __restrict__ col_a,
                   uint32_t* __restrict__ S2, uint32_t* __restrict__ S3, int NP) {
    int gw = (blockIdx.x * 256 + threadIdx.x) >> 6;
    if (gw < NP)          agg_row_quad(P1, off_c, col_c, S2, gw);
    else if (gw < 2 * NP) agg_row_quad(A1, off_a, col_a, S3, gw - NP);
}

// ======================= transform (split-bf16 MFMA) =======================

// Y[i,:] = relu( sum_p A_p[i,:] @ W_p^T + bias ); A bf16, W hi/lo split.
// Block: 4 waves x 32 rows = 128 rows x 128 cols; W(p) staged into
// XOR-swizzled LDS (swizzle on the GLOBAL source + matching ds_read).
template <int PAIRS>
__device__ __forceinline__ void transform_body(
        int blk, const unsigned short* A0, const unsigned short* A1,
        const unsigned short* A2,
        const unsigned short* __restrict__ Whi, const unsigned short* __restrict__ Wlo,
        const float* __restrict__ bias, unsigned short* Y, int N,
        unsigned short* Bhi, unsigned short* Blo) {
    const int tid  = threadIdx.x;
    const int l    = tid & 63;
    const int wv   = tid >> 6;
    const int lrow = l & 15;
    const int lkg  = l >> 4;
    const int rw   = blk * 128 + wv * 32;

    f32x4 acc0[8], acc1[8];
#pragma unroll
    for (int t = 0; t < 8; ++t) {
        acc0[t] = (f32x4){0.f, 0.f, 0.f, 0.f};
        acc1[t] = (f32x4){0.f, 0.f, 0.f, 0.f};
    }

    int arow0 = rw + lrow;      if (arow0 >= N) arow0 = N - 1;
    int arow1 = rw + 16 + lrow; if (arow1 >= N) arow1 = N - 1;
    const int kbase = lkg << 3;
    const int cb    = lkg << 4;

#pragma unroll 1
    for (int p = 0; p < PAIRS; ++p) {
        {
            const char* srcH = (const char*)(Whi + (p << 14));
            const char* srcL = (const char*)(Wlo + (p << 14));
#pragma unroll
            for (int it = 0; it < 8; ++it) {
                const int L = it * 4096 + tid * 16;
                const int j = L >> 8;
                const int g = (j << 8) + ((L & 255) ^ ((j & 7) << 4));
                gload_lds16(srcH + g, (char*)Bhi + L);
                gload_lds16(srcL + g, (char*)Blo + L);
            }
        }
        __syncthreads();
        const unsigned short* A = (p == 0) ? A0 : (p == 1) ? A1 : A2;
#pragma unroll
        for (int kc = 0; kc < 4; ++kc) {
            bf16x8 a0 = *(const bf16x8*)(A + (size_t)arow0 * 128 + kc * 32 + kbase);
            bf16x8 a1 = *(const bf16x8*)(A + (size_t)arow1 * 128 + kc * 32 + kbase);
            const int cbk = kc * 64 + cb;
#pragma unroll
            for (int t = 0; t < 8; ++t) {
                const int jt   = (t << 4) + lrow;
                const int addr = (jt << 8) + (cbk ^ ((jt & 7) << 4));
                bf16x8 bh = *(const bf16x8*)((const char*)Bhi + addr);
                bf16x8 bl = *(const bf16x8*)((const char*)Blo + addr);
                acc0[t] = mfma16(a0, bh, acc0[t]);
                acc1[t] = mfma16(a1, bh, acc1[t]);
                acc0[t] = mfma16(a0, bl, acc0[t]);
                acc1[t] = mfma16(a1, bl, acc1[t]);
            }
        }
        __syncthreads();
    }
#pragma unroll
    for (int t = 0; t < 8; ++t) {
        const int c = t * 16 + lrow;
        const float bv = bias[c];
#pragma unroll
        for (int r = 0; r < 4; ++r) {
            int row0 = rw + (lkg << 2) + r;
            if (row0 < N)
                Y[(size_t)row0 * 128 + c] =
                    (unsigned short)rne_bf16(fmaxf(acc0[t][r] + bv, 0.f));
            int row1 = row0 + 16;
            if (row1 < N)
                Y[(size_t)row1 * 128 + c] =
                    (unsigned short)rne_bf16(fmaxf(acc1[t][r] + bv, 0.f));
        }
    }
}

// merged L1 transform: blocks [0,nbP) do p1 (3 pairs), rest do a1 (2 pairs)
__global__ __launch_bounds__(256, 2)
void transform_l1_kernel(const unsigned short* S1, const unsigned short* S2,
                         const unsigned short* xb_p,
                         const unsigned short* __restrict__ W1hi,
                         const unsigned short* __restrict__ W1lo,
                         const float* __restrict__ b1,
                         const unsigned short* SH, const unsigned short* xb_a,
                         const unsigned short* __restrict__ WHhi,
                         const unsigned short* __restrict__ WHlo,
                         const float* __restrict__ bh,
                         unsigned short* P1out, unsigned short* A1out,
                         int NP, int NA, int nbP) {
    __shared__ unsigned short Bhi[128 * 128];
    __shared__ unsigned short Blo[128 * 128];
    if ((int)blockIdx.x < nbP)
        transform_body<3>(blockIdx.x, S1, S2, xb_p, W1hi, W1lo, b1,
                          P1out, NP, Bhi, Blo);
    else
        transform_body<2>(blockIdx.x - nbP, SH, xb_a, nullptr, WHhi, WHlo, bh,
                          A1out, NA, Bhi, Blo);
}

__global__ __launch_bounds__(256, 2)
void transform_p2_kernel(const unsigned short* A0, const unsigned short* A1,
                         const unsigned short* A2,
                         const unsigned short* __restrict__ Whi,
                         const unsigned short* __restrict__ Wlo,
                         const float* __restrict__ bias, unsigned short* Y, int N) {
    __shared__ unsigned short Bhi[128 * 128];
    __shared__ unsigned short Blo[128 * 128];
    transform_body<3>(blockIdx.x, A0, A1, A2, Whi, Wlo, bias, Y, N, Bhi, Blo);
}

__global__ __launch_bounds__(256)
void final_linear_kernel(const uint32_t* __restrict__ P, const float* __restrict__ Wt,
                         const float* __restrict__ bb, float* __restrict__ out, int N) {
    __shared__ float lw[1024];
    __shared__ float lb[8];
    for (int i = threadIdx.x; i < 1024; i += 256) lw[i] = Wt[i];
    if (threadIdx.x < 8) lb[threadIdx.x] = bb[threadIdx.x];
    __syncthreads();
    int idx = blockIdx.x * 256 + threadIdx.x;
    if (idx >= N * 8) return;
    int row = idx >> 3, c = idx & 7;
    const uint32_t* pr = P + (size_t)row * 64;
    const float* wr = &lw[c << 7];
    float s = 0.f;
#pragma unroll
    for (int k = 0; k < 64; k += 4) {
        uint4 q = *(const uint4*)(pr + k);
        const float* w = wr + (k << 1);
        s += blo(q.x) * w[0] + bhi(q.x) * w[1]
           + blo(q.y) * w[2] + bhi(q.y) * w[3]
           + blo(q.z) * w[4] + bhi(q.z) * w[5]
           + blo(q.w) * w[6] + bhi(q.w) * w[7];
    }
    out[idx] = s + lb[c];
}

extern "C" void kernel_launch(void* const* d_in, const int* in_sizes, int n_in,
                              void* d_out, int out_size, void* d_ws, size_t ws_size,
                              hipStream_t stream) {
    const float* x_p = (const float*)d_in[0];
    const float* x_a = (const float*)d_in[1];
    const int* c_src = (const int*)d_in[2];
    const int* c_dst = (const int*)d_in[3];
    const int* a_src = (const int*)d_in[4];
    const int* a_dst = (const int*)d_in[5];
    const int* h_src = (const int*)d_in[6];
    const int* h_dst = (const int*)d_in[7];
    const float* l1c_Wl = (const float*)d_in[8];
    const float* l1c_bl = (const float*)d_in[9];
    const float* l1c_Wr = (const float*)d_in[10];
    const float* l1a_Wl = (const float*)d_in[11];
    const float* l1a_bl = (const float*)d_in[12];
    const float* l1a_Wr = (const float*)d_in[13];
    const float* l1h_Wl = (const float*)d_in[14];
    const float* l1h_bl = (const float*)d_in[15];
    const float* l1h_Wr = (const float*)d_in[16];
    const float* l2c_Wl = (const float*)d_in[17];
    const float* l2c_bl = (const float*)d_in[18];
    const float* l2c_Wr = (const float*)d_in[19];
    const float* l2a_Wl = (const float*)d_in[20];
    const float* l2a_bl = (const float*)d_in[21];
    const float* l2a_Wr = (const float*)d_in[22];
    const float* linW   = (const float*)d_in[26];
    const float* linb   = (const float*)d_in[27];

    const int NP = in_sizes[0] / 128;
    const int NA = in_sizes[1] / 128;
    const int Ec = in_sizes[2];
    const int Ea = in_sizes[4];
    const int Eh = in_sizes[6];
    const int Etot = Ec + Ea + Eh;

    const int nbc = (NP + 127) >> 7;
    const int nba = (NP + 127) >> 7;
    const int nbh = (NA + 127) >> 7;
    const int totB = nbc + nba + nbh;
    if (totB > HB) return;

    // ---- carve workspace ----
    char* base = (char*)d_ws;
    size_t cur = 0;
    auto carve = [&](size_t bytes) -> char* {
        char* p = base + cur;
        cur = (cur + bytes + 255) & ~(size_t)255;
        return p;
    };
    uint32_t* xb_p = (uint32_t*)carve((size_t)NP * 128 * 2);
    uint32_t* xb_a = (uint32_t*)carve((size_t)NA * 128 * 2);
    uint32_t* S1 = (uint32_t*)carve((size_t)NP * 128 * 2);
    uint32_t* S2 = (uint32_t*)carve((size_t)NP * 128 * 2);
    uint32_t* S3 = (uint32_t*)carve((size_t)NP * 128 * 2);
    uint32_t* SH = (uint32_t*)carve((size_t)NA * 128 * 2);
    unsigned short* W1hi = (unsigned short*)carve(3 * 16384 * 2);
    unsigned short* W1lo = (unsigned short*)carve(3 * 16384 * 2);
    unsigned short* W2hi = (unsigned short*)carve(3 * 16384 * 2);
    unsigned short* W2lo = (unsigned short*)carve(3 * 16384 * 2);
    unsigned short* WHhi = (unsigned short*)carve(2 * 16384 * 2);
    unsigned short* WHlo = (unsigned short*)carve(2 * 16384 * 2);
    float* b1 = (float*)carve(512);
    float* b2 = (float*)carve(512);
    int* off_c = (int*)carve((size_t)(NP + 1) * 4);
    int* off_a = (int*)carve((size_t)(NP + 1) * 4);
    int* off_h = (int*)carve((size_t)(NA + 1) * 4);
    int* colAll = (int*)carve((size_t)Etot * 4);
    uint2* pairs = (uint2*)carve((size_t)Etot * 8);
    int* gboff = (int*)carve((size_t)(totB + 1) * 4);
    int* bcur  = (int*)carve((size_t)totB * 4);
    int* bcnt  = (int*)carve((size_t)totB * 4);
    if (cur > ws_size) return;

    // ---- CSR build via bucket partition ----
    hipMemsetAsync(bcnt, 0, (size_t)totB * 4, stream);
    bucket_hist_kernel<<<(Etot + 16383) / 16384, 256, 0, stream>>>(
        c_dst, Ec, a_dst, Ea, h_dst, Eh, nbc, nba, totB, bcnt);
    bucket_scan_kernel<<<3, 256, 0, stream>>>(bcnt, nbc, nba, nbh, Ec, Ea, Eh,
                                              gboff, bcur);
    partition_kernel<<<(Etot + 2047) / 2048, 256, 0, stream>>>(
        c_src, c_dst, Ec, a_src, a_dst, Ea, h_src, h_dst, Eh,
        nbc, nba, totB, bcur, pairs);
    bucket_build_kernel<<<totB, 256, 0, stream>>>(
        pairs, gboff, nbc, nba, NP, NA, Ec, Ea, Eh, off_c, off_a, off_h, colAll);

    const int* col_c = colAll;
    const int* col_a = colAll + Ec;
    const int* col_h = colAll + Ec + Ea;

    // ---- dtype prep ----
    cvt2_bf16_kernel<<<((NP + NA) * 16 + 255) / 256, 256, 0, stream>>>(
        x_p, xb_p, NP * 16, x_a, xb_a, NA * 16);
    prep_weights_kernel<<<192, 256, 0, stream>>>(
        l1c_Wl, l1c_bl, l1c_Wr, l1a_Wl, l1a_bl, l1a_Wr,
        l2c_Wl, l2c_bl, l2c_Wr, l2a_Wl, l2a_bl, l2a_Wr,
        l1h_Wl, l1h_Wr, W1hi, W1lo, b1, W2hi, W2lo, b2, WHhi, WHlo);

    // ---- layer 1 ----
    const int rows_l1 = 2 * NP + NA;
    agg_l1_kernel<<<(rows_l1 + 3) / 4, 256, 0, stream>>>(
        xb_p, xb_a, off_c, col_c, off_a, col_a, off_h, col_h, S1, S2, SH, NP, NA);
    const int nbP = (NP + 127) / 128;
    const int nbA = (NA + 127) / 128;
    transform_l1_kernel<<<nbP + nbA, 256, 0, stream>>>(
        (const unsigned short*)S1, (const unsigned short*)S2,
        (const unsigned short*)xb_p, W1hi, W1lo, b1,
        (const unsigned short*)SH, (const unsigned short*)xb_a, WHhi, WHlo, l1h_bl,
        (unsigned short*)S1, (unsigned short*)SH, NP, NA, nbP);

    // ---- layer 2 ----
    agg_l2_kernel<<<(2 * NP + 3) / 4, 256, 0, stream>>>(
        S1, SH, off_c, col_c, off_a, col_a, S2, S3, NP);
    transform_p2_kernel<<<nbP, 256, 0, stream>>>(
        (const unsigned short*)S2, (const unsigned short*)S3,
        (const unsigned short*)S1, W2hi, W2lo, b2,
        (unsigned short*)S2, NP);

    // ---- head ----
    final_linear_kernel<<<((NP * 8) + 255) / 256, 256, 0, stream>>>(
        S2, linW, linb, (float*)d_out, NP);
}

// Round 10
// 292.300 us; speedup vs baseline: 62.4459x; 1.0407x over previous
//
#include <hip/hip_runtime.h>
#include <hip/hip_bf16.h>
#include <cstdint>

// ---------------------------------------------------------------------------
// FullHeteroGCN: 2-layer hetero GraphSAGE (mean aggr).
// R10: aggs are instruction-issue bound (R9: ILP-deepening bought nothing;
// ~170 wave-instr/row x 2cyc explains 81us). Cuts:
//  - padded CSR: per-dst edge lists padded to multiple of 4 with edges to a
//    zero row (index N of each gathered table); off|deg packed in one uint32
//    -> uniform quad loop, zero tail predication, one less load.
//  - 32-bit byte-offset gather addressing (no 64-bit addr chains).
//  - v_cvt_pk_bf16_f32 (1 instr) replaces manual RNE packing everywhere.
//  - cvt+prep+hist+zero-rows merged into one prologue dispatch.
// CSR build: bucket radix-partition (R8). Activations bf16; weights hi/lo
// split-bf16 (2 MFMA/tile), XOR-swizzled LDS staging; f32 accumulation.
// ---------------------------------------------------------------------------

typedef __attribute__((ext_vector_type(8))) short bf16x8;
typedef __attribute__((ext_vector_type(4))) float f32x4;

#define HB 2048          // max total buckets (LDS arrays); totB = 1564 here
#define BCAP 6144        // bucket_build col staging capacity (padded edges)

__device__ __forceinline__ void gload_lds16(const void* g, void* l) {
    __builtin_amdgcn_global_load_lds(
        (const __attribute__((address_space(1))) unsigned int*)g,
        (__attribute__((address_space(3))) unsigned int*)l,
        16, 0, 0);
}
__device__ __forceinline__ f32x4 mfma16(bf16x8 a, bf16x8 b, f32x4 c) {
    return __builtin_amdgcn_mfma_f32_16x16x32_bf16(a, b, c, 0, 0, 0);
}
// packed f32->bf16 RNE, one instruction (gfx950-verified)
__device__ __forceinline__ uint32_t cvtpk(float lo, float hi) {
    uint32_t r;
    asm("v_cvt_pk_bf16_f32 %0, %1, %2" : "=v"(r) : "v"(lo), "v"(hi));
    return r;
}
__device__ __forceinline__ unsigned short bf16_1(float v) {
    uint32_t r;
    asm("v_cvt_pk_bf16_f32 %0, %1, %2" : "=v"(r) : "v"(v), "v"(v));
    return (unsigned short)r;
}
__device__ __forceinline__ float blo(uint32_t v) { return __uint_as_float(v << 16); }
__device__ __forceinline__ float bhi(uint32_t v) { return __uint_as_float(v & 0xFFFF0000u); }

// ======================= CSR build (bucket partition) =======================

__global__ __launch_bounds__(256)
void bucket_scan_kernel(const int* __restrict__ bcnt, int nbc, int nba, int nbh,
                        int Ec, int Ea, int Eh,
                        int* __restrict__ gboff, int* __restrict__ bcur) {
    const int r  = blockIdx.x;
    const int sb = (r == 0) ? 0 : (r == 1) ? nbc : nbc + nba;
    const int nb = (r == 0) ? nbc : (r == 1) ? nba : nbh;
    const int base = (r == 0) ? 0 : (r == 1) ? Ec : Ec + Ea;
    const int tid = threadIdx.x;
    __shared__ int sm[256];
    __shared__ int carry;
    if (tid == 0) carry = base;
    __syncthreads();
    for (int c0 = 0; c0 < nb; c0 += 256) {
        int i = c0 + tid;
        int v = (i < nb) ? bcnt[sb + i] : 0;
        sm[tid] = v; __syncthreads();
        for (int d = 1; d < 256; d <<= 1) {
            int t = (tid >= d) ? sm[tid - d] : 0;
            __syncthreads();
            sm[tid] += t;
            __syncthreads();
        }
        int pre = carry + sm[tid] - v;
        if (i < nb) { gboff[sb + i] = pre; bcur[sb + i] = pre; }
        int tot = sm[255];
        __syncthreads();
        if (tid == 0) carry += tot;
        __syncthreads();
    }
    if (tid == 0 && r == 2) gboff[nbc + nba + nbh] = Ec + Ea + Eh;
}

__global__ __launch_bounds__(256)
void partition_kernel(const int* __restrict__ sc, const int* __restrict__ dc, int Ec,
                      const int* __restrict__ sa, const int* __restrict__ da, int Ea,
                      const int* __restrict__ sh, const int* __restrict__ dh, int Eh,
                      int nbc, int nba, int totB,
                      int* __restrict__ bcur, uint2* __restrict__ pairs) {
    __shared__ int lbin[HB];
    __shared__ int gbase[HB];
    __shared__ int swork[256];
    __shared__ uint2 sorted[2048];
    __shared__ unsigned short sbin[2048];
    const int tid = threadIdx.x;
    const int Etot = Ec + Ea + Eh;
    const int start = blockIdx.x * 2048;
    const int cnt = min(2048, Etot - start);
    for (int b = tid; b < HB; b += 256) lbin[b] = 0;
    __syncthreads();
    uint32_t esrc[8], edst[8]; int ebin[8];
#pragma unroll
    for (int k = 0; k < 8; ++k) {
        int i = start + k * 256 + tid;
        int bin = -1; uint32_t s = 0, d = 0;
        if (i < Etot) {
            if (i < Ec)           { s = sc[i];           d = dc[i];           bin = (int)(d >> 7); }
            else if (i < Ec + Ea) { s = sa[i - Ec];      d = da[i - Ec];      bin = nbc + (int)(d >> 7); }
            else                  { s = sh[i - Ec - Ea]; d = dh[i - Ec - Ea]; bin = nbc + nba + (int)(d >> 7); }
            atomicAdd(&lbin[bin], 1);
        }
        esrc[k] = s; edst[k] = d; ebin[k] = bin;
    }
    __syncthreads();
    const int base8 = tid * 8;
    int lv[8]; int s0 = 0;
#pragma unroll
    for (int j = 0; j < 8; ++j) { lv[j] = lbin[base8 + j]; s0 += lv[j]; }
    swork[tid] = s0; __syncthreads();
    for (int d = 1; d < 256; d <<= 1) {
        int t = (tid >= d) ? swork[tid - d] : 0;
        __syncthreads();
        swork[tid] += t;
        __syncthreads();
    }
    int run = swork[tid] - s0;
    __syncthreads();
#pragma unroll
    for (int j = 0; j < 8; ++j) { lbin[base8 + j] = run; run += lv[j]; }
    __syncthreads();
    for (int b = tid; b < totB; b += 256) {
        int off = lbin[b];
        int c = lbin[b + 1] - off;
        if (c > 0) gbase[b] = atomicAdd(&bcur[b], c) - off;
    }
    __syncthreads();
#pragma unroll
    for (int k = 0; k < 8; ++k) {
        if (ebin[k] >= 0) {
            int p = atomicAdd(&lbin[ebin[k]], 1);
            sorted[p] = make_uint2(esrc[k], edst[k]);
            sbin[p] = (unsigned short)ebin[k];
        }
    }
    __syncthreads();
    for (int p = tid; p < cnt; p += 256)
        pairs[gbase[sbin[p]] + p] = sorted[p];
}

// One block per bucket (<=128 dsts): LDS count -> padded scan -> packed
// off|deg write; colbuf pre-filled with zero-row index; scatter; coalesced
// col write. Padded layout: bucket base = (e0-relbase) + 384*lb.
__global__ __launch_bounds__(256)
void bucket_build_kernel(const uint2* __restrict__ pairs,
                         const int* __restrict__ gboff,
                         int nbc, int nba,
                         int NP, int NA, int Ec, int Ea,
                         uint32_t* __restrict__ off_c, uint32_t* __restrict__ off_a,
                         uint32_t* __restrict__ off_h,
                         int* __restrict__ col_c, int* __restrict__ col_a,
                         int* __restrict__ col_h) {
    const int bin = blockIdx.x;
    int lb, relbase, n, zrow; uint32_t* off; int* colp;
    if (bin < nbc)            { lb = bin;             relbase = 0;       n = NP; zrow = NP; off = off_c; colp = col_c; }
    else if (bin < nbc + nba) { lb = bin - nbc;       relbase = Ec;      n = NP; zrow = NA; off = off_a; colp = col_a; }
    else                      { lb = bin - nbc - nba; relbase = Ec + Ea; n = NA; zrow = NP; off = off_h; colp = col_h; }
    const int d0 = lb << 7;
    const int e0 = gboff[bin], e1 = gboff[bin + 1];
    const int padBase = (e0 - relbase) + lb * 384;
    const int tid = threadIdx.x;
    __shared__ int lcnt[128];
    __shared__ int lcur[128];
    __shared__ int colbuf[BCAP];
    if (tid < 128) lcnt[tid] = 0;
    __syncthreads();
    for (int e = e0 + tid; e < e1; e += 256)
        atomicAdd(&lcnt[(int)pairs[e].y - d0], 1);
    __syncthreads();
    int c = 0, pc = 0;
    if (tid < 128) { c = lcnt[tid]; pc = (c + 3) & ~3; lcnt[tid] = pc; }
    __syncthreads();
    for (int d = 1; d < 128; d <<= 1) {
        int t = (tid < 128 && tid >= d) ? lcnt[tid - d] : 0;
        __syncthreads();
        if (tid < 128) lcnt[tid] += t;
        __syncthreads();
    }
    if (tid < 128) {
        int excl = lcnt[tid] - pc;
        lcur[tid] = excl;
        int d = d0 + tid;
        if (d < n) off[d] = (uint32_t)(padBase + excl) | ((uint32_t)c << 22);
    }
    __syncthreads();
    const int cntPad = lcnt[127];
    if (cntPad <= BCAP) {
        for (int i = tid; i < cntPad; i += 256) colbuf[i] = zrow;
        __syncthreads();
        for (int e = e0 + tid; e < e1; e += 256) {
            uint2 pr = pairs[e];
            int p = atomicAdd(&lcur[(int)pr.y - d0], 1);
            colbuf[p] = (int)pr.x;
        }
        __syncthreads();
        for (int i = tid; i < cntPad; i += 256) colp[padBase + i] = colbuf[i];
    } else {  // overflow fallback
        for (int i = tid; i < cntPad; i += 256) colp[padBase + i] = zrow;
        __syncthreads();
        for (int e = e0 + tid; e < e1; e += 256) {
            uint2 pr = pairs[e];
            int p = atomicAdd(&lcur[(int)pr.y - d0], 1);
            colp[padBase + p] = (int)pr.x;
        }
    }
}

// ======================= prologue (cvt + prep + hist + zero rows) ==========

__device__ __forceinline__ void split_store(float w, unsigned short* hi,
                                            unsigned short* lo, int i) {
    uint32_t u = __float_as_uint(w);
    hi[i] = (unsigned short)(u >> 16);
    float l = w - __uint_as_float(u & 0xFFFF0000u);
    lo[i] = (unsigned short)(__float_as_uint(l) >> 16);
}

__global__ __launch_bounds__(256)
void prologue_kernel(const float* __restrict__ x_p, const float* __restrict__ x_a,
                     uint32_t* __restrict__ xb_p, uint32_t* __restrict__ xb_a,
                     int NP, int NA, int nbCvt,
                     const float* l1cWl, const float* l1cbl, const float* l1cWr,
                     const float* l1aWl, const float* l1abl, const float* l1aWr,
                     const float* l2cWl, const float* l2cbl, const float* l2cWr,
                     const float* l2aWl, const float* l2abl, const float* l2aWr,
                     const float* lhWl, const float* lhWr,
                     unsigned short* W1hi, unsigned short* W1lo, float* b1,
                     unsigned short* W2hi, unsigned short* W2lo, float* b2,
                     unsigned short* WHhi, unsigned short* WHlo,
                     const int* __restrict__ dc, int Ec,
                     const int* __restrict__ da, int Ea,
                     const int* __restrict__ dh, int Eh,
                     int nbc, int nba, int totB, int* __restrict__ bcnt,
                     int nbHist, uint32_t* __restrict__ S1, uint32_t* __restrict__ SH) {
    __shared__ int lh[HB];
    const int b = blockIdx.x, tid = threadIdx.x;
    if (b < nbCvt) {
        // f32 -> bf16 RNE table convert, 8 elems per thread
        int i = b * 256 + tid;
        const float* X; uint32_t* Y; int j;
        const int n80 = NP * 16;
        if (i < n80)                 { X = x_p; Y = xb_p; j = i; }
        else if (i < n80 + NA * 16)  { X = x_a; Y = xb_a; j = i - n80; }
        else return;
        float4 v0 = *(const float4*)(X + (size_t)j * 8);
        float4 v1 = *(const float4*)(X + (size_t)j * 8 + 4);
        uint4 o;
        o.x = cvtpk(v0.x, v0.y); o.y = cvtpk(v0.z, v0.w);
        o.z = cvtpk(v1.x, v1.y); o.w = cvtpk(v1.z, v1.w);
        *(uint4*)(Y + (size_t)j * 4) = o;
    } else if (b < nbCvt + 192) {
        const int bid = b - nbCvt;
        if (bid < 64) {
            int i = bid * 256 + tid;
            split_store(0.5f * l1cWl[i], W1hi, W1lo, i);
            split_store(0.5f * l1aWl[i], W1hi, W1lo, 16384 + i);
            split_store(0.5f * (l1cWr[i] + l1aWr[i]), W1hi, W1lo, 32768 + i);
            if (i < 128) b1[i] = 0.5f * (l1cbl[i] + l1abl[i]);
        } else if (bid < 128) {
            int i = (bid - 64) * 256 + tid;
            split_store(0.5f * l2cWl[i], W2hi, W2lo, i);
            split_store(0.5f * l2aWl[i], W2hi, W2lo, 16384 + i);
            split_store(0.5f * (l2cWr[i] + l2aWr[i]), W2hi, W2lo, 32768 + i);
            if (i < 128) b2[i] = 0.5f * (l2cbl[i] + l2abl[i]);
        } else {
            int i = (bid - 128) * 256 + tid;
            split_store(lhWl[i], WHhi, WHlo, i);
            split_store(lhWr[i], WHhi, WHlo, 16384 + i);
        }
    } else if (b < nbCvt + 192 + nbHist) {
        // bucket histogram via LDS
        const int hb = b - nbCvt - 192;
        for (int k = tid; k < HB; k += 256) lh[k] = 0;
        __syncthreads();
        const int Etot = Ec + Ea + Eh;
        const int start = hb * 16384;
        const int end = min(start + 16384, Etot);
        for (int i = start + tid; i < end; i += 256) {
            int bin;
            if (i < Ec)            bin = dc[i] >> 7;
            else if (i < Ec + Ea)  bin = nbc + (da[i - Ec] >> 7);
            else                   bin = nbc + nba + (dh[i - Ec - Ea] >> 7);
            atomicAdd(&lh[bin], 1);
        }
        __syncthreads();
        for (int k = tid; k < totB; k += 256) {
            int v = lh[k];
            if (v) atomicAdd(&bcnt[k], v);
        }
    } else {
        // zero rows at index N of each gathered table
        const int w = tid & 63, which = tid >> 6;
        uint32_t* dst = (which == 0) ? xb_p + (size_t)NP * 64
                      : (which == 1) ? xb_a + (size_t)NA * 64
                      : (which == 2) ? S1 + (size_t)NP * 64
                                     : SH + (size_t)NA * 64;
        dst[w] = 0;
    }
}

// ======================= aggregation =======================

__device__ __forceinline__ void acc8(float* a, uint4 q) {
    a[0] += blo(q.x); a[1] += bhi(q.x);
    a[2] += blo(q.y); a[3] += bhi(q.y);
    a[4] += blo(q.z); a[5] += bhi(q.z);
    a[6] += blo(q.w); a[7] += bhi(q.w);
}

// padded quad-edge gather mean: 1 wave/row; uniform quad count (no
// predication); 32-bit byte-offset gathers; cvt_pk epilogue.
__device__ __forceinline__ void agg_row(const uint32_t* __restrict__ X,
                                        const uint32_t* __restrict__ offp,
                                        const int* __restrict__ col,
                                        uint32_t* __restrict__ Y, int row) {
    const int lane = threadIdx.x & 63;
    const int g = lane >> 4, t = lane & 15;
    const uint32_t pk = offp[row];
    int e = (int)(pk & 0x3FFFFFu);
    const int deg = (int)(pk >> 22);
    int nq = (deg + 3) >> 2;
    const char* Xc = (const char*)X;
    const uint32_t bo = (uint32_t)(t << 4);
    float A0[8] = {0.f, 0.f, 0.f, 0.f, 0.f, 0.f, 0.f, 0.f};
    float A1[8] = {0.f, 0.f, 0.f, 0.f, 0.f, 0.f, 0.f, 0.f};
    while (nq >= 2) {
        int sA = col[e + g];
        int sB = col[e + 4 + g];
        uint4 qA = *(const uint4*)(Xc + (((uint32_t)sA << 8) + bo));
        uint4 qB = *(const uint4*)(Xc + (((uint32_t)sB << 8) + bo));
        acc8(A0, qA); acc8(A1, qB);
        e += 8; nq -= 2;
    }
    if (nq) {
        int sA = col[e + g];
        uint4 qA = *(const uint4*)(Xc + (((uint32_t)sA << 8) + bo));
        acc8(A0, qA);
    }
    const float inv = 1.0f / (float)(deg > 0 ? deg : 1);
    float a[8];
#pragma unroll
    for (int j = 0; j < 8; ++j) {
        float v = A0[j] + A1[j];
        v += __shfl_xor(v, 16, 64);
        v += __shfl_xor(v, 32, 64);
        a[j] = v * inv;
    }
    if (g == 0) {
        uint4 o;
        o.x = cvtpk(a[0], a[1]); o.y = cvtpk(a[2], a[3]);
        o.z = cvtpk(a[4], a[5]); o.w = cvtpk(a[6], a[7]);
        *(uint4*)(Y + (size_t)row * 64 + (t << 2)) = o;
    }
}

__global__ __launch_bounds__(256)
void agg_l1_kernel(const uint32_t* __restrict__ xb_p, const uint32_t* __restrict__ xb_a,
                   const uint32_t* __restrict__ off_c, const int* __restrict__ col_c,
                   const uint32_t* __restrict__ off_a, const int* __restrict__ col_a,
                   const uint32_t* __restrict__ off_h, const int* __restrict__ col_h,
                   uint32_t* __restrict__ S1, uint32_t* __restrict__ S2,
                   uint32_t* __restrict__ SH, int NP, int NA) {
    int gw = (blockIdx.x * 256 + threadIdx.x) >> 6;
    if (gw < NP)               agg_row(xb_p, off_c, col_c, S1, gw);
    else if (gw < 2 * NP)      agg_row(xb_a, off_a, col_a, S2, gw - NP);
    else if (gw < 2 * NP + NA) agg_row(xb_p, off_h, col_h, SH, gw - 2 * NP);
}

__global__ __launch_bounds__(256)
void agg_l2_kernel(const uint32_t* __restrict__ P1, const uint32_t* __restrict__ A1,
                   const uint32_t* __restrict__ off_c, const int* __restrict__ col_c,
                   const uint32_t* __restrict__ off_a, const int* __restrict__ col_a,
                   uint32_t* __restrict__ S2, uint32_t* __restrict__ S3, int NP) {
    int gw = (blockIdx.x * 256 + threadIdx.x) >> 6;
    if (gw < NP)          agg_row(P1, off_c, col_c, S2, gw);
    else if (gw < 2 * NP) agg_row(A1, off_a, col_a, S3, gw - NP);
}

// ======================= transform (split-bf16 MFMA) =======================

template <int PAIRS>
__device__ __forceinline__ void transform_body(
        int blk, const unsigned short* A0, const unsigned short* A1,
        const unsigned short* A2,
        const unsigned short* __restrict__ Whi, const unsigned short* __restrict__ Wlo,
        const float* __restrict__ bias, unsigned short* Y, int N,
        unsigned short* Bhi, unsigned short* Blo) {
    const int tid  = threadIdx.x;
    const int l    = tid & 63;
    const int wv   = tid >> 6;
    const int lrow = l & 15;
    const int lkg  = l >> 4;
    const int rw   = blk * 128 + wv * 32;

    f32x4 acc0[8], acc1[8];
#pragma unroll
    for (int t = 0; t < 8; ++t) {
        acc0[t] = (f32x4){0.f, 0.f, 0.f, 0.f};
        acc1[t] = (f32x4){0.f, 0.f, 0.f, 0.f};
    }

    int arow0 = rw + lrow;      if (arow0 >= N) arow0 = N - 1;
    int arow1 = rw + 16 + lrow; if (arow1 >= N) arow1 = N - 1;
    const int kbase = lkg << 3;
    const int cb    = lkg << 4;

#pragma unroll 1
    for (int p = 0; p < PAIRS; ++p) {
        {
            const char* srcH = (const char*)(Whi + (p << 14));
            const char* srcL = (const char*)(Wlo + (p << 14));
#pragma unroll
            for (int it = 0; it < 8; ++it) {
                const int L = it * 4096 + tid * 16;
                const int j = L >> 8;
                const int g = (j << 8) + ((L & 255) ^ ((j & 7) << 4));
                gload_lds16(srcH + g, (char*)Bhi + L);
                gload_lds16(srcL + g, (char*)Blo + L);
            }
        }
        __syncthreads();
        const unsigned short* A = (p == 0) ? A0 : (p == 1) ? A1 : A2;
#pragma unroll
        for (int kc = 0; kc < 4; ++kc) {
            bf16x8 a0 = *(const bf16x8*)(A + (size_t)arow0 * 128 + kc * 32 + kbase);
            bf16x8 a1 = *(const bf16x8*)(A + (size_t)arow1 * 128 + kc * 32 + kbase);
            const int cbk = kc * 64 + cb;
#pragma unroll
            for (int t = 0; t < 8; ++t) {
                const int jt   = (t << 4) + lrow;
                const int addr = (jt << 8) + (cbk ^ ((jt & 7) << 4));
                bf16x8 bh = *(const bf16x8*)((const char*)Bhi + addr);
                bf16x8 bl = *(const bf16x8*)((const char*)Blo + addr);
                acc0[t] = mfma16(a0, bh, acc0[t]);
                acc1[t] = mfma16(a1, bh, acc1[t]);
                acc0[t] = mfma16(a0, bl, acc0[t]);
                acc1[t] = mfma16(a1, bl, acc1[t]);
            }
        }
        __syncthreads();
    }
#pragma unroll
    for (int t = 0; t < 8; ++t) {
        const int c = t * 16 + lrow;
        const float bv = bias[c];
#pragma unroll
        for (int r = 0; r < 4; ++r) {
            int row0 = rw + (lkg << 2) + r;
            if (row0 < N)
                Y[(size_t)row0 * 128 + c] = bf16_1(fmaxf(acc0[t][r] + bv, 0.f));
            int row1 = row0 + 16;
            if (row1 < N)
                Y[(size_t)row1 * 128 + c] = bf16_1(fmaxf(acc1[t][r] + bv, 0.f));
        }
    }
}

__global__ __launch_bounds__(256, 2)
void transform_l1_kernel(const unsigned short* S1, const unsigned short* S2,
                         const unsigned short* xb_p,
                         const unsigned short* __restrict__ W1hi,
                         const unsigned short* __restrict__ W1lo,
                         const float* __restrict__ b1,
                         const unsigned short* SH, const unsigned short* xb_a,
                         const unsigned short* __restrict__ WHhi,
                         const unsigned short* __restrict__ WHlo,
                         const float* __restrict__ bh,
                         unsigned short* P1out, unsigned short* A1out,
                         int NP, int NA, int nbP) {
    __shared__ unsigned short Bhi[128 * 128];
    __shared__ unsigned short Blo[128 * 128];
    if ((int)blockIdx.x < nbP)
        transform_body<3>(blockIdx.x, S1, S2, xb_p, W1hi, W1lo, b1,
                          P1out, NP, Bhi, Blo);
    else
        transform_body<2>(blockIdx.x - nbP, SH, xb_a, nullptr, WHhi, WHlo, bh,
                          A1out, NA, Bhi, Blo);
}

__global__ __launch_bounds__(256, 2)
void transform_p2_kernel(const unsigned short* A0, const unsigned short* A1,
                         const unsigned short* A2,
                         const unsigned short* __restrict__ Whi,
                         const unsigned short* __restrict__ Wlo,
                         const float* __restrict__ bias, unsigned short* Y, int N) {
    __shared__ unsigned short Bhi[128 * 128];
    __shared__ unsigned short Blo[128 * 128];
    transform_body<3>(blockIdx.x, A0, A1, A2, Whi, Wlo, bias, Y, N, Bhi, Blo);
}

__global__ __launch_bounds__(256)
void final_linear_kernel(const uint32_t* __restrict__ P, const float* __restrict__ Wt,
                         const float* __restrict__ bb, float* __restrict__ out, int N) {
    __shared__ float lw[1024];
    __shared__ float lb[8];
    for (int i = threadIdx.x; i < 1024; i += 256) lw[i] = Wt[i];
    if (threadIdx.x < 8) lb[threadIdx.x] = bb[threadIdx.x];
    __syncthreads();
    int idx = blockIdx.x * 256 + threadIdx.x;
    if (idx >= N * 8) return;
    int row = idx >> 3, c = idx & 7;
    const uint32_t* pr = P + (size_t)row * 64;
    const float* wr = &lw[c << 7];
    float s = 0.f;
#pragma unroll
    for (int k = 0; k < 64; k += 4) {
        uint4 q = *(const uint4*)(pr + k);
        const float* w = wr + (k << 1);
        s += blo(q.x) * w[0] + bhi(q.x) * w[1]
           + blo(q.y) * w[2] + bhi(q.y) * w[3]
           + blo(q.z) * w[4] + bhi(q.z) * w[5]
           + blo(q.w) * w[6] + bhi(q.w) * w[7];
    }
    out[idx] = s + lb[c];
}

extern "C" void kernel_launch(void* const* d_in, const int* in_sizes, int n_in,
                              void* d_out, int out_size, void* d_ws, size_t ws_size,
                              hipStream_t stream) {
    const float* x_p = (const float*)d_in[0];
    const float* x_a = (const float*)d_in[1];
    const int* c_src = (const int*)d_in[2];
    const int* c_dst = (const int*)d_in[3];
    const int* a_src = (const int*)d_in[4];
    const int* a_dst = (const int*)d_in[5];
    const int* h_src = (const int*)d_in[6];
    const int* h_dst = (const int*)d_in[7];
    const float* l1c_Wl = (const float*)d_in[8];
    const float* l1c_bl = (const float*)d_in[9];
    const float* l1c_Wr = (const float*)d_in[10];
    const float* l1a_Wl = (const float*)d_in[11];
    const float* l1a_bl = (const float*)d_in[12];
    const float* l1a_Wr = (const float*)d_in[13];
    const float* l1h_Wl = (const float*)d_in[14];
    const float* l1h_bl = (const float*)d_in[15];
    const float* l1h_Wr = (const float*)d_in[16];
    const float* l2c_Wl = (const float*)d_in[17];
    const float* l2c_bl = (const float*)d_in[18];
    const float* l2c_Wr = (const float*)d_in[19];
    const float* l2a_Wl = (const float*)d_in[20];
    const float* l2a_bl = (const float*)d_in[21];
    const float* l2a_Wr = (const float*)d_in[22];
    const float* linW   = (const float*)d_in[26];
    const float* linb   = (const float*)d_in[27];

    const int NP = in_sizes[0] / 128;
    const int NA = in_sizes[1] / 128;
    const int Ec = in_sizes[2];
    const int Ea = in_sizes[4];
    const int Eh = in_sizes[6];
    const int Etot = Ec + Ea + Eh;

    const int nbc = (NP + 127) >> 7;
    const int nba = (NP + 127) >> 7;
    const int nbh = (NA + 127) >> 7;
    const int totB = nbc + nba + nbh;
    if (totB > HB) return;

    // ---- carve workspace ----
    char* base = (char*)d_ws;
    size_t cur = 0;
    auto carve = [&](size_t bytes) -> char* {
        char* p = base + cur;
        cur = (cur + bytes + 255) & ~(size_t)255;
        return p;
    };
    uint32_t* xb_p = (uint32_t*)carve((size_t)(NP + 1) * 128 * 2);  // +zero row
    uint32_t* xb_a = (uint32_t*)carve((size_t)(NA + 1) * 128 * 2);  // +zero row
    uint32_t* S1 = (uint32_t*)carve((size_t)(NP + 1) * 128 * 2);    // +zero row
    uint32_t* S2 = (uint32_t*)carve((size_t)NP * 128 * 2);
    uint32_t* S3 = (uint32_t*)carve((size_t)NP * 128 * 2);
    uint32_t* SH = (uint32_t*)carve((size_t)(NA + 1) * 128 * 2);    // +zero row
    unsigned short* W1hi = (unsigned short*)carve(3 * 16384 * 2);
    unsigned short* W1lo = (unsigned short*)carve(3 * 16384 * 2);
    unsigned short* W2hi = (unsigned short*)carve(3 * 16384 * 2);
    unsigned short* W2lo = (unsigned short*)carve(3 * 16384 * 2);
    unsigned short* WHhi = (unsigned short*)carve(2 * 16384 * 2);
    unsigned short* WHlo = (unsigned short*)carve(2 * 16384 * 2);
    float* b1 = (float*)carve(512);
    float* b2 = (float*)carve(512);
    uint32_t* off_c = (uint32_t*)carve((size_t)NP * 4);
    uint32_t* off_a = (uint32_t*)carve((size_t)NP * 4);
    uint32_t* off_h = (uint32_t*)carve((size_t)NA * 4);
    int* colAll = (int*)carve(((size_t)Etot + 384 * (size_t)totB) * 4);
    uint2* pairs = (uint2*)carve((size_t)Etot * 8);
    int* gboff = (int*)carve((size_t)(totB + 1) * 4);
    int* bcur  = (int*)carve((size_t)totB * 4);
    int* bcnt  = (int*)carve((size_t)totB * 4);
    if (cur > ws_size) return;

    const int EcPad = Ec + 384 * nbc;
    const int EaPad = Ea + 384 * nba;
    int* col_c = colAll;
    int* col_a = colAll + EcPad;
    int* col_h = colAll + EcPad + EaPad;

    // ---- prologue: memset + {cvt, prep, hist, zero-rows} in one dispatch ----
    hipMemsetAsync(bcnt, 0, (size_t)totB * 4, stream);
    const int nbCvt = ((NP + NA) * 16 + 255) / 256;
    const int nbHist = (Etot + 16383) / 16384;
    prologue_kernel<<<nbCvt + 192 + nbHist + 1, 256, 0, stream>>>(
        x_p, x_a, xb_p, xb_a, NP, NA, nbCvt,
        l1c_Wl, l1c_bl, l1c_Wr, l1a_Wl, l1a_bl, l1a_Wr,
        l2c_Wl, l2c_bl, l2c_Wr, l2a_Wl, l2a_bl, l2a_Wr,
        l1h_Wl, l1h_Wr, W1hi, W1lo, b1, W2hi, W2lo, b2, WHhi, WHlo,
        c_dst, Ec, a_dst, Ea, h_dst, Eh, nbc, nba, totB, bcnt, nbHist, S1, SH);

    // ---- CSR build (padded, packed off|deg) ----
    bucket_scan_kernel<<<3, 256, 0, stream>>>(bcnt, nbc, nba, nbh, Ec, Ea, Eh,
                                              gboff, bcur);
    partition_kernel<<<(Etot + 2047) / 2048, 256, 0, stream>>>(
        c_src, c_dst, Ec, a_src, a_dst, Ea, h_src, h_dst, Eh,
        nbc, nba, totB, bcur, pairs);
    bucket_build_kernel<<<totB, 256, 0, stream>>>(
        pairs, gboff, nbc, nba, NP, NA, Ec, Ea,
        off_c, off_a, off_h, col_c, col_a, col_h);

    // ---- layer 1 ----
    const int rows_l1 = 2 * NP + NA;
    agg_l1_kernel<<<(rows_l1 + 3) / 4, 256, 0, stream>>>(
        xb_p, xb_a, off_c, col_c, off_a, col_a, off_h, col_h, S1, S2, SH, NP, NA);
    const int nbP = (NP + 127) / 128;
    const int nbA = (NA + 127) / 128;
    transform_l1_kernel<<<nbP + nbA, 256, 0, stream>>>(
        (const unsigned short*)S1, (const unsigned short*)S2,
        (const unsigned short*)xb_p, W1hi, W1lo, b1,
        (const unsigned short*)SH, (const unsigned short*)xb_a, WHhi, WHlo, l1h_bl,
        (unsigned short*)S1, (unsigned short*)SH, NP, NA, nbP);

    // ---- layer 2 ----
    agg_l2_kernel<<<(2 * NP + 3) / 4, 256, 0, stream>>>(
        S1, SH, off_c, col_c, off_a, col_a, S2, S3, NP);
    transform_p2_kernel<<<nbP, 256, 0, stream>>>(
        (const unsigned short*)S2, (const unsigned short*)S3,
        (const unsigned short*)S1, W2hi, W2lo, b2,
        (unsigned short*)S2, NP);

    // ---- head ----
    final_linear_kernel<<<((NP * 8) + 255) / 256, 256, 0, stream>>>(
        S2, linW, linb, (float*)d_out, NP);
}